// Round 18
// baseline (619.939 us; speedup 1.0000x reference)
//
#include <hip/hip_runtime.h>
#include <math.h>

#define H 128
#define NHD 8
#define DH 16
#define RB 6
#define NBI 2
#define BSG 16
#define LBLK 64
#define KATOM 16
#define NBLKT 1024
#define NA 16384
#define NE 262144
#define EBE 512

__device__ __forceinline__ float atomAddF(float* p, float v) {
#if defined(__gfx90a__) || defined(__gfx940__) || defined(__gfx941__) || defined(__gfx942__) || defined(__gfx950__)
  return unsafeAtomicAdd(p, v);
#else
  return atomicAdd(p, v);
#endif
}

__device__ __forceinline__ float fsilu(float v) {
  return v * __builtin_amdgcn_rcpf(1.0f + __expf(-v));
}

// ---------------- embedding ----------------
__global__ __launch_bounds__(256) void k_embed(
    const int* __restrict__ A, const int* __restrict__ apos,
    const int* __restrict__ btypes,
    const float* __restrict__ emb_atom, const float* __restrict__ emb_pos,
    const float* __restrict__ emb_block, float* __restrict__ x)
{
  int idx = blockIdx.x * 256 + threadIdx.x;   // over NA*H
  int n = idx >> 7, h = idx & 127;
  x[idx] = emb_atom[A[n] * H + h] + emb_pos[apos[n] * H + h]
         + emb_block[btypes[n >> 4] * H + h];
}

// ---------------- edge sort: histogram ----------------
__global__ __launch_bounds__(256) void k_hist(
    const int* __restrict__ ei, int* __restrict__ cnt)
{
  int e = blockIdx.x * 256 + threadIdx.x;
  atomicAdd(&cnt[ei[e]], 1);
}

// ---------------- edge sort: scan (single block, 1024 thr, 16 bins each) ----
__global__ __launch_bounds__(1024) void k_scan(
    const int* __restrict__ cnt, int* __restrict__ off,
    int* __restrict__ cur, float* __restrict__ cntf)
{
  __shared__ int ps[1024];
  int t = threadIdx.x;
  int base = t * 16;
  int local[16];
  int s = 0;
  #pragma unroll
  for (int k = 0; k < 16; ++k) { local[k] = s; s += cnt[base + k]; }
  ps[t] = s;
  __syncthreads();
  for (int d = 1; d < 1024; d <<= 1) {
    int v = (t >= d) ? ps[t - d] : 0;
    __syncthreads();
    ps[t] += v;
    __syncthreads();
  }
  int offset = (t == 0) ? 0 : ps[t - 1];
  #pragma unroll
  for (int k = 0; k < 16; ++k) {
    int o = offset + local[k];
    off[base + k] = o;
    cur[base + k] = o;
    cntf[base + k] = (float)cnt[base + k];
  }
  if (t == 1023) off[NA] = offset + s;
}

// ---------------- edge sort: scatter + fused RBF ----------------
__global__ __launch_bounds__(256) void k_scatter(
    const int* __restrict__ ei, const int* __restrict__ ej,
    const float* __restrict__ coords, const float* __restrict__ freq,
    int* __restrict__ cur, int* __restrict__ ej_s, float* __restrict__ rbf_s)
{
  int e = blockIdx.x * 256 + threadIdx.x;
  int i = ei[e], j = ej[e];
  int pos = atomicAdd(&cur[i], 1);
  ej_s[pos] = j;
  float dx = coords[i*3+0] - coords[j*3+0];
  float dy = coords[i*3+1] - coords[j*3+1];
  float dz = coords[i*3+2] - coords[j*3+2];
  float d = sqrtf(dx*dx + dy*dy + dz*dz);
  float u = fmaxf(d * 0.125f, 1e-3f);
  float u2 = u*u, u4 = u2*u2, u5 = u4*u, u6 = u5*u, u7 = u6*u;
  float env = 1.0f/u - 28.0f*u5 + 48.0f*u6 - 21.0f*u7;
  #pragma unroll
  for (int r = 0; r < RB; ++r)
    rbf_s[(size_t)pos*RB + r] = env * sinf(freq[r] * u);
}

// ---------------- block-edge CSR (per-graph src buckets) ----------------
__global__ __launch_bounds__(256) void k_bedge_csr(
    const int* __restrict__ bedges, int* __restrict__ blist,
    int* __restrict__ boff, float* __restrict__ ind)
{
  __shared__ int hist[64], offs[65], curs[64];
  int b = blockIdx.x, t = threadIdx.x;
  if (t < 64) hist[t] = 0;
  __syncthreads();
  for (int e = t; e < EBE; e += 256) atomicAdd(&hist[bedges[(b*EBE + e)*2]], 1);
  __syncthreads();
  if (t == 0) {
    offs[0] = 0;
    for (int k = 0; k < 64; ++k) offs[k+1] = offs[k] + hist[k];
  }
  __syncthreads();
  if (t < 64) curs[t] = offs[t];
  __syncthreads();
  for (int e = t; e < EBE; e += 256) {
    int src = bedges[(b*EBE + e)*2];
    int pos = atomicAdd(&curs[src], 1);
    blist[b*EBE + pos] = e;
  }
  if (t < 65) boff[b*65 + t] = offs[t];
  if (t < 64) ind[b*64 + t] = (hist[t] > 0) ? 1.0f : 0.0f;
}

// ---------------- per-atom CSR edge pass v2 (float4 channels, no atomics) ----
__global__ __launch_bounds__(256) void k_edge_csr(
    const float* __restrict__ P, const float* __restrict__ Q,
    const float* __restrict__ rbf_s, const float* __restrict__ W1c,
    const int* __restrict__ ej_s, const int* __restrict__ off,
    float* __restrict__ Hagg)
{
  __shared__ float w[RB * H];
  for (int idx = threadIdx.x; idx < RB * H; idx += 256) w[idx] = W1c[idx];
  __syncthreads();
  int c4 = threadIdx.x & 31;        // channel quad
  int sub = threadIdx.x >> 5;       // atom within block
  int i = blockIdx.x * 8 + sub;
  int e0 = off[i], e1 = off[i + 1];
  float4 pv = *(const float4*)&P[(size_t)i * H + c4 * 4];
  float4 W0 = *(const float4*)&w[0*H + c4*4];
  float4 W1 = *(const float4*)&w[1*H + c4*4];
  float4 W2 = *(const float4*)&w[2*H + c4*4];
  float4 W3 = *(const float4*)&w[3*H + c4*4];
  float4 W4 = *(const float4*)&w[4*H + c4*4];
  float4 W5 = *(const float4*)&w[5*H + c4*4];
  float4 acc = {0, 0, 0, 0};
  for (int e = e0; e < e1; ++e) {
    int j = ej_s[e];
    float4 qv = *(const float4*)&Q[(size_t)j * H + c4 * 4];
    const float* rb = &rbf_s[(size_t)e * RB];
    float r0 = rb[0], r1 = rb[1], r2 = rb[2], r3 = rb[3], r4 = rb[4], r5 = rb[5];
    float4 v;
    v.x = pv.x + qv.x + r0*W0.x + r1*W1.x + r2*W2.x + r3*W3.x + r4*W4.x + r5*W5.x;
    v.y = pv.y + qv.y + r0*W0.y + r1*W1.y + r2*W2.y + r3*W3.y + r4*W4.y + r5*W5.y;
    v.z = pv.z + qv.z + r0*W0.z + r1*W1.z + r2*W2.z + r3*W3.z + r4*W4.z + r5*W5.z;
    v.w = pv.w + qv.w + r0*W0.w + r1*W1.w + r2*W2.w + r3*W3.w + r4*W4.w + r5*W5.w;
    acc.x += fsilu(v.x);
    acc.y += fsilu(v.y);
    acc.z += fsilu(v.z);
    acc.w += fsilu(v.w);
  }
  *(float4*)&Hagg[(size_t)i * H + c4 * 4] = acc;
}

// ---------------- weight prep: wbuf = [U1a ; W2@U1b], bvec = b2@U1b ----------
__global__ __launch_bounds__(128) void k_wprep(
    const float* __restrict__ W2, const float* __restrict__ U1,
    const float* __restrict__ b2, float* __restrict__ wbuf,
    float* __restrict__ bvec)
{
  int k = blockIdx.x, c = threadIdx.x;
  const float* U1b = U1 + 128 * H;
  wbuf[k * H + c] = U1[k * H + c];
  float s = 0.0f;
  for (int t = 0; t < H; ++t) s += W2[k * H + t] * U1b[t * H + c];
  wbuf[(128 + k) * H + c] = s;
  if (k == 0) {
    float sb = 0.0f;
    for (int t = 0; t < H; ++t) sb += b2[t] * U1b[t * H + c];
    bvec[c] = sb;
  }
}

// ---------------- generic 128-col GEMM v3: barrier-minimal, full-W panel ----
// Stages A[32][128] once per 128-K chunk and the whole W panel [128][128];
// inner loop has NO barriers (2 syncs per 128-K chunk vs 16 before).
__global__ __launch_bounds__(256) void gemm128(
    const float* __restrict__ A1, const float* __restrict__ A2,
    const float* __restrict__ W, int ldw, int wcol0,
    const float* __restrict__ bias, const float* __restrict__ bias2,
    const float* __restrict__ bias_scale,
    const float* __restrict__ res,
    float* __restrict__ C, int ldc, int ccol0,
    int M, int Ktot, int act, int ymul)
{
  __shared__ float As[32][128];    // 16 KB
  __shared__ float Ws[128][128];   // 64 KB  (80 KB total -> 2 blocks/CU)
  int tid = threadIdx.x;
  int m0 = blockIdx.x * 32;
  int yoff = blockIdx.y * ymul;
  int rr = tid >> 5;    // 0..7
  int cq = tid & 31;    // col quad
  float acc[4][4] = {};
  for (int kk0 = 0; kk0 < Ktot; kk0 += 128) {
    const float* Asrc = (kk0 == 0) ? A1 : A2;
    __syncthreads();   // protect previous chunk's LDS reads
    for (int idx = tid; idx < 32*32; idx += 256) {
      int r = idx >> 5, k4 = idx & 31;
      *(float4*)&As[r][k4*4] = *(const float4*)&Asrc[(size_t)(m0 + r)*H + k4*4];
    }
    for (int idx = tid; idx < 128*32; idx += 256) {
      int kr = idx >> 5, c4 = idx & 31;
      *(float4*)&Ws[kr][c4*4] =
          *(const float4*)&W[(size_t)(kk0 + kr)*ldw + wcol0 + yoff + c4*4];
    }
    __syncthreads();
    #pragma unroll 4
    for (int k4 = 0; k4 < 32; ++k4) {
      float4 w0 = *(const float4*)&Ws[k4*4+0][cq*4];
      float4 w1 = *(const float4*)&Ws[k4*4+1][cq*4];
      float4 w2 = *(const float4*)&Ws[k4*4+2][cq*4];
      float4 w3 = *(const float4*)&Ws[k4*4+3][cq*4];
      #pragma unroll
      for (int i = 0; i < 4; ++i) {
        float4 a = *(const float4*)&As[rr + 8*i][k4*4];
        acc[i][0] += a.x*w0.x + a.y*w1.x + a.z*w2.x + a.w*w3.x;
        acc[i][1] += a.x*w0.y + a.y*w1.y + a.z*w2.y + a.w*w3.y;
        acc[i][2] += a.x*w0.z + a.y*w1.z + a.z*w2.z + a.w*w3.z;
        acc[i][3] += a.x*w0.w + a.y*w1.w + a.z*w2.w + a.w*w3.w;
      }
    }
  }
  #pragma unroll
  for (int i = 0; i < 4; ++i) {
    int m = m0 + rr + 8*i;
    float bs = bias_scale ? bias_scale[m] : 1.0f;
    float4 out;
    float* po = &out.x;
    #pragma unroll
    for (int j = 0; j < 4; ++j) {
      int c = cq*4 + j;
      float v = acc[i][j];
      if (bias) v += bias[yoff + c];
      if (bias2) v += bias2[yoff + c] * bs;
      if (act == 1) v = fsilu(v);
      else if (act == 2) v = fmaxf(v, 0.0f);
      if (res) v += res[(size_t)m*H + c];
      po[j] = v;
    }
    *(float4*)&C[(size_t)m*ldc + ccol0 + yoff + cq*4] = out;
  }
}

// ---------------- block mean over K atoms ----------------
__global__ __launch_bounds__(256) void k_block_mean(
    const float* __restrict__ x, float* __restrict__ blocks)
{
  int idx = blockIdx.x * 256 + threadIdx.x;   // over NBLKT*H
  int nb = idx >> 7, h = idx & 127;
  float s = 0.0f;
  #pragma unroll
  for (int k = 0; k < KATOM; ++k)
    s += x[(size_t)(nb*KATOM + k)*H + h];
  blocks[idx] = s * (1.0f / KATOM);
}

// ---------------- block-edge pre-activation gather ----------------
__global__ __launch_bounds__(256) void k_gather_pre(
    const float* __restrict__ Pb, const float* __restrict__ Qb,
    const int* __restrict__ bedges, float* __restrict__ Epre)
{
  int idx = blockIdx.x * 256 + threadIdx.x;   // over BSG*EBE*H
  int row = idx >> 7, c = idx & 127;
  int g = row >> 9;
  int src = bedges[row*2], dst = bedges[row*2 + 1];
  float v = Pb[(size_t)(g*LBLK + src)*H + c] + Qb[(size_t)(g*LBLK + dst)*H + c];
  Epre[idx] = fmaxf(v, 0.0f);
}

// ---------------- MHA v7: thread-per-row, key-split, chunked online softmax ----
template <int S, int KS>
__global__ __launch_bounds__(256) void k_attn4(
    const float* __restrict__ qkv,
    float* __restrict__ pm, float* __restrict__ pl, float* __restrict__ po)
{
  constexpr int KP = S / KS;       // keys per split
  constexpr int RCH = S / 256;     // row chunks
  constexpr int NR = BSG * NHD * S;
  constexpr int CH = 32;           // score-cache chunk
  __shared__ float Ks[KP][DH];
  __shared__ float Vs[KP][DH];
  int idx = blockIdx.x;
  int rc = idx % RCH;
  int ks = (idx / RCH) % KS;
  int bh = idx / (RCH * KS);
  int b = bh >> 3, h = bh & 7;
  const float* base = qkv + (size_t)b * S * 384;
  int tid = threadIdx.x;
  for (int t = tid; t < KP * 4; t += 256) {
    int j = t >> 2, d4 = t & 3;
    int jg = ks * KP + j;
    *(float4*)&Ks[j][d4*4] = *(const float4*)(base + (size_t)jg*384 + 128 + h*DH + d4*4);
    *(float4*)&Vs[j][d4*4] = *(const float4*)(base + (size_t)jg*384 + 256 + h*DH + d4*4);
  }
  __syncthreads();
  int s = rc * 256 + tid;
  const float4* qp = (const float4*)(base + (size_t)s * 384 + h * DH);
  float4 q0 = qp[0], q1 = qp[1], q2 = qp[2], q3 = qp[3];
  float m = -1e30f, l = 0.0f;
  float4 o0 = {0,0,0,0}, o1 = {0,0,0,0}, o2 = {0,0,0,0}, o3 = {0,0,0,0};
  for (int c0 = 0; c0 < KP; c0 += CH) {
    float scv[CH];
    float mc = -1e30f;
    #pragma unroll
    for (int j = 0; j < CH; ++j) {
      float4 k0 = *(const float4*)&Ks[c0+j][0];
      float4 k1 = *(const float4*)&Ks[c0+j][4];
      float4 k2 = *(const float4*)&Ks[c0+j][8];
      float4 k3 = *(const float4*)&Ks[c0+j][12];
      float s0 = q0.x*k0.x + q0.y*k0.y + q0.z*k0.z + q0.w*k0.w;
      float s1 = q1.x*k1.x + q1.y*k1.y + q1.z*k1.z + q1.w*k1.w;
      float s2 = q2.x*k2.x + q2.y*k2.y + q2.z*k2.z + q2.w*k2.w;
      float s3 = q3.x*k3.x + q3.y*k3.y + q3.z*k3.z + q3.w*k3.w;
      float sc = (s0 + s1) + (s2 + s3);
      scv[j] = sc;
      mc = fmaxf(mc, sc);
    }
    float mn = fmaxf(m, mc);
    float corr = __expf((m - mn) * 0.25f);
    l *= corr;
    o0.x *= corr; o0.y *= corr; o0.z *= corr; o0.w *= corr;
    o1.x *= corr; o1.y *= corr; o1.z *= corr; o1.w *= corr;
    o2.x *= corr; o2.y *= corr; o2.z *= corr; o2.w *= corr;
    o3.x *= corr; o3.y *= corr; o3.z *= corr; o3.w *= corr;
    m = mn;
    #pragma unroll
    for (int j = 0; j < CH; ++j) {
      float p = __expf((scv[j] - m) * 0.25f);
      l += p;
      float4 v0 = *(const float4*)&Vs[c0+j][0];
      float4 v1 = *(const float4*)&Vs[c0+j][4];
      float4 v2 = *(const float4*)&Vs[c0+j][8];
      float4 v3 = *(const float4*)&Vs[c0+j][12];
      o0.x += p*v0.x; o0.y += p*v0.y; o0.z += p*v0.z; o0.w += p*v0.w;
      o1.x += p*v1.x; o1.y += p*v1.y; o1.z += p*v1.z; o1.w += p*v1.w;
      o2.x += p*v2.x; o2.y += p*v2.y; o2.z += p*v2.z; o2.w += p*v2.w;
      o3.x += p*v3.x; o3.y += p*v3.y; o3.z += p*v3.z; o3.w += p*v3.w;
    }
  }
  size_t R = (size_t)bh * S + s;
  pm[(size_t)ks * NR + R] = m;
  pl[(size_t)ks * NR + R] = l;
  float4* po4 = (float4*)po;
  po4[(size_t)(ks*4 + 0) * NR + R] = o0;
  po4[(size_t)(ks*4 + 1) * NR + R] = o1;
  po4[(size_t)(ks*4 + 2) * NR + R] = o2;
  po4[(size_t)(ks*4 + 3) * NR + R] = o3;
}

// combine KS partials per row (4 threads/row, d4 wave-uniform), write normalized ea
template <int S, int KS>
__global__ __launch_bounds__(256) void k_attn4c(
    const float* __restrict__ pm, const float* __restrict__ pl,
    const float* __restrict__ po, float* __restrict__ ea)
{
  constexpr int NR = BSG * NHD * S;
  int R = blockIdx.x * 64 + (threadIdx.x & 63);
  int d4 = threadIdx.x >> 6;   // wave-uniform
  float mv[KS];
  float m = -1e30f;
  #pragma unroll
  for (int k = 0; k < KS; ++k) { mv[k] = pm[(size_t)k*NR + R]; m = fmaxf(m, mv[k]); }
  const float4* po4 = (const float4*)po;
  float l = 0.0f;
  float4 o = {0, 0, 0, 0};
  #pragma unroll
  for (int k = 0; k < KS; ++k) {
    float w = __expf((mv[k] - m) * 0.25f);
    l += pl[(size_t)k*NR + R] * w;
    float4 p = po4[(size_t)(k*4 + d4)*NR + R];
    o.x += p.x*w; o.y += p.y*w; o.z += p.z*w; o.w += p.w*w;
  }
  float inv = 1.0f / l;
  float4 r = {o.x*inv, o.y*inv, o.z*inv, o.w*inv};
  ((float4*)ea)[(size_t)d4*NR + R] = r;
}

// gather ea rows per (block, channel) via block-edge CSR; divide by cnt
__global__ __launch_bounds__(256) void k_bsum_gather(
    const float* __restrict__ ea, const int* __restrict__ blist,
    const int* __restrict__ boff, float* __restrict__ bsum)
{
  constexpr int NR = BSG * NHD * EBE;
  int idx = blockIdx.x * 256 + threadIdx.x;   // over NBLKT*32
  int i = idx >> 5, c4 = idx & 31;
  int b = i >> 6, blk = i & 63;
  int h = c4 >> 2, d4 = c4 & 3;
  int e0 = boff[b*65 + blk], e1 = boff[b*65 + blk + 1];
  const float4* ea4 = (const float4*)ea;
  size_t basein = (size_t)d4 * NR + (size_t)(b*NHD + h) * EBE;
  float4 s = {0, 0, 0, 0};
  for (int e = e0; e < e1; ++e) {
    int srow = blist[b*EBE + e];
    float4 v = ea4[basein + srow];
    s.x += v.x; s.y += v.y; s.z += v.z; s.w += v.w;
  }
  float cnt = (float)(e1 - e0);
  float sc = (cnt > 0.0f) ? (1.0f / cnt) : 0.0f;
  float4 o = {s.x*sc, s.y*sc, s.z*sc, s.w*sc};
  *(float4*)&bsum[(size_t)i*H + c4*4] = o;
}

// ---------------- block self-attention: LDS K/V, wave-reduced mean, NO atomics ----
__global__ __launch_bounds__(256) void k_attnS(
    const float* __restrict__ qkv, float* __restrict__ m2)
{
  __shared__ float Ks[4][LBLK][DH];
  __shared__ float Vs[4][LBLK][DH];
  __shared__ float red[4][LBLK][DH + 1];   // pad 17: odd stride -> conflict-free
  int b = blockIdx.x >> 1, hq = blockIdx.x & 1;
  int tid = threadIdx.x;
  const float* base = qkv + (size_t)b * LBLK * 384;
  for (int t = tid; t < 1024; t += 256) {
    int hl = t >> 8, j = (t >> 2) & 63, d4 = t & 3;
    int h = hq*4 + hl;
    *(float4*)&Ks[hl][j][d4*4] = *(const float4*)(base + (size_t)j*384 + 128 + h*DH + d4*4);
    *(float4*)&Vs[hl][j][d4*4] = *(const float4*)(base + (size_t)j*384 + 256 + h*DH + d4*4);
  }
  __syncthreads();
  int hl = tid >> 6, s = tid & 63;   // hl uniform per wave; wave owns (b, h)
  int h = hq*4 + hl;
  const float4* qp = (const float4*)(base + (size_t)s * 384 + h * DH);
  float4 q0 = qp[0], q1 = qp[1], q2 = qp[2], q3 = qp[3];
  float m = -1e30f, l = 0.0f;
  float4 o0 = {0,0,0,0}, o1 = {0,0,0,0}, o2 = {0,0,0,0}, o3 = {0,0,0,0};
  for (int c0 = 0; c0 < LBLK; c0 += 32) {
    float scv[32];
    float mc = -1e30f;
    #pragma unroll
    for (int j = 0; j < 32; ++j) {
      float4 k0 = *(const float4*)&Ks[hl][c0+j][0];
      float4 k1 = *(const float4*)&Ks[hl][c0+j][4];
      float4 k2 = *(const float4*)&Ks[hl][c0+j][8];
      float4 k3 = *(const float4*)&Ks[hl][c0+j][12];
      float s0 = q0.x*k0.x + q0.y*k0.y + q0.z*k0.z + q0.w*k0.w;
      float s1 = q1.x*k1.x + q1.y*k1.y + q1.z*k1.z + q1.w*k1.w;
      float s2 = q2.x*k2.x + q2.y*k2.y + q2.z*k2.z + q2.w*k2.w;
      float s3 = q3.x*k3.x + q3.y*k3.y + q3.z*k3.z + q3.w*k3.w;
      float sc = (s0 + s1) + (s2 + s3);
      scv[j] = sc;
      mc = fmaxf(mc, sc);
    }
    float mn = fmaxf(m, mc);
    float corr = __expf((m - mn) * 0.25f);
    l *= corr;
    o0.x *= corr; o0.y *= corr; o0.z *= corr; o0.w *= corr;
    o1.x *= corr; o1.y *= corr; o1.z *= corr; o1.w *= corr;
    o2.x *= corr; o2.y *= corr; o2.z *= corr; o2.w *= corr;
    o3.x *= corr; o3.y *= corr; o3.z *= corr; o3.w *= corr;
    m = mn;
    #pragma unroll
    for (int j = 0; j < 32; ++j) {
      float p = __expf((scv[j] - m) * 0.25f);
      l += p;
      float4 v0 = *(const float4*)&Vs[hl][c0+j][0];
      float4 v1 = *(const float4*)&Vs[hl][c0+j][4];
      float4 v2 = *(const float4*)&Vs[hl][c0+j][8];
      float4 v3 = *(const float4*)&Vs[hl][c0+j][12];
      o0.x += p*v0.x; o0.y += p*v0.y; o0.z += p*v0.z; o0.w += p*v0.w;
      o1.x += p*v1.x; o1.y += p*v1.y; o1.z += p*v1.z; o1.w += p*v1.w;
      o2.x += p*v2.x; o2.y += p*v2.y; o2.z += p*v2.z; o2.w += p*v2.w;
      o3.x += p*v3.x; o3.y += p*v3.y; o3.z += p*v3.z; o3.w += p*v3.w;
    }
  }
  // normalize this row's output and stash in LDS (17-stride, conflict-free)
  float inv = (1.0f / l) * (1.0f / 64.0f);
  float ov[DH] = {o0.x,o0.y,o0.z,o0.w, o1.x,o1.y,o1.z,o1.w,
                  o2.x,o2.y,o2.z,o2.w, o3.x,o3.y,o3.z,o3.w};
  #pragma unroll
  for (int d = 0; d < DH; ++d) red[hl][s][d] = ov[d] * inv;
  __syncthreads();
  // wave owns (b,h): lanes 0..15 sum the 64 rows, plain store (no atomics)
  if (s < DH) {
    float acc = 0.0f;
    for (int r = 0; r < LBLK; ++r) acc += red[hl][r][s];
    m2[(size_t)b * H + h * DH + s] = acc;
  }
}

// ---------------- final: out-proj + LN + 3-layer MLP ----------------
__device__ __forceinline__ float bsum128(float v, float* red) {
  int t = threadIdx.x;
  red[t] = v; __syncthreads();
  #pragma unroll
  for (int off = 64; off > 0; off >>= 1) {
    if (t < off) red[t] += red[t + off];
    __syncthreads();
  }
  float s = red[0];
  __syncthreads();
  return s;
}

__global__ __launch_bounds__(128) void k_final(
    const float* __restrict__ m2, const float* __restrict__ out_w,
    const float* __restrict__ out_b, const float* __restrict__ lng,
    const float* __restrict__ lnb, const float* __restrict__ w1,
    const float* __restrict__ b1, const float* __restrict__ w2,
    const float* __restrict__ b2, const float* __restrict__ w3,
    const float* __restrict__ b3, float* __restrict__ out)
{
  __shared__ float buf[128];
  __shared__ float red[128];
  int b = blockIdx.x, t = threadIdx.x;
  buf[t] = m2[b*H + t];
  __syncthreads();
  float g = out_b[t];
  for (int k = 0; k < H; ++k) g += buf[k] * out_w[k*H + t];
  float mu = bsum128(g, red) * (1.0f / H);
  float df = g - mu;
  float var = bsum128(df * df, red) * (1.0f / H);
  float gn = df / sqrtf(var + 1e-5f) * lng[t] + lnb[t];
  __syncthreads();
  buf[t] = gn; __syncthreads();
  float h1 = b1[t];
  for (int k = 0; k < H; ++k) h1 += buf[k] * w1[k*H + t];
  h1 = fmaxf(h1, 0.0f);
  __syncthreads();
  buf[t] = h1; __syncthreads();
  float h2 = b2[t];
  for (int k = 0; k < H; ++k) h2 += buf[k] * w2[k*H + t];
  h2 = fmaxf(h2, 0.0f);
  float tot = bsum128(h2 * w3[t], red);
  if (t == 0) out[b] = tot + b3[0];
}

extern "C" void kernel_launch(void* const* d_in, const int* in_sizes, int n_in,
                              void* d_out, int out_size, void* d_ws, size_t ws_size,
                              hipStream_t stream) {
  (void)in_sizes; (void)n_in; (void)out_size; (void)ws_size;
  const int*   A          = (const int*)d_in[0];
  const int*   apos       = (const int*)d_in[1];
  const int*   btypes     = (const int*)d_in[2];
  const float* coords     = (const float*)d_in[3];
  const int*   edge_index = (const int*)d_in[4];
  const int*   bedges     = (const int*)d_in[5];
  const float* emb_atom   = (const float*)d_in[6];
  const float* emb_pos    = (const float*)d_in[7];
  const float* emb_block  = (const float*)d_in[8];
  const float* rbf_freq   = (const float*)d_in[9];
  const float* inter_w1   = (const float*)d_in[10];
  const float* inter_b1   = (const float*)d_in[11];
  const float* inter_w2   = (const float*)d_in[12];
  const float* inter_b2   = (const float*)d_in[13];
  const float* upd_w1     = (const float*)d_in[14];
  const float* upd_b1     = (const float*)d_in[15];
  const float* upd_w2     = (const float*)d_in[16];
  const float* upd_b2     = (const float*)d_in[17];
  const float* edge_w1    = (const float*)d_in[18];
  const float* edge_b1    = (const float*)d_in[19];
  const float* edge_w2    = (const float*)d_in[20];
  const float* edge_b2    = (const float*)d_in[21];
  const float* attn_in_w  = (const float*)d_in[22];
  const float* attn_in_b  = (const float*)d_in[23];
  const float* attn_out_w = (const float*)d_in[24];
  const float* attn_out_b = (const float*)d_in[25];
  const float* ln_g       = (const float*)d_in[26];
  const float* ln_b       = (const float*)d_in[27];
  const float* fin_w1     = (const float*)d_in[28];
  const float* fin_b1     = (const float*)d_in[29];
  const float* fin_w2     = (const float*)d_in[30];
  const float* fin_b2     = (const float*)d_in[31];
  const float* fin_w3     = (const float*)d_in[32];
  const float* fin_b3     = (const float*)d_in[33];
  float* out = (float*)d_out;

  float* ws = (float*)d_ws;
  float* x      = ws + 0;
  float* P      = ws + 2097152;
  float* Q      = ws + 4194304;
  float* Hagg   = ws + 6291456;
  float* rbf_s  = ws + 8388608;    // E*6 (sorted RBF)
  float* cntf   = ws + 9961472;    // NA
  float* blocks = ws + 9977856;    // NBLKT*H
  float* Pb     = ws + 10108928;
  float* Qb     = ws + 10240000;
  float* Epre   = ws + 10371072;   // BSG*EBE*H (sort scratch early; ea late)
  float* ef2    = ws + 11419648;
  float* qkv    = ws + 12468224;   // BSG*EBE*384
  float* bsum   = ws + 15613952;   // NBLKT*H
  float* ind    = ws + 15746048;   // NBLKT
  float* m2     = ws + 15747072;   // BSG*H
  int* blist    = (int*)(ws + 15749120);  // BSG*EBE ints
  int* boff     = (int*)(ws + 15757312);  // BSG*65 ints
  // sort scratch + wprep live in Epre region (dead until block-attention phase):
  int* ej_s   = (int*)(ws + 10371072);          // NE ints
  int* off    = (int*)(ws + 10371072 + 262144); // NA+1 ints
  int* cur    = (int*)(ws + 10371072 + 278784); // NA ints
  int* cnt    = (int*)(ws + 10371072 + 295168); // NA ints
  float* wbuf = ws + 10371072 + 311552;         // 256*128 floats
  float* bvec = ws + 10371072 + 344320;         // 128 floats
  // attention partials (KS=8, split-major) reuse x/P/Q/Hagg/rbf_s regions:
  float* part_m = ws + 0;          // 8*65536 = 524288 floats
  float* part_l = ws + 524288;     // 524288 floats
  float* part_o = ws + 1048576;    // 8*65536*16 = 8388608 floats -> ends 9437184
  float* ea     = ws + 10371072;   // 65536*16 = 1048576 floats (Epre region, d4-major)

  const int* ei = edge_index;
  const int* ej = edge_index + NE;

  // ---- edge sort (once; reused by both interaction blocks) ----
  (void)hipMemsetAsync(cnt, 0, NA * sizeof(int), stream);
  k_hist<<<NE/256, 256, 0, stream>>>(ei, cnt);
  k_scan<<<1, 1024, 0, stream>>>(cnt, off, cur, cntf);
  k_scatter<<<NE/256, 256, 0, stream>>>(ei, ej, coords, rbf_freq, cur, ej_s, rbf_s);
  k_bedge_csr<<<BSG, 256, 0, stream>>>(bedges, blist, boff, ind);

  k_embed<<<NA*H/256, 256, 0, stream>>>(A, apos, btypes, emb_atom, emb_pos, emb_block, x);

  for (int b = 0; b < NBI; ++b) {
    const float* w1 = inter_w1 + (size_t)b * 262 * H;
    k_wprep<<<128, 128, 0, stream>>>(inter_w2 + (size_t)b*H*H, upd_w1 + (size_t)b*2*H*H,
                                     inter_b2 + b*H, wbuf, bvec);
    // P = x@W1a + b1 ; Q = x@W1b
    gemm128<<<NA/32, 256, 0, stream>>>(x, nullptr, w1, H, 0, inter_b1 + b*H, nullptr,
                                       nullptr, nullptr, P, H, 0, NA, H, 0, 0);
    gemm128<<<NA/32, 256, 0, stream>>>(x, nullptr, w1 + 128*H, H, 0, nullptr, nullptr,
                                       nullptr, nullptr, Q, H, 0, NA, H, 0, 0);
    k_edge_csr<<<NA/8, 256, 0, stream>>>(P, Q, rbf_s, w1 + 256*H, ej_s, off, Hagg);
    // U = silu(x@U1a + Hagg@W2' + b1 + cnt*bvec) -> into Q  (agg-gemm folded in)
    gemm128<<<NA/32, 256, 0, stream>>>(x, Hagg, wbuf, H, 0, upd_b1 + b*H, bvec,
                                       cntf, nullptr, Q, H, 0, NA, 2*H, 1, 0);
    // x = U@upd_w2 + b2 + x
    gemm128<<<NA/32, 256, 0, stream>>>(Q, nullptr, upd_w2 + (size_t)b*H*H, H, 0,
                                       upd_b2 + b*H, nullptr, nullptr, x, x, H, 0, NA, H, 0, 0);
  }

  k_block_mean<<<NBLKT*H/256, 256, 0, stream>>>(x, blocks);
  gemm128<<<NBLKT/32, 256, 0, stream>>>(blocks, nullptr, edge_w1, H, 0, edge_b1, nullptr,
                                        nullptr, nullptr, Pb, H, 0, NBLKT, H, 0, 0);
  gemm128<<<NBLKT/32, 256, 0, stream>>>(blocks, nullptr, edge_w1 + 128*H, H, 0, nullptr,
                                        nullptr, nullptr, nullptr, Qb, H, 0, NBLKT, H, 0, 0);
  k_gather_pre<<<BSG*EBE*H/256, 256, 0, stream>>>(Pb, Qb, bedges, Epre);
  gemm128<<<BSG*EBE/32, 256, 0, stream>>>(Epre, nullptr, edge_w2, H, 0, edge_b2, nullptr,
                                          nullptr, nullptr, ef2, H, 0, BSG*EBE, H, 0, 0);
  gemm128<<<dim3(BSG*EBE/32, 3), 256, 0, stream>>>(ef2, nullptr, attn_in_w, 384, 0,
                                                   attn_in_b, nullptr, nullptr, nullptr,
                                                   qkv, 384, 0, BSG*EBE, H, 0, 128);
  k_attn4<EBE, 8><<<BSG*NHD*8*(EBE/256), 256, 0, stream>>>(qkv, part_m, part_l, part_o);
  k_attn4c<EBE, 8><<<BSG*NHD*EBE/64, 256, 0, stream>>>(part_m, part_l, part_o, ea);
  k_bsum_gather<<<NBLKT*32/256, 256, 0, stream>>>(ea, blist, boff, bsum);
  // blocks += (bsum/cnt)@out_w + out_b*[cnt>0]
  gemm128<<<NBLKT/32, 256, 0, stream>>>(bsum, nullptr, attn_out_w, H, 0, nullptr,
                                        attn_out_b, ind, blocks, blocks, H, 0, NBLKT, H, 0, 0);
  gemm128<<<dim3(NBLKT/32, 3), 256, 0, stream>>>(blocks, nullptr, attn_in_w, 384, 0,
                                                 attn_in_b, nullptr, nullptr, nullptr,
                                                 qkv, 384, 0, NBLKT, H, 0, 128);
  k_attnS<<<BSG*2, 256, 0, stream>>>(qkv, m2);
  k_final<<<BSG, 128, 0, stream>>>(m2, attn_out_w, attn_out_b, ln_g, ln_b,
                                   fin_w1, fin_b1, fin_w2, fin_b2, fin_w3, fin_b3, out);
}

// Round 19
// 586.681 us; speedup vs baseline: 1.0567x; 1.0567x over previous
//
#include <hip/hip_runtime.h>
#include <math.h>

#define H 128
#define NHD 8
#define DH 16
#define RB 6
#define NBI 2
#define BSG 16
#define LBLK 64
#define KATOM 16
#define NBLKT 1024
#define NA 16384
#define NE 262144
#define EBE 512

__device__ __forceinline__ float atomAddF(float* p, float v) {
#if defined(__gfx90a__) || defined(__gfx940__) || defined(__gfx941__) || defined(__gfx942__) || defined(__gfx950__)
  return unsafeAtomicAdd(p, v);
#else
  return atomicAdd(p, v);
#endif
}

__device__ __forceinline__ float fsilu(float v) {
  return v * __builtin_amdgcn_rcpf(1.0f + __expf(-v));
}

// ---------------- embedding ----------------
__global__ __launch_bounds__(256) void k_embed(
    const int* __restrict__ A, const int* __restrict__ apos,
    const int* __restrict__ btypes,
    const float* __restrict__ emb_atom, const float* __restrict__ emb_pos,
    const float* __restrict__ emb_block, float* __restrict__ x)
{
  int idx = blockIdx.x * 256 + threadIdx.x;   // over NA*H
  int n = idx >> 7, h = idx & 127;
  x[idx] = emb_atom[A[n] * H + h] + emb_pos[apos[n] * H + h]
         + emb_block[btypes[n >> 4] * H + h];
}

// ---------------- edge sort: histogram ----------------
__global__ __launch_bounds__(256) void k_hist(
    const int* __restrict__ ei, int* __restrict__ cnt)
{
  int e = blockIdx.x * 256 + threadIdx.x;
  atomicAdd(&cnt[ei[e]], 1);
}

// ---------------- edge sort: scan (single block, 1024 thr, 16 bins each) ----
__global__ __launch_bounds__(1024) void k_scan(
    const int* __restrict__ cnt, int* __restrict__ off,
    int* __restrict__ cur, float* __restrict__ cntf)
{
  __shared__ int ps[1024];
  int t = threadIdx.x;
  int base = t * 16;
  int local[16];
  int s = 0;
  #pragma unroll
  for (int k = 0; k < 16; ++k) { local[k] = s; s += cnt[base + k]; }
  ps[t] = s;
  __syncthreads();
  for (int d = 1; d < 1024; d <<= 1) {
    int v = (t >= d) ? ps[t - d] : 0;
    __syncthreads();
    ps[t] += v;
    __syncthreads();
  }
  int offset = (t == 0) ? 0 : ps[t - 1];
  #pragma unroll
  for (int k = 0; k < 16; ++k) {
    int o = offset + local[k];
    off[base + k] = o;
    cur[base + k] = o;
    cntf[base + k] = (float)cnt[base + k];
  }
  if (t == 1023) off[NA] = offset + s;
}

// ---------------- edge sort: scatter + fused RBF ----------------
__global__ __launch_bounds__(256) void k_scatter(
    const int* __restrict__ ei, const int* __restrict__ ej,
    const float* __restrict__ coords, const float* __restrict__ freq,
    int* __restrict__ cur, int* __restrict__ ej_s, float* __restrict__ rbf_s)
{
  int e = blockIdx.x * 256 + threadIdx.x;
  int i = ei[e], j = ej[e];
  int pos = atomicAdd(&cur[i], 1);
  ej_s[pos] = j;
  float dx = coords[i*3+0] - coords[j*3+0];
  float dy = coords[i*3+1] - coords[j*3+1];
  float dz = coords[i*3+2] - coords[j*3+2];
  float d = sqrtf(dx*dx + dy*dy + dz*dz);
  float u = fmaxf(d * 0.125f, 1e-3f);
  float u2 = u*u, u4 = u2*u2, u5 = u4*u, u6 = u5*u, u7 = u6*u;
  float env = 1.0f/u - 28.0f*u5 + 48.0f*u6 - 21.0f*u7;
  #pragma unroll
  for (int r = 0; r < RB; ++r)
    rbf_s[(size_t)pos*RB + r] = env * sinf(freq[r] * u);
}

// ---------------- block-edge CSR (per-graph src buckets) ----------------
__global__ __launch_bounds__(256) void k_bedge_csr(
    const int* __restrict__ bedges, int* __restrict__ blist,
    int* __restrict__ boff, float* __restrict__ ind)
{
  __shared__ int hist[64], offs[65], curs[64];
  int b = blockIdx.x, t = threadIdx.x;
  if (t < 64) hist[t] = 0;
  __syncthreads();
  for (int e = t; e < EBE; e += 256) atomicAdd(&hist[bedges[(b*EBE + e)*2]], 1);
  __syncthreads();
  if (t == 0) {
    offs[0] = 0;
    for (int k = 0; k < 64; ++k) offs[k+1] = offs[k] + hist[k];
  }
  __syncthreads();
  if (t < 64) curs[t] = offs[t];
  __syncthreads();
  for (int e = t; e < EBE; e += 256) {
    int src = bedges[(b*EBE + e)*2];
    int pos = atomicAdd(&curs[src], 1);
    blist[b*EBE + pos] = e;
  }
  if (t < 65) boff[b*65 + t] = offs[t];
  if (t < 64) ind[b*64 + t] = (hist[t] > 0) ? 1.0f : 0.0f;
}

// ---------------- per-atom CSR edge pass v2 (float4 channels, no atomics) ----
__global__ __launch_bounds__(256) void k_edge_csr(
    const float* __restrict__ P, const float* __restrict__ Q,
    const float* __restrict__ rbf_s, const float* __restrict__ W1c,
    const int* __restrict__ ej_s, const int* __restrict__ off,
    float* __restrict__ Hagg)
{
  __shared__ float w[RB * H];
  for (int idx = threadIdx.x; idx < RB * H; idx += 256) w[idx] = W1c[idx];
  __syncthreads();
  int c4 = threadIdx.x & 31;        // channel quad
  int sub = threadIdx.x >> 5;       // atom within block
  int i = blockIdx.x * 8 + sub;
  int e0 = off[i], e1 = off[i + 1];
  float4 pv = *(const float4*)&P[(size_t)i * H + c4 * 4];
  float4 W0 = *(const float4*)&w[0*H + c4*4];
  float4 W1 = *(const float4*)&w[1*H + c4*4];
  float4 W2 = *(const float4*)&w[2*H + c4*4];
  float4 W3 = *(const float4*)&w[3*H + c4*4];
  float4 W4 = *(const float4*)&w[4*H + c4*4];
  float4 W5 = *(const float4*)&w[5*H + c4*4];
  float4 acc = {0, 0, 0, 0};
  for (int e = e0; e < e1; ++e) {
    int j = ej_s[e];
    float4 qv = *(const float4*)&Q[(size_t)j * H + c4 * 4];
    const float* rb = &rbf_s[(size_t)e * RB];
    float r0 = rb[0], r1 = rb[1], r2 = rb[2], r3 = rb[3], r4 = rb[4], r5 = rb[5];
    float4 v;
    v.x = pv.x + qv.x + r0*W0.x + r1*W1.x + r2*W2.x + r3*W3.x + r4*W4.x + r5*W5.x;
    v.y = pv.y + qv.y + r0*W0.y + r1*W1.y + r2*W2.y + r3*W3.y + r4*W4.y + r5*W5.y;
    v.z = pv.z + qv.z + r0*W0.z + r1*W1.z + r2*W2.z + r3*W3.z + r4*W4.z + r5*W5.z;
    v.w = pv.w + qv.w + r0*W0.w + r1*W1.w + r2*W2.w + r3*W3.w + r4*W4.w + r5*W5.w;
    acc.x += fsilu(v.x);
    acc.y += fsilu(v.y);
    acc.z += fsilu(v.z);
    acc.w += fsilu(v.w);
  }
  *(float4*)&Hagg[(size_t)i * H + c4 * 4] = acc;
}

// ---------------- weight prep: wbuf = [U1a ; W2@U1b], bvec = b2@U1b ----------
__global__ __launch_bounds__(128) void k_wprep(
    const float* __restrict__ W2, const float* __restrict__ U1,
    const float* __restrict__ b2, float* __restrict__ wbuf,
    float* __restrict__ bvec)
{
  int k = blockIdx.x, c = threadIdx.x;
  const float* U1b = U1 + 128 * H;
  wbuf[k * H + c] = U1[k * H + c];
  float s = 0.0f;
  for (int t = 0; t < H; ++t) s += W2[k * H + t] * U1b[t * H + c];
  wbuf[(128 + k) * H + c] = s;
  if (k == 0) {
    float sb = 0.0f;
    for (int t = 0; t < H; ++t) sb += b2[t] * U1b[t * H + c];
    bvec[c] = sb;
  }
}

// ---------------- generic 128-col GEMM v2 + row-mode y fusion ----------------
// Column mode (ymul!=0): W col offset = y*ymul, bias col-offset, same C.
// Row mode (wrowmul!=0): W row offset = y*wrowmul, C += y*cymul, bias y==0 only.
__global__ __launch_bounds__(256) void gemm128(
    const float* __restrict__ A1, const float* __restrict__ A2,
    const float* __restrict__ W, int ldw, int wcol0,
    const float* __restrict__ bias, const float* __restrict__ bias2,
    const float* __restrict__ bias_scale,
    const float* __restrict__ res,
    float* __restrict__ C, int ldc, int ccol0,
    int M, int Ktot, int act, int ymul, int wrowmul, long long cymul)
{
  __shared__ float As[32][256];
  __shared__ float Ws[16][128];
  int tid = threadIdx.x;
  int m0 = blockIdx.x * 32;
  int yoff = blockIdx.y * ymul;
  W += (size_t)blockIdx.y * wrowmul * ldw;
  C += (size_t)blockIdx.y * cymul;
  bool doBias = (ymul != 0) || (blockIdx.y == 0);
  for (int idx = tid; idx < 32*32; idx += 256) {
    int r = idx >> 5, k4 = idx & 31;
    float4 v = *(const float4*)&A1[(size_t)(m0 + r)*H + k4*4];
    *(float4*)&As[r][k4*4] = v;
  }
  if (A2) {
    for (int idx = tid; idx < 32*32; idx += 256) {
      int r = idx >> 5, k4 = idx & 31;
      float4 v = *(const float4*)&A2[(size_t)(m0 + r)*H + k4*4];
      *(float4*)&As[r][128 + k4*4] = v;
    }
  }
  int rr = tid >> 5;    // 0..7
  int cq = tid & 31;    // col quad
  float acc[4][4] = {};
  for (int kk0 = 0; kk0 < Ktot; kk0 += 16) {
    __syncthreads();
    for (int idx = tid; idx < 16*32; idx += 256) {
      int kr = idx >> 5, c4 = idx & 31;
      float4 v = *(const float4*)&W[(size_t)(kk0 + kr)*ldw + wcol0 + yoff + c4*4];
      *(float4*)&Ws[kr][c4*4] = v;
    }
    __syncthreads();
    #pragma unroll
    for (int k4 = 0; k4 < 4; ++k4) {
      float4 w0 = *(const float4*)&Ws[k4*4+0][cq*4];
      float4 w1 = *(const float4*)&Ws[k4*4+1][cq*4];
      float4 w2 = *(const float4*)&Ws[k4*4+2][cq*4];
      float4 w3 = *(const float4*)&Ws[k4*4+3][cq*4];
      #pragma unroll
      for (int i = 0; i < 4; ++i) {
        float4 a = *(const float4*)&As[rr + 8*i][kk0 + k4*4];
        acc[i][0] += a.x*w0.x + a.y*w1.x + a.z*w2.x + a.w*w3.x;
        acc[i][1] += a.x*w0.y + a.y*w1.y + a.z*w2.y + a.w*w3.y;
        acc[i][2] += a.x*w0.z + a.y*w1.z + a.z*w2.z + a.w*w3.z;
        acc[i][3] += a.x*w0.w + a.y*w1.w + a.z*w2.w + a.w*w3.w;
      }
    }
  }
  #pragma unroll
  for (int i = 0; i < 4; ++i) {
    int m = m0 + rr + 8*i;
    float bs = bias_scale ? bias_scale[m] : 1.0f;
    float4 out;
    float* po = &out.x;
    #pragma unroll
    for (int j = 0; j < 4; ++j) {
      int c = cq*4 + j;
      float v = acc[i][j];
      if (bias && doBias) v += bias[yoff + c];
      if (bias2 && doBias) v += bias2[yoff + c] * bs;
      if (act == 1) v = fsilu(v);
      else if (act == 2) v = fmaxf(v, 0.0f);
      if (res) v += res[(size_t)m*H + c];
      po[j] = v;
    }
    *(float4*)&C[(size_t)m*ldc + ccol0 + yoff + cq*4] = out;
  }
}

// ---------------- block mean over K atoms ----------------
__global__ __launch_bounds__(256) void k_block_mean(
    const float* __restrict__ x, float* __restrict__ blocks)
{
  int idx = blockIdx.x * 256 + threadIdx.x;   // over NBLKT*H
  int nb = idx >> 7, h = idx & 127;
  float s = 0.0f;
  #pragma unroll
  for (int k = 0; k < KATOM; ++k)
    s += x[(size_t)(nb*KATOM + k)*H + h];
  blocks[idx] = s * (1.0f / KATOM);
}

// ---------------- block-edge pre-activation gather ----------------
__global__ __launch_bounds__(256) void k_gather_pre(
    const float* __restrict__ Pb, const float* __restrict__ Qb,
    const int* __restrict__ bedges, float* __restrict__ Epre)
{
  int idx = blockIdx.x * 256 + threadIdx.x;   // over BSG*EBE*H
  int row = idx >> 7, c = idx & 127;
  int g = row >> 9;
  int src = bedges[row*2], dst = bedges[row*2 + 1];
  float v = Pb[(size_t)(g*LBLK + src)*H + c] + Qb[(size_t)(g*LBLK + dst)*H + c];
  Epre[idx] = fmaxf(v, 0.0f);
}

// ---------------- MHA v7: thread-per-row, key-split, chunked online softmax ----
template <int S, int KS>
__global__ __launch_bounds__(256) void k_attn4(
    const float* __restrict__ qkv,
    float* __restrict__ pm, float* __restrict__ pl, float* __restrict__ po)
{
  constexpr int KP = S / KS;       // keys per split
  constexpr int RCH = S / 256;     // row chunks
  constexpr int NR = BSG * NHD * S;
  constexpr int CH = 32;           // score-cache chunk
  __shared__ float Ks[KP][DH];
  __shared__ float Vs[KP][DH];
  int idx = blockIdx.x;
  int rc = idx % RCH;
  int ks = (idx / RCH) % KS;
  int bh = idx / (RCH * KS);
  int b = bh >> 3, h = bh & 7;
  const float* base = qkv + (size_t)b * S * 384;
  int tid = threadIdx.x;
  for (int t = tid; t < KP * 4; t += 256) {
    int j = t >> 2, d4 = t & 3;
    int jg = ks * KP + j;
    *(float4*)&Ks[j][d4*4] = *(const float4*)(base + (size_t)jg*384 + 128 + h*DH + d4*4);
    *(float4*)&Vs[j][d4*4] = *(const float4*)(base + (size_t)jg*384 + 256 + h*DH + d4*4);
  }
  __syncthreads();
  int s = rc * 256 + tid;
  const float4* qp = (const float4*)(base + (size_t)s * 384 + h * DH);
  float4 q0 = qp[0], q1 = qp[1], q2 = qp[2], q3 = qp[3];
  float m = -1e30f, l = 0.0f;
  float4 o0 = {0,0,0,0}, o1 = {0,0,0,0}, o2 = {0,0,0,0}, o3 = {0,0,0,0};
  for (int c0 = 0; c0 < KP; c0 += CH) {
    float scv[CH];
    float mc = -1e30f;
    #pragma unroll
    for (int j = 0; j < CH; ++j) {
      float4 k0 = *(const float4*)&Ks[c0+j][0];
      float4 k1 = *(const float4*)&Ks[c0+j][4];
      float4 k2 = *(const float4*)&Ks[c0+j][8];
      float4 k3 = *(const float4*)&Ks[c0+j][12];
      float s0 = q0.x*k0.x + q0.y*k0.y + q0.z*k0.z + q0.w*k0.w;
      float s1 = q1.x*k1.x + q1.y*k1.y + q1.z*k1.z + q1.w*k1.w;
      float s2 = q2.x*k2.x + q2.y*k2.y + q2.z*k2.z + q2.w*k2.w;
      float s3 = q3.x*k3.x + q3.y*k3.y + q3.z*k3.z + q3.w*k3.w;
      float sc = (s0 + s1) + (s2 + s3);
      scv[j] = sc;
      mc = fmaxf(mc, sc);
    }
    float mn = fmaxf(m, mc);
    float corr = __expf((m - mn) * 0.25f);
    l *= corr;
    o0.x *= corr; o0.y *= corr; o0.z *= corr; o0.w *= corr;
    o1.x *= corr; o1.y *= corr; o1.z *= corr; o1.w *= corr;
    o2.x *= corr; o2.y *= corr; o2.z *= corr; o2.w *= corr;
    o3.x *= corr; o3.y *= corr; o3.z *= corr; o3.w *= corr;
    m = mn;
    #pragma unroll
    for (int j = 0; j < CH; ++j) {
      float p = __expf((scv[j] - m) * 0.25f);
      l += p;
      float4 v0 = *(const float4*)&Vs[c0+j][0];
      float4 v1 = *(const float4*)&Vs[c0+j][4];
      float4 v2 = *(const float4*)&Vs[c0+j][8];
      float4 v3 = *(const float4*)&Vs[c0+j][12];
      o0.x += p*v0.x; o0.y += p*v0.y; o0.z += p*v0.z; o0.w += p*v0.w;
      o1.x += p*v1.x; o1.y += p*v1.y; o1.z += p*v1.z; o1.w += p*v1.w;
      o2.x += p*v2.x; o2.y += p*v2.y; o2.z += p*v2.z; o2.w += p*v2.w;
      o3.x += p*v3.x; o3.y += p*v3.y; o3.z += p*v3.z; o3.w += p*v3.w;
    }
  }
  size_t R = (size_t)bh * S + s;
  pm[(size_t)ks * NR + R] = m;
  pl[(size_t)ks * NR + R] = l;
  float4* po4 = (float4*)po;
  po4[(size_t)(ks*4 + 0) * NR + R] = o0;
  po4[(size_t)(ks*4 + 1) * NR + R] = o1;
  po4[(size_t)(ks*4 + 2) * NR + R] = o2;
  po4[(size_t)(ks*4 + 3) * NR + R] = o3;
}

// combine KS partials per row (4 threads/row, d4 wave-uniform), write normalized ea
template <int S, int KS>
__global__ __launch_bounds__(256) void k_attn4c(
    const float* __restrict__ pm, const float* __restrict__ pl,
    const float* __restrict__ po, float* __restrict__ ea)
{
  constexpr int NR = BSG * NHD * S;
  int R = blockIdx.x * 64 + (threadIdx.x & 63);
  int d4 = threadIdx.x >> 6;   // wave-uniform
  float mv[KS];
  float m = -1e30f;
  #pragma unroll
  for (int k = 0; k < KS; ++k) { mv[k] = pm[(size_t)k*NR + R]; m = fmaxf(m, mv[k]); }
  const float4* po4 = (const float4*)po;
  float l = 0.0f;
  float4 o = {0, 0, 0, 0};
  #pragma unroll
  for (int k = 0; k < KS; ++k) {
    float w = __expf((mv[k] - m) * 0.25f);
    l += pl[(size_t)k*NR + R] * w;
    float4 p = po4[(size_t)(k*4 + d4)*NR + R];
    o.x += p.x*w; o.y += p.y*w; o.z += p.z*w; o.w += p.w*w;
  }
  float inv = 1.0f / l;
  float4 r = {o.x*inv, o.y*inv, o.z*inv, o.w*inv};
  ((float4*)ea)[(size_t)d4*NR + R] = r;
}

// gather ea rows per (block, channel) via block-edge CSR; divide by cnt
__global__ __launch_bounds__(256) void k_bsum_gather(
    const float* __restrict__ ea, const int* __restrict__ blist,
    const int* __restrict__ boff, float* __restrict__ bsum)
{
  constexpr int NR = BSG * NHD * EBE;
  int idx = blockIdx.x * 256 + threadIdx.x;   // over NBLKT*32
  int i = idx >> 5, c4 = idx & 31;
  int b = i >> 6, blk = i & 63;
  int h = c4 >> 2, d4 = c4 & 3;
  int e0 = boff[b*65 + blk], e1 = boff[b*65 + blk + 1];
  const float4* ea4 = (const float4*)ea;
  size_t basein = (size_t)d4 * NR + (size_t)(b*NHD + h) * EBE;
  float4 s = {0, 0, 0, 0};
  for (int e = e0; e < e1; ++e) {
    int srow = blist[b*EBE + e];
    float4 v = ea4[basein + srow];
    s.x += v.x; s.y += v.y; s.z += v.z; s.w += v.w;
  }
  float cnt = (float)(e1 - e0);
  float sc = (cnt > 0.0f) ? (1.0f / cnt) : 0.0f;
  float4 o = {s.x*sc, s.y*sc, s.z*sc, s.w*sc};
  *(float4*)&bsum[(size_t)i*H + c4*4] = o;
}

// ---------------- block self-attention: LDS K/V, wave-reduced mean, NO atomics ----
__global__ __launch_bounds__(256) void k_attnS(
    const float* __restrict__ qkv, float* __restrict__ m2)
{
  __shared__ float Ks[4][LBLK][DH];
  __shared__ float Vs[4][LBLK][DH];
  __shared__ float red[4][LBLK][DH + 1];   // pad 17: odd stride -> conflict-free
  int b = blockIdx.x >> 1, hq = blockIdx.x & 1;
  int tid = threadIdx.x;
  const float* base = qkv + (size_t)b * LBLK * 384;
  for (int t = tid; t < 1024; t += 256) {
    int hl = t >> 8, j = (t >> 2) & 63, d4 = t & 3;
    int h = hq*4 + hl;
    *(float4*)&Ks[hl][j][d4*4] = *(const float4*)(base + (size_t)j*384 + 128 + h*DH + d4*4);
    *(float4*)&Vs[hl][j][d4*4] = *(const float4*)(base + (size_t)j*384 + 256 + h*DH + d4*4);
  }
  __syncthreads();
  int hl = tid >> 6, s = tid & 63;   // hl uniform per wave; wave owns (b, h)
  int h = hq*4 + hl;
  const float4* qp = (const float4*)(base + (size_t)s * 384 + h * DH);
  float4 q0 = qp[0], q1 = qp[1], q2 = qp[2], q3 = qp[3];
  float m = -1e30f, l = 0.0f;
  float4 o0 = {0,0,0,0}, o1 = {0,0,0,0}, o2 = {0,0,0,0}, o3 = {0,0,0,0};
  for (int c0 = 0; c0 < LBLK; c0 += 32) {
    float scv[32];
    float mc = -1e30f;
    #pragma unroll
    for (int j = 0; j < 32; ++j) {
      float4 k0 = *(const float4*)&Ks[hl][c0+j][0];
      float4 k1 = *(const float4*)&Ks[hl][c0+j][4];
      float4 k2 = *(const float4*)&Ks[hl][c0+j][8];
      float4 k3 = *(const float4*)&Ks[hl][c0+j][12];
      float s0 = q0.x*k0.x + q0.y*k0.y + q0.z*k0.z + q0.w*k0.w;
      float s1 = q1.x*k1.x + q1.y*k1.y + q1.z*k1.z + q1.w*k1.w;
      float s2 = q2.x*k2.x + q2.y*k2.y + q2.z*k2.z + q2.w*k2.w;
      float s3 = q3.x*k3.x + q3.y*k3.y + q3.z*k3.z + q3.w*k3.w;
      float sc = (s0 + s1) + (s2 + s3);
      scv[j] = sc;
      mc = fmaxf(mc, sc);
    }
    float mn = fmaxf(m, mc);
    float corr = __expf((m - mn) * 0.25f);
    l *= corr;
    o0.x *= corr; o0.y *= corr; o0.z *= corr; o0.w *= corr;
    o1.x *= corr; o1.y *= corr; o1.z *= corr; o1.w *= corr;
    o2.x *= corr; o2.y *= corr; o2.z *= corr; o2.w *= corr;
    o3.x *= corr; o3.y *= corr; o3.z *= corr; o3.w *= corr;
    m = mn;
    #pragma unroll
    for (int j = 0; j < 32; ++j) {
      float p = __expf((scv[j] - m) * 0.25f);
      l += p;
      float4 v0 = *(const float4*)&Vs[hl][c0+j][0];
      float4 v1 = *(const float4*)&Vs[hl][c0+j][4];
      float4 v2 = *(const float4*)&Vs[hl][c0+j][8];
      float4 v3 = *(const float4*)&Vs[hl][c0+j][12];
      o0.x += p*v0.x; o0.y += p*v0.y; o0.z += p*v0.z; o0.w += p*v0.w;
      o1.x += p*v1.x; o1.y += p*v1.y; o1.z += p*v1.z; o1.w += p*v1.w;
      o2.x += p*v2.x; o2.y += p*v2.y; o2.z += p*v2.z; o2.w += p*v2.w;
      o3.x += p*v3.x; o3.y += p*v3.y; o3.z += p*v3.z; o3.w += p*v3.w;
    }
  }
  // normalize this row's output and stash in LDS (17-stride, conflict-free)
  float inv = (1.0f / l) * (1.0f / 64.0f);
  float ov[DH] = {o0.x,o0.y,o0.z,o0.w, o1.x,o1.y,o1.z,o1.w,
                  o2.x,o2.y,o2.z,o2.w, o3.x,o3.y,o3.z,o3.w};
  #pragma unroll
  for (int d = 0; d < DH; ++d) red[hl][s][d] = ov[d] * inv;
  __syncthreads();
  // wave owns (b,h): lanes 0..15 sum the 64 rows, plain store (no atomics)
  if (s < DH) {
    float acc = 0.0f;
    for (int r = 0; r < LBLK; ++r) acc += red[hl][r][s];
    m2[(size_t)b * H + h * DH + s] = acc;
  }
}

// ---------------- final: out-proj + LN + 3-layer MLP ----------------
__device__ __forceinline__ float bsum128(float v, float* red) {
  int t = threadIdx.x;
  red[t] = v; __syncthreads();
  #pragma unroll
  for (int off = 64; off > 0; off >>= 1) {
    if (t < off) red[t] += red[t + off];
    __syncthreads();
  }
  float s = red[0];
  __syncthreads();
  return s;
}

__global__ __launch_bounds__(128) void k_final(
    const float* __restrict__ m2, const float* __restrict__ out_w,
    const float* __restrict__ out_b, const float* __restrict__ lng,
    const float* __restrict__ lnb, const float* __restrict__ w1,
    const float* __restrict__ b1, const float* __restrict__ w2,
    const float* __restrict__ b2, const float* __restrict__ w3,
    const float* __restrict__ b3, float* __restrict__ out)
{
  __shared__ float buf[128];
  __shared__ float red[128];
  int b = blockIdx.x, t = threadIdx.x;
  buf[t] = m2[b*H + t];
  __syncthreads();
  float g = out_b[t];
  for (int k = 0; k < H; ++k) g += buf[k] * out_w[k*H + t];
  float mu = bsum128(g, red) * (1.0f / H);
  float df = g - mu;
  float var = bsum128(df * df, red) * (1.0f / H);
  float gn = df / sqrtf(var + 1e-5f) * lng[t] + lnb[t];
  __syncthreads();
  buf[t] = gn; __syncthreads();
  float h1 = b1[t];
  for (int k = 0; k < H; ++k) h1 += buf[k] * w1[k*H + t];
  h1 = fmaxf(h1, 0.0f);
  __syncthreads();
  buf[t] = h1; __syncthreads();
  float h2 = b2[t];
  for (int k = 0; k < H; ++k) h2 += buf[k] * w2[k*H + t];
  h2 = fmaxf(h2, 0.0f);
  float tot = bsum128(h2 * w3[t], red);
  if (t == 0) out[b] = tot + b3[0];
}

extern "C" void kernel_launch(void* const* d_in, const int* in_sizes, int n_in,
                              void* d_out, int out_size, void* d_ws, size_t ws_size,
                              hipStream_t stream) {
  (void)in_sizes; (void)n_in; (void)out_size; (void)ws_size;
  const int*   A          = (const int*)d_in[0];
  const int*   apos       = (const int*)d_in[1];
  const int*   btypes     = (const int*)d_in[2];
  const float* coords     = (const float*)d_in[3];
  const int*   edge_index = (const int*)d_in[4];
  const int*   bedges     = (const int*)d_in[5];
  const float* emb_atom   = (const float*)d_in[6];
  const float* emb_pos    = (const float*)d_in[7];
  const float* emb_block  = (const float*)d_in[8];
  const float* rbf_freq   = (const float*)d_in[9];
  const float* inter_w1   = (const float*)d_in[10];
  const float* inter_b1   = (const float*)d_in[11];
  const float* inter_w2   = (const float*)d_in[12];
  const float* inter_b2   = (const float*)d_in[13];
  const float* upd_w1     = (const float*)d_in[14];
  const float* upd_b1     = (const float*)d_in[15];
  const float* upd_w2     = (const float*)d_in[16];
  const float* upd_b2     = (const float*)d_in[17];
  const float* edge_w1    = (const float*)d_in[18];
  const float* edge_b1    = (const float*)d_in[19];
  const float* edge_w2    = (const float*)d_in[20];
  const float* edge_b2    = (const float*)d_in[21];
  const float* attn_in_w  = (const float*)d_in[22];
  const float* attn_in_b  = (const float*)d_in[23];
  const float* attn_out_w = (const float*)d_in[24];
  const float* attn_out_b = (const float*)d_in[25];
  const float* ln_g       = (const float*)d_in[26];
  const float* ln_b       = (const float*)d_in[27];
  const float* fin_w1     = (const float*)d_in[28];
  const float* fin_b1     = (const float*)d_in[29];
  const float* fin_w2     = (const float*)d_in[30];
  const float* fin_b2     = (const float*)d_in[31];
  const float* fin_w3     = (const float*)d_in[32];
  const float* fin_b3     = (const float*)d_in[33];
  float* out = (float*)d_out;

  float* ws = (float*)d_ws;
  float* x      = ws + 0;
  float* P      = ws + 2097152;
  float* Q      = ws + 4194304;
  float* Hagg   = ws + 6291456;
  float* rbf_s  = ws + 8388608;    // E*6 (sorted RBF)
  float* cntf   = ws + 9961472;    // NA
  float* blocks = ws + 9977856;    // NBLKT*H
  float* Pb     = ws + 10108928;
  float* Qb     = ws + 10240000;
  float* Epre   = ws + 10371072;   // BSG*EBE*H (sort scratch early; ea late)
  float* ef2    = ws + 11419648;
  float* qkv    = ws + 12468224;   // BSG*EBE*384
  float* bsum   = ws + 15613952;   // NBLKT*H
  float* ind    = ws + 15746048;   // NBLKT
  float* m2     = ws + 15747072;   // BSG*H
  int* blist    = (int*)(ws + 15749120);  // BSG*EBE ints
  int* boff     = (int*)(ws + 15757312);  // BSG*65 ints
  // sort scratch + wprep live in Epre region (dead until block-attention phase):
  int* ej_s   = (int*)(ws + 10371072);          // NE ints
  int* off    = (int*)(ws + 10371072 + 262144); // NA+1 ints
  int* cur    = (int*)(ws + 10371072 + 278784); // NA ints
  int* cnt    = (int*)(ws + 10371072 + 295168); // NA ints
  float* wbuf = ws + 10371072 + 311552;         // 256*128 floats
  float* bvec = ws + 10371072 + 344320;         // 128 floats
  // attention partials (KS=8, split-major) reuse x/P/Q/Hagg/rbf_s regions:
  float* part_m = ws + 0;          // 8*65536 = 524288 floats
  float* part_l = ws + 524288;     // 524288 floats
  float* part_o = ws + 1048576;    // 8*65536*16 = 8388608 floats -> ends 9437184
  float* ea     = ws + 10371072;   // 65536*16 = 1048576 floats (Epre region, d4-major)

  const int* ei = edge_index;
  const int* ej = edge_index + NE;

  // ---- edge sort (once; reused by both interaction blocks) ----
  (void)hipMemsetAsync(cnt, 0, NA * sizeof(int), stream);
  k_hist<<<NE/256, 256, 0, stream>>>(ei, cnt);
  k_scan<<<1, 1024, 0, stream>>>(cnt, off, cur, cntf);
  k_scatter<<<NE/256, 256, 0, stream>>>(ei, ej, coords, rbf_freq, cur, ej_s, rbf_s);
  k_bedge_csr<<<BSG, 256, 0, stream>>>(bedges, blist, boff, ind);

  k_embed<<<NA*H/256, 256, 0, stream>>>(A, apos, btypes, emb_atom, emb_pos, emb_block, x);

  for (int b = 0; b < NBI; ++b) {
    const float* w1 = inter_w1 + (size_t)b * 262 * H;
    k_wprep<<<128, 128, 0, stream>>>(inter_w2 + (size_t)b*H*H, upd_w1 + (size_t)b*2*H*H,
                                     inter_b2 + b*H, wbuf, bvec);
    // fused: P = x@W1a + b1 (y=0) ; Q = x@W1b (y=1, no bias)
    gemm128<<<dim3(NA/32, 2), 256, 0, stream>>>(x, nullptr, w1, H, 0, inter_b1 + b*H,
                                                nullptr, nullptr, nullptr,
                                                P, H, 0, NA, H, 0, 0, 128, 2097152);
    k_edge_csr<<<NA/8, 256, 0, stream>>>(P, Q, rbf_s, w1 + 256*H, ej_s, off, Hagg);
    // U = silu(x@U1a + Hagg@W2' + b1 + cnt*bvec) -> into Q  (agg-gemm folded in)
    gemm128<<<NA/32, 256, 0, stream>>>(x, Hagg, wbuf, H, 0, upd_b1 + b*H, bvec,
                                       cntf, nullptr, Q, H, 0, NA, 2*H, 1, 0, 0, 0);
    // x = U@upd_w2 + b2 + x
    gemm128<<<NA/32, 256, 0, stream>>>(Q, nullptr, upd_w2 + (size_t)b*H*H, H, 0,
                                       upd_b2 + b*H, nullptr, nullptr, x, x, H, 0,
                                       NA, H, 0, 0, 0, 0);
  }

  k_block_mean<<<NBLKT*H/256, 256, 0, stream>>>(x, blocks);
  // fused: Pb = blocks@edge_w1a + b (y=0) ; Qb = blocks@edge_w1b (y=1)
  gemm128<<<dim3(NBLKT/32, 2), 256, 0, stream>>>(blocks, nullptr, edge_w1, H, 0, edge_b1,
                                                 nullptr, nullptr, nullptr,
                                                 Pb, H, 0, NBLKT, H, 0, 0, 128, 131072);
  k_gather_pre<<<BSG*EBE*H/256, 256, 0, stream>>>(Pb, Qb, bedges, Epre);
  gemm128<<<BSG*EBE/32, 256, 0, stream>>>(Epre, nullptr, edge_w2, H, 0, edge_b2, nullptr,
                                          nullptr, nullptr, ef2, H, 0, BSG*EBE, H, 0,
                                          0, 0, 0);
  gemm128<<<dim3(BSG*EBE/32, 3), 256, 0, stream>>>(ef2, nullptr, attn_in_w, 384, 0,
                                                   attn_in_b, nullptr, nullptr, nullptr,
                                                   qkv, 384, 0, BSG*EBE, H, 0, 128, 0, 0);
  k_attn4<EBE, 8><<<BSG*NHD*8*(EBE/256), 256, 0, stream>>>(qkv, part_m, part_l, part_o);
  k_attn4c<EBE, 8><<<BSG*NHD*EBE/64, 256, 0, stream>>>(part_m, part_l, part_o, ea);
  k_bsum_gather<<<NBLKT*32/256, 256, 0, stream>>>(ea, blist, boff, bsum);
  // blocks += (bsum/cnt)@out_w + out_b*[cnt>0]
  gemm128<<<NBLKT/32, 256, 0, stream>>>(bsum, nullptr, attn_out_w, H, 0, nullptr,
                                        attn_out_b, ind, blocks, blocks, H, 0,
                                        NBLKT, H, 0, 0, 0, 0);
  gemm128<<<dim3(NBLKT/32, 3), 256, 0, stream>>>(blocks, nullptr, attn_in_w, 384, 0,
                                                 attn_in_b, nullptr, nullptr, nullptr,
                                                 qkv, 384, 0, NBLKT, H, 0, 128, 0, 0);
  k_attnS<<<BSG*2, 256, 0, stream>>>(qkv, m2);
  k_final<<<BSG, 128, 0, stream>>>(m2, attn_out_w, attn_out_b, ln_g, ln_b,
                                   fin_w1, fin_b1, fin_w2, fin_b2, fin_w3, fin_b3, out);
}

// Round 20
// 556.809 us; speedup vs baseline: 1.1134x; 1.0536x over previous
//
#include <hip/hip_runtime.h>
#include <math.h>

#define H 128
#define NHD 8
#define DH 16
#define RB 6
#define NBI 2
#define BSG 16
#define LBLK 64
#define KATOM 16
#define NBLKT 1024
#define NA 16384
#define NE 262144
#define EBE 512

__device__ __forceinline__ float atomAddF(float* p, float v) {
#if defined(__gfx90a__) || defined(__gfx940__) || defined(__gfx941__) || defined(__gfx942__) || defined(__gfx950__)
  return unsafeAtomicAdd(p, v);
#else
  return atomicAdd(p, v);
#endif
}

__device__ __forceinline__ float fsilu(float v) {
  return v * __builtin_amdgcn_rcpf(1.0f + __expf(-v));
}

// ---------------- embedding ----------------
__global__ __launch_bounds__(256) void k_embed(
    const int* __restrict__ A, const int* __restrict__ apos,
    const int* __restrict__ btypes,
    const float* __restrict__ emb_atom, const float* __restrict__ emb_pos,
    const float* __restrict__ emb_block, float* __restrict__ x)
{
  int idx = blockIdx.x * 256 + threadIdx.x;   // over NA*H
  int n = idx >> 7, h = idx & 127;
  x[idx] = emb_atom[A[n] * H + h] + emb_pos[apos[n] * H + h]
         + emb_block[btypes[n >> 4] * H + h];
}

// ---------------- edge sort: histogram ----------------
__global__ __launch_bounds__(256) void k_hist(
    const int* __restrict__ ei, int* __restrict__ cnt)
{
  int e = blockIdx.x * 256 + threadIdx.x;
  atomicAdd(&cnt[ei[e]], 1);
}

// ---------------- edge sort: scan (single block, 1024 thr, 16 bins each) ----
__global__ __launch_bounds__(1024) void k_scan(
    const int* __restrict__ cnt, int* __restrict__ off,
    int* __restrict__ cur, float* __restrict__ cntf)
{
  __shared__ int ps[1024];
  int t = threadIdx.x;
  int base = t * 16;
  int local[16];
  int s = 0;
  #pragma unroll
  for (int k = 0; k < 16; ++k) { local[k] = s; s += cnt[base + k]; }
  ps[t] = s;
  __syncthreads();
  for (int d = 1; d < 1024; d <<= 1) {
    int v = (t >= d) ? ps[t - d] : 0;
    __syncthreads();
    ps[t] += v;
    __syncthreads();
  }
  int offset = (t == 0) ? 0 : ps[t - 1];
  #pragma unroll
  for (int k = 0; k < 16; ++k) {
    int o = offset + local[k];
    off[base + k] = o;
    cur[base + k] = o;
    cntf[base + k] = (float)cnt[base + k];
  }
  if (t == 1023) off[NA] = offset + s;
}

// ---------------- edge sort: scatter + fused RBF ----------------
__global__ __launch_bounds__(256) void k_scatter(
    const int* __restrict__ ei, const int* __restrict__ ej,
    const float* __restrict__ coords, const float* __restrict__ freq,
    int* __restrict__ cur, int* __restrict__ ej_s, float* __restrict__ rbf_s)
{
  int e = blockIdx.x * 256 + threadIdx.x;
  int i = ei[e], j = ej[e];
  int pos = atomicAdd(&cur[i], 1);
  ej_s[pos] = j;
  float dx = coords[i*3+0] - coords[j*3+0];
  float dy = coords[i*3+1] - coords[j*3+1];
  float dz = coords[i*3+2] - coords[j*3+2];
  float d = sqrtf(dx*dx + dy*dy + dz*dz);
  float u = fmaxf(d * 0.125f, 1e-3f);
  float u2 = u*u, u4 = u2*u2, u5 = u4*u, u6 = u5*u, u7 = u6*u;
  float env = 1.0f/u - 28.0f*u5 + 48.0f*u6 - 21.0f*u7;
  #pragma unroll
  for (int r = 0; r < RB; ++r)
    rbf_s[(size_t)pos*RB + r] = env * sinf(freq[r] * u);
}

// ---------------- block-edge CSR (per-graph src buckets) ----------------
__global__ __launch_bounds__(256) void k_bedge_csr(
    const int* __restrict__ bedges, int* __restrict__ blist,
    int* __restrict__ boff, float* __restrict__ ind)
{
  __shared__ int hist[64], offs[65], curs[64];
  int b = blockIdx.x, t = threadIdx.x;
  if (t < 64) hist[t] = 0;
  __syncthreads();
  for (int e = t; e < EBE; e += 256) atomicAdd(&hist[bedges[(b*EBE + e)*2]], 1);
  __syncthreads();
  if (t == 0) {
    offs[0] = 0;
    for (int k = 0; k < 64; ++k) offs[k+1] = offs[k] + hist[k];
  }
  __syncthreads();
  if (t < 64) curs[t] = offs[t];
  __syncthreads();
  for (int e = t; e < EBE; e += 256) {
    int src = bedges[(b*EBE + e)*2];
    int pos = atomicAdd(&curs[src], 1);
    blist[b*EBE + pos] = e;
  }
  if (t < 65) boff[b*65 + t] = offs[t];
  if (t < 64) ind[b*64 + t] = (hist[t] > 0) ? 1.0f : 0.0f;
}

// ---------------- per-atom CSR edge pass v2 (float4 channels, no atomics) ----
__global__ __launch_bounds__(256) void k_edge_csr(
    const float* __restrict__ P, const float* __restrict__ Q,
    const float* __restrict__ rbf_s, const float* __restrict__ W1c,
    const int* __restrict__ ej_s, const int* __restrict__ off,
    float* __restrict__ Hagg)
{
  __shared__ float w[RB * H];
  for (int idx = threadIdx.x; idx < RB * H; idx += 256) w[idx] = W1c[idx];
  __syncthreads();
  int c4 = threadIdx.x & 31;        // channel quad
  int sub = threadIdx.x >> 5;       // atom within block
  int i = blockIdx.x * 8 + sub;
  int e0 = off[i], e1 = off[i + 1];
  float4 pv = *(const float4*)&P[(size_t)i * H + c4 * 4];
  float4 W0 = *(const float4*)&w[0*H + c4*4];
  float4 W1 = *(const float4*)&w[1*H + c4*4];
  float4 W2 = *(const float4*)&w[2*H + c4*4];
  float4 W3 = *(const float4*)&w[3*H + c4*4];
  float4 W4 = *(const float4*)&w[4*H + c4*4];
  float4 W5 = *(const float4*)&w[5*H + c4*4];
  float4 acc = {0, 0, 0, 0};
  for (int e = e0; e < e1; ++e) {
    int j = ej_s[e];
    float4 qv = *(const float4*)&Q[(size_t)j * H + c4 * 4];
    const float* rb = &rbf_s[(size_t)e * RB];
    float r0 = rb[0], r1 = rb[1], r2 = rb[2], r3 = rb[3], r4 = rb[4], r5 = rb[5];
    float4 v;
    v.x = pv.x + qv.x + r0*W0.x + r1*W1.x + r2*W2.x + r3*W3.x + r4*W4.x + r5*W5.x;
    v.y = pv.y + qv.y + r0*W0.y + r1*W1.y + r2*W2.y + r3*W3.y + r4*W4.y + r5*W5.y;
    v.z = pv.z + qv.z + r0*W0.z + r1*W1.z + r2*W2.z + r3*W3.z + r4*W4.z + r5*W5.z;
    v.w = pv.w + qv.w + r0*W0.w + r1*W1.w + r2*W2.w + r3*W3.w + r4*W4.w + r5*W5.w;
    acc.x += fsilu(v.x);
    acc.y += fsilu(v.y);
    acc.z += fsilu(v.z);
    acc.w += fsilu(v.w);
  }
  *(float4*)&Hagg[(size_t)i * H + c4 * 4] = acc;
}

// ---------------- weight prep: wbuf = [U1a ; W2@U1b], bvec = b2@U1b ----------
__global__ __launch_bounds__(128) void k_wprep(
    const float* __restrict__ W2, const float* __restrict__ U1,
    const float* __restrict__ b2, float* __restrict__ wbuf,
    float* __restrict__ bvec)
{
  int k = blockIdx.x, c = threadIdx.x;
  const float* U1b = U1 + 128 * H;
  wbuf[k * H + c] = U1[k * H + c];
  float s = 0.0f;
  for (int t = 0; t < H; ++t) s += W2[k * H + t] * U1b[t * H + c];
  wbuf[(128 + k) * H + c] = s;
  if (k == 0) {
    float sb = 0.0f;
    for (int t = 0; t < H; ++t) sb += b2[t] * U1b[t * H + c];
    bvec[c] = sb;
  }
}

// ---------------- generic 128-col GEMM v2 + row-mode y fusion ----------------
__global__ __launch_bounds__(256) void gemm128(
    const float* __restrict__ A1, const float* __restrict__ A2,
    const float* __restrict__ W, int ldw, int wcol0,
    const float* __restrict__ bias, const float* __restrict__ bias2,
    const float* __restrict__ bias_scale,
    const float* __restrict__ res,
    float* __restrict__ C, int ldc, int ccol0,
    int M, int Ktot, int act, int ymul, int wrowmul, long long cymul)
{
  __shared__ float As[32][256];
  __shared__ float Ws[16][128];
  int tid = threadIdx.x;
  int m0 = blockIdx.x * 32;
  int yoff = blockIdx.y * ymul;
  W += (size_t)blockIdx.y * wrowmul * ldw;
  C += (size_t)blockIdx.y * cymul;
  bool doBias = (ymul != 0) || (blockIdx.y == 0);
  for (int idx = tid; idx < 32*32; idx += 256) {
    int r = idx >> 5, k4 = idx & 31;
    float4 v = *(const float4*)&A1[(size_t)(m0 + r)*H + k4*4];
    *(float4*)&As[r][k4*4] = v;
  }
  if (A2) {
    for (int idx = tid; idx < 32*32; idx += 256) {
      int r = idx >> 5, k4 = idx & 31;
      float4 v = *(const float4*)&A2[(size_t)(m0 + r)*H + k4*4];
      *(float4*)&As[r][128 + k4*4] = v;
    }
  }
  int rr = tid >> 5;    // 0..7
  int cq = tid & 31;    // col quad
  float acc[4][4] = {};
  for (int kk0 = 0; kk0 < Ktot; kk0 += 16) {
    __syncthreads();
    for (int idx = tid; idx < 16*32; idx += 256) {
      int kr = idx >> 5, c4 = idx & 31;
      float4 v = *(const float4*)&W[(size_t)(kk0 + kr)*ldw + wcol0 + yoff + c4*4];
      *(float4*)&Ws[kr][c4*4] = v;
    }
    __syncthreads();
    #pragma unroll
    for (int k4 = 0; k4 < 4; ++k4) {
      float4 w0 = *(const float4*)&Ws[k4*4+0][cq*4];
      float4 w1 = *(const float4*)&Ws[k4*4+1][cq*4];
      float4 w2 = *(const float4*)&Ws[k4*4+2][cq*4];
      float4 w3 = *(const float4*)&Ws[k4*4+3][cq*4];
      #pragma unroll
      for (int i = 0; i < 4; ++i) {
        float4 a = *(const float4*)&As[rr + 8*i][kk0 + k4*4];
        acc[i][0] += a.x*w0.x + a.y*w1.x + a.z*w2.x + a.w*w3.x;
        acc[i][1] += a.x*w0.y + a.y*w1.y + a.z*w2.y + a.w*w3.y;
        acc[i][2] += a.x*w0.z + a.y*w1.z + a.z*w2.z + a.w*w3.z;
        acc[i][3] += a.x*w0.w + a.y*w1.w + a.z*w2.w + a.w*w3.w;
      }
    }
  }
  #pragma unroll
  for (int i = 0; i < 4; ++i) {
    int m = m0 + rr + 8*i;
    float bs = bias_scale ? bias_scale[m] : 1.0f;
    float4 out;
    float* po = &out.x;
    #pragma unroll
    for (int j = 0; j < 4; ++j) {
      int c = cq*4 + j;
      float v = acc[i][j];
      if (bias && doBias) v += bias[yoff + c];
      if (bias2 && doBias) v += bias2[yoff + c] * bs;
      if (act == 1) v = fsilu(v);
      else if (act == 2) v = fmaxf(v, 0.0f);
      if (res) v += res[(size_t)m*H + c];
      po[j] = v;
    }
    *(float4*)&C[(size_t)m*ldc + ccol0 + yoff + cq*4] = out;
  }
}

// ---------------- chained update: U = silu([x|Hagg]@W1 + b1 + cnt*bvec);
//                  xout = U@W2 + b2 + x  (one kernel, U stays in LDS) --------
__global__ __launch_bounds__(256) void k_upd_chain(
    const float* __restrict__ x, const float* __restrict__ Hagg,
    const float* __restrict__ W1,    // wbuf [256][128]
    const float* __restrict__ b1, const float* __restrict__ bvec,
    const float* __restrict__ cntf,
    const float* __restrict__ W2,    // upd_w2 [128][128]
    const float* __restrict__ b2,
    float* __restrict__ xout)
{
  __shared__ float As[32][256];   // 32 KB
  __shared__ float Ws[16][128];   // 8 KB
  __shared__ float Us[32][128];   // 16 KB  -> 56 KB total, 2 blocks/CU
  int tid = threadIdx.x;
  int m0 = blockIdx.x * 32;
  for (int idx = tid; idx < 32*32; idx += 256) {
    int r = idx >> 5, k4 = idx & 31;
    *(float4*)&As[r][k4*4] = *(const float4*)&x[(size_t)(m0 + r)*H + k4*4];
    *(float4*)&As[r][128 + k4*4] = *(const float4*)&Hagg[(size_t)(m0 + r)*H + k4*4];
  }
  int rr = tid >> 5;    // 0..7
  int cq = tid & 31;    // col quad
  float acc[4][4] = {};
  // stage 1: K=256 over [x|Hagg] with W1 (identical structure to gemm128 v2)
  for (int kk0 = 0; kk0 < 256; kk0 += 16) {
    __syncthreads();
    for (int idx = tid; idx < 16*32; idx += 256) {
      int kr = idx >> 5, c4 = idx & 31;
      *(float4*)&Ws[kr][c4*4] = *(const float4*)&W1[(size_t)(kk0 + kr)*H + c4*4];
    }
    __syncthreads();
    #pragma unroll
    for (int k4 = 0; k4 < 4; ++k4) {
      float4 w0 = *(const float4*)&Ws[k4*4+0][cq*4];
      float4 w1 = *(const float4*)&Ws[k4*4+1][cq*4];
      float4 w2 = *(const float4*)&Ws[k4*4+2][cq*4];
      float4 w3 = *(const float4*)&Ws[k4*4+3][cq*4];
      #pragma unroll
      for (int i = 0; i < 4; ++i) {
        float4 a = *(const float4*)&As[rr + 8*i][kk0 + k4*4];
        acc[i][0] += a.x*w0.x + a.y*w1.x + a.z*w2.x + a.w*w3.x;
        acc[i][1] += a.x*w0.y + a.y*w1.y + a.z*w2.y + a.w*w3.y;
        acc[i][2] += a.x*w0.z + a.y*w1.z + a.z*w2.z + a.w*w3.z;
        acc[i][3] += a.x*w0.w + a.y*w1.w + a.z*w2.w + a.w*w3.w;
      }
    }
  }
  // epilogue 1 -> Us (silu), matching old order: +b1, +bvec*cnt, silu
  #pragma unroll
  for (int i = 0; i < 4; ++i) {
    int m = m0 + rr + 8*i;
    float bs = cntf[m];
    float4 u;
    float* pu = &u.x;
    #pragma unroll
    for (int j = 0; j < 4; ++j) {
      int c = cq*4 + j;
      float v = acc[i][j] + b1[c] + bvec[c] * bs;
      pu[j] = fsilu(v);
    }
    *(float4*)&Us[rr + 8*i][cq*4] = u;
    acc[i][0] = 0.0f; acc[i][1] = 0.0f; acc[i][2] = 0.0f; acc[i][3] = 0.0f;
  }
  // stage 2: K=128 over Us with W2
  for (int kk0 = 0; kk0 < 128; kk0 += 16) {
    __syncthreads();
    for (int idx = tid; idx < 16*32; idx += 256) {
      int kr = idx >> 5, c4 = idx & 31;
      *(float4*)&Ws[kr][c4*4] = *(const float4*)&W2[(size_t)(kk0 + kr)*H + c4*4];
    }
    __syncthreads();
    #pragma unroll
    for (int k4 = 0; k4 < 4; ++k4) {
      float4 w0 = *(const float4*)&Ws[k4*4+0][cq*4];
      float4 w1 = *(const float4*)&Ws[k4*4+1][cq*4];
      float4 w2 = *(const float4*)&Ws[k4*4+2][cq*4];
      float4 w3 = *(const float4*)&Ws[k4*4+3][cq*4];
      #pragma unroll
      for (int i = 0; i < 4; ++i) {
        float4 a = *(const float4*)&Us[rr + 8*i][kk0 + k4*4];
        acc[i][0] += a.x*w0.x + a.y*w1.x + a.z*w2.x + a.w*w3.x;
        acc[i][1] += a.x*w0.y + a.y*w1.y + a.z*w2.y + a.w*w3.y;
        acc[i][2] += a.x*w0.z + a.y*w1.z + a.z*w2.z + a.w*w3.z;
        acc[i][3] += a.x*w0.w + a.y*w1.w + a.z*w2.w + a.w*w3.w;
      }
    }
  }
  // epilogue 2: + b2 + x (residual), store
  #pragma unroll
  for (int i = 0; i < 4; ++i) {
    int m = m0 + rr + 8*i;
    float4 out;
    float* po = &out.x;
    #pragma unroll
    for (int j = 0; j < 4; ++j) {
      int c = cq*4 + j;
      po[j] = acc[i][j] + b2[c] + x[(size_t)m*H + c];
    }
    *(float4*)&xout[(size_t)m*H + cq*4] = out;
  }
}

// ---------------- block mean over K atoms ----------------
__global__ __launch_bounds__(256) void k_block_mean(
    const float* __restrict__ x, float* __restrict__ blocks)
{
  int idx = blockIdx.x * 256 + threadIdx.x;   // over NBLKT*H
  int nb = idx >> 7, h = idx & 127;
  float s = 0.0f;
  #pragma unroll
  for (int k = 0; k < KATOM; ++k)
    s += x[(size_t)(nb*KATOM + k)*H + h];
  blocks[idx] = s * (1.0f / KATOM);
}

// ---------------- block-edge pre-activation gather ----------------
__global__ __launch_bounds__(256) void k_gather_pre(
    const float* __restrict__ Pb, const float* __restrict__ Qb,
    const int* __restrict__ bedges, float* __restrict__ Epre)
{
  int idx = blockIdx.x * 256 + threadIdx.x;   // over BSG*EBE*H
  int row = idx >> 7, c = idx & 127;
  int g = row >> 9;
  int src = bedges[row*2], dst = bedges[row*2 + 1];
  float v = Pb[(size_t)(g*LBLK + src)*H + c] + Qb[(size_t)(g*LBLK + dst)*H + c];
  Epre[idx] = fmaxf(v, 0.0f);
}

// ---------------- MHA v7: thread-per-row, key-split, chunked online softmax ----
template <int S, int KS>
__global__ __launch_bounds__(256) void k_attn4(
    const float* __restrict__ qkv,
    float* __restrict__ pm, float* __restrict__ pl, float* __restrict__ po)
{
  constexpr int KP = S / KS;       // keys per split
  constexpr int RCH = S / 256;     // row chunks
  constexpr int NR = BSG * NHD * S;
  constexpr int CH = 32;           // score-cache chunk
  __shared__ float Ks[KP][DH];
  __shared__ float Vs[KP][DH];
  int idx = blockIdx.x;
  int rc = idx % RCH;
  int ks = (idx / RCH) % KS;
  int bh = idx / (RCH * KS);
  int b = bh >> 3, h = bh & 7;
  const float* base = qkv + (size_t)b * S * 384;
  int tid = threadIdx.x;
  for (int t = tid; t < KP * 4; t += 256) {
    int j = t >> 2, d4 = t & 3;
    int jg = ks * KP + j;
    *(float4*)&Ks[j][d4*4] = *(const float4*)(base + (size_t)jg*384 + 128 + h*DH + d4*4);
    *(float4*)&Vs[j][d4*4] = *(const float4*)(base + (size_t)jg*384 + 256 + h*DH + d4*4);
  }
  __syncthreads();
  int s = rc * 256 + tid;
  const float4* qp = (const float4*)(base + (size_t)s * 384 + h * DH);
  float4 q0 = qp[0], q1 = qp[1], q2 = qp[2], q3 = qp[3];
  float m = -1e30f, l = 0.0f;
  float4 o0 = {0,0,0,0}, o1 = {0,0,0,0}, o2 = {0,0,0,0}, o3 = {0,0,0,0};
  for (int c0 = 0; c0 < KP; c0 += CH) {
    float scv[CH];
    float mc = -1e30f;
    #pragma unroll
    for (int j = 0; j < CH; ++j) {
      float4 k0 = *(const float4*)&Ks[c0+j][0];
      float4 k1 = *(const float4*)&Ks[c0+j][4];
      float4 k2 = *(const float4*)&Ks[c0+j][8];
      float4 k3 = *(const float4*)&Ks[c0+j][12];
      float s0 = q0.x*k0.x + q0.y*k0.y + q0.z*k0.z + q0.w*k0.w;
      float s1 = q1.x*k1.x + q1.y*k1.y + q1.z*k1.z + q1.w*k1.w;
      float s2 = q2.x*k2.x + q2.y*k2.y + q2.z*k2.z + q2.w*k2.w;
      float s3 = q3.x*k3.x + q3.y*k3.y + q3.z*k3.z + q3.w*k3.w;
      float sc = (s0 + s1) + (s2 + s3);
      scv[j] = sc;
      mc = fmaxf(mc, sc);
    }
    float mn = fmaxf(m, mc);
    float corr = __expf((m - mn) * 0.25f);
    l *= corr;
    o0.x *= corr; o0.y *= corr; o0.z *= corr; o0.w *= corr;
    o1.x *= corr; o1.y *= corr; o1.z *= corr; o1.w *= corr;
    o2.x *= corr; o2.y *= corr; o2.z *= corr; o2.w *= corr;
    o3.x *= corr; o3.y *= corr; o3.z *= corr; o3.w *= corr;
    m = mn;
    #pragma unroll
    for (int j = 0; j < CH; ++j) {
      float p = __expf((scv[j] - m) * 0.25f);
      l += p;
      float4 v0 = *(const float4*)&Vs[c0+j][0];
      float4 v1 = *(const float4*)&Vs[c0+j][4];
      float4 v2 = *(const float4*)&Vs[c0+j][8];
      float4 v3 = *(const float4*)&Vs[c0+j][12];
      o0.x += p*v0.x; o0.y += p*v0.y; o0.z += p*v0.z; o0.w += p*v0.w;
      o1.x += p*v1.x; o1.y += p*v1.y; o1.z += p*v1.z; o1.w += p*v1.w;
      o2.x += p*v2.x; o2.y += p*v2.y; o2.z += p*v2.z; o2.w += p*v2.w;
      o3.x += p*v3.x; o3.y += p*v3.y; o3.z += p*v3.z; o3.w += p*v3.w;
    }
  }
  size_t R = (size_t)bh * S + s;
  pm[(size_t)ks * NR + R] = m;
  pl[(size_t)ks * NR + R] = l;
  float4* po4 = (float4*)po;
  po4[(size_t)(ks*4 + 0) * NR + R] = o0;
  po4[(size_t)(ks*4 + 1) * NR + R] = o1;
  po4[(size_t)(ks*4 + 2) * NR + R] = o2;
  po4[(size_t)(ks*4 + 3) * NR + R] = o3;
}

// combine KS partials per row (4 threads/row, d4 wave-uniform), write normalized ea
template <int S, int KS>
__global__ __launch_bounds__(256) void k_attn4c(
    const float* __restrict__ pm, const float* __restrict__ pl,
    const float* __restrict__ po, float* __restrict__ ea)
{
  constexpr int NR = BSG * NHD * S;
  int R = blockIdx.x * 64 + (threadIdx.x & 63);
  int d4 = threadIdx.x >> 6;   // wave-uniform
  float mv[KS];
  float m = -1e30f;
  #pragma unroll
  for (int k = 0; k < KS; ++k) { mv[k] = pm[(size_t)k*NR + R]; m = fmaxf(m, mv[k]); }
  const float4* po4 = (const float4*)po;
  float l = 0.0f;
  float4 o = {0, 0, 0, 0};
  #pragma unroll
  for (int k = 0; k < KS; ++k) {
    float w = __expf((mv[k] - m) * 0.25f);
    l += pl[(size_t)k*NR + R] * w;
    float4 p = po4[(size_t)(k*4 + d4)*NR + R];
    o.x += p.x*w; o.y += p.y*w; o.z += p.z*w; o.w += p.w*w;
  }
  float inv = 1.0f / l;
  float4 r = {o.x*inv, o.y*inv, o.z*inv, o.w*inv};
  ((float4*)ea)[(size_t)d4*NR + R] = r;
}

// gather ea rows per (block, channel) via block-edge CSR; divide by cnt
__global__ __launch_bounds__(256) void k_bsum_gather(
    const float* __restrict__ ea, const int* __restrict__ blist,
    const int* __restrict__ boff, float* __restrict__ bsum)
{
  constexpr int NR = BSG * NHD * EBE;
  int idx = blockIdx.x * 256 + threadIdx.x;   // over NBLKT*32
  int i = idx >> 5, c4 = idx & 31;
  int b = i >> 6, blk = i & 63;
  int h = c4 >> 2, d4 = c4 & 3;
  int e0 = boff[b*65 + blk], e1 = boff[b*65 + blk + 1];
  const float4* ea4 = (const float4*)ea;
  size_t basein = (size_t)d4 * NR + (size_t)(b*NHD + h) * EBE;
  float4 s = {0, 0, 0, 0};
  for (int e = e0; e < e1; ++e) {
    int srow = blist[b*EBE + e];
    float4 v = ea4[basein + srow];
    s.x += v.x; s.y += v.y; s.z += v.z; s.w += v.w;
  }
  float cnt = (float)(e1 - e0);
  float sc = (cnt > 0.0f) ? (1.0f / cnt) : 0.0f;
  float4 o = {s.x*sc, s.y*sc, s.z*sc, s.w*sc};
  *(float4*)&bsum[(size_t)i*H + c4*4] = o;
}

// ---------------- block self-attention: LDS K/V, wave-reduced mean, NO atomics ----
__global__ __launch_bounds__(256) void k_attnS(
    const float* __restrict__ qkv, float* __restrict__ m2)
{
  __shared__ float Ks[4][LBLK][DH];
  __shared__ float Vs[4][LBLK][DH];
  __shared__ float red[4][LBLK][DH + 1];   // pad 17: odd stride -> conflict-free
  int b = blockIdx.x >> 1, hq = blockIdx.x & 1;
  int tid = threadIdx.x;
  const float* base = qkv + (size_t)b * LBLK * 384;
  for (int t = tid; t < 1024; t += 256) {
    int hl = t >> 8, j = (t >> 2) & 63, d4 = t & 3;
    int h = hq*4 + hl;
    *(float4*)&Ks[hl][j][d4*4] = *(const float4*)(base + (size_t)j*384 + 128 + h*DH + d4*4);
    *(float4*)&Vs[hl][j][d4*4] = *(const float4*)(base + (size_t)j*384 + 256 + h*DH + d4*4);
  }
  __syncthreads();
  int hl = tid >> 6, s = tid & 63;   // hl uniform per wave; wave owns (b, h)
  int h = hq*4 + hl;
  const float4* qp = (const float4*)(base + (size_t)s * 384 + h * DH);
  float4 q0 = qp[0], q1 = qp[1], q2 = qp[2], q3 = qp[3];
  float m = -1e30f, l = 0.0f;
  float4 o0 = {0,0,0,0}, o1 = {0,0,0,0}, o2 = {0,0,0,0}, o3 = {0,0,0,0};
  for (int c0 = 0; c0 < LBLK; c0 += 32) {
    float scv[32];
    float mc = -1e30f;
    #pragma unroll
    for (int j = 0; j < 32; ++j) {
      float4 k0 = *(const float4*)&Ks[hl][c0+j][0];
      float4 k1 = *(const float4*)&Ks[hl][c0+j][4];
      float4 k2 = *(const float4*)&Ks[hl][c0+j][8];
      float4 k3 = *(const float4*)&Ks[hl][c0+j][12];
      float s0 = q0.x*k0.x + q0.y*k0.y + q0.z*k0.z + q0.w*k0.w;
      float s1 = q1.x*k1.x + q1.y*k1.y + q1.z*k1.z + q1.w*k1.w;
      float s2 = q2.x*k2.x + q2.y*k2.y + q2.z*k2.z + q2.w*k2.w;
      float s3 = q3.x*k3.x + q3.y*k3.y + q3.z*k3.z + q3.w*k3.w;
      float sc = (s0 + s1) + (s2 + s3);
      scv[j] = sc;
      mc = fmaxf(mc, sc);
    }
    float mn = fmaxf(m, mc);
    float corr = __expf((m - mn) * 0.25f);
    l *= corr;
    o0.x *= corr; o0.y *= corr; o0.z *= corr; o0.w *= corr;
    o1.x *= corr; o1.y *= corr; o1.z *= corr; o1.w *= corr;
    o2.x *= corr; o2.y *= corr; o2.z *= corr; o2.w *= corr;
    o3.x *= corr; o3.y *= corr; o3.z *= corr; o3.w *= corr;
    m = mn;
    #pragma unroll
    for (int j = 0; j < 32; ++j) {
      float p = __expf((scv[j] - m) * 0.25f);
      l += p;
      float4 v0 = *(const float4*)&Vs[hl][c0+j][0];
      float4 v1 = *(const float4*)&Vs[hl][c0+j][4];
      float4 v2 = *(const float4*)&Vs[hl][c0+j][8];
      float4 v3 = *(const float4*)&Vs[hl][c0+j][12];
      o0.x += p*v0.x; o0.y += p*v0.y; o0.z += p*v0.z; o0.w += p*v0.w;
      o1.x += p*v1.x; o1.y += p*v1.y; o1.z += p*v1.z; o1.w += p*v1.w;
      o2.x += p*v2.x; o2.y += p*v2.y; o2.z += p*v2.z; o2.w += p*v2.w;
      o3.x += p*v3.x; o3.y += p*v3.y; o3.z += p*v3.z; o3.w += p*v3.w;
    }
  }
  // normalize this row's output and stash in LDS (17-stride, conflict-free)
  float inv = (1.0f / l) * (1.0f / 64.0f);
  float ov[DH] = {o0.x,o0.y,o0.z,o0.w, o1.x,o1.y,o1.z,o1.w,
                  o2.x,o2.y,o2.z,o2.w, o3.x,o3.y,o3.z,o3.w};
  #pragma unroll
  for (int d = 0; d < DH; ++d) red[hl][s][d] = ov[d] * inv;
  __syncthreads();
  // wave owns (b,h): lanes 0..15 sum the 64 rows, plain store (no atomics)
  if (s < DH) {
    float acc = 0.0f;
    for (int r = 0; r < LBLK; ++r) acc += red[hl][r][s];
    m2[(size_t)b * H + h * DH + s] = acc;
  }
}

// ---------------- final: out-proj + LN + 3-layer MLP ----------------
__device__ __forceinline__ float bsum128(float v, float* red) {
  int t = threadIdx.x;
  red[t] = v; __syncthreads();
  #pragma unroll
  for (int off = 64; off > 0; off >>= 1) {
    if (t < off) red[t] += red[t + off];
    __syncthreads();
  }
  float s = red[0];
  __syncthreads();
  return s;
}

__global__ __launch_bounds__(128) void k_final(
    const float* __restrict__ m2, const float* __restrict__ out_w,
    const float* __restrict__ out_b, const float* __restrict__ lng,
    const float* __restrict__ lnb, const float* __restrict__ w1,
    const float* __restrict__ b1, const float* __restrict__ w2,
    const float* __restrict__ b2, const float* __restrict__ w3,
    const float* __restrict__ b3, float* __restrict__ out)
{
  __shared__ float buf[128];
  __shared__ float red[128];
  int b = blockIdx.x, t = threadIdx.x;
  buf[t] = m2[b*H + t];
  __syncthreads();
  float g = out_b[t];
  for (int k = 0; k < H; ++k) g += buf[k] * out_w[k*H + t];
  float mu = bsum128(g, red) * (1.0f / H);
  float df = g - mu;
  float var = bsum128(df * df, red) * (1.0f / H);
  float gn = df / sqrtf(var + 1e-5f) * lng[t] + lnb[t];
  __syncthreads();
  buf[t] = gn; __syncthreads();
  float h1 = b1[t];
  for (int k = 0; k < H; ++k) h1 += buf[k] * w1[k*H + t];
  h1 = fmaxf(h1, 0.0f);
  __syncthreads();
  buf[t] = h1; __syncthreads();
  float h2 = b2[t];
  for (int k = 0; k < H; ++k) h2 += buf[k] * w2[k*H + t];
  h2 = fmaxf(h2, 0.0f);
  float tot = bsum128(h2 * w3[t], red);
  if (t == 0) out[b] = tot + b3[0];
}

extern "C" void kernel_launch(void* const* d_in, const int* in_sizes, int n_in,
                              void* d_out, int out_size, void* d_ws, size_t ws_size,
                              hipStream_t stream) {
  (void)in_sizes; (void)n_in; (void)out_size; (void)ws_size;
  const int*   A          = (const int*)d_in[0];
  const int*   apos       = (const int*)d_in[1];
  const int*   btypes     = (const int*)d_in[2];
  const float* coords     = (const float*)d_in[3];
  const int*   edge_index = (const int*)d_in[4];
  const int*   bedges     = (const int*)d_in[5];
  const float* emb_atom   = (const float*)d_in[6];
  const float* emb_pos    = (const float*)d_in[7];
  const float* emb_block  = (const float*)d_in[8];
  const float* rbf_freq   = (const float*)d_in[9];
  const float* inter_w1   = (const float*)d_in[10];
  const float* inter_b1   = (const float*)d_in[11];
  const float* inter_w2   = (const float*)d_in[12];
  const float* inter_b2   = (const float*)d_in[13];
  const float* upd_w1     = (const float*)d_in[14];
  const float* upd_b1     = (const float*)d_in[15];
  const float* upd_w2     = (const float*)d_in[16];
  const float* upd_b2     = (const float*)d_in[17];
  const float* edge_w1    = (const float*)d_in[18];
  const float* edge_b1    = (const float*)d_in[19];
  const float* edge_w2    = (const float*)d_in[20];
  const float* edge_b2    = (const float*)d_in[21];
  const float* attn_in_w  = (const float*)d_in[22];
  const float* attn_in_b  = (const float*)d_in[23];
  const float* attn_out_w = (const float*)d_in[24];
  const float* attn_out_b = (const float*)d_in[25];
  const float* ln_g       = (const float*)d_in[26];
  const float* ln_b       = (const float*)d_in[27];
  const float* fin_w1     = (const float*)d_in[28];
  const float* fin_b1     = (const float*)d_in[29];
  const float* fin_w2     = (const float*)d_in[30];
  const float* fin_b2     = (const float*)d_in[31];
  const float* fin_w3     = (const float*)d_in[32];
  const float* fin_b3     = (const float*)d_in[33];
  float* out = (float*)d_out;

  float* ws = (float*)d_ws;
  float* x      = ws + 0;
  float* P      = ws + 2097152;
  float* Q      = ws + 4194304;
  float* Hagg   = ws + 6291456;
  float* rbf_s  = ws + 8388608;    // E*6 (sorted RBF)
  float* cntf   = ws + 9961472;    // NA
  float* blocks = ws + 9977856;    // NBLKT*H
  float* Pb     = ws + 10108928;
  float* Qb     = ws + 10240000;
  float* Epre   = ws + 10371072;   // BSG*EBE*H (sort scratch early; ea late)
  float* ef2    = ws + 11419648;
  float* qkv    = ws + 12468224;   // BSG*EBE*384
  float* bsum   = ws + 15613952;   // NBLKT*H
  float* ind    = ws + 15746048;   // NBLKT
  float* m2     = ws + 15747072;   // BSG*H
  int* blist    = (int*)(ws + 15749120);  // BSG*EBE ints
  int* boff     = (int*)(ws + 15757312);  // BSG*65 ints
  // sort scratch + wprep live in Epre region (dead until block-attention phase):
  int* ej_s   = (int*)(ws + 10371072);          // NE ints
  int* off    = (int*)(ws + 10371072 + 262144); // NA+1 ints
  int* cur    = (int*)(ws + 10371072 + 278784); // NA ints
  int* cnt    = (int*)(ws + 10371072 + 295168); // NA ints
  float* wbuf = ws + 10371072 + 311552;         // 256*128 floats
  float* bvec = ws + 10371072 + 344320;         // 128 floats
  // attention partials (KS=8, split-major) reuse x/P/Q/Hagg/rbf_s regions:
  float* part_m = ws + 0;          // 8*65536 = 524288 floats
  float* part_l = ws + 524288;     // 524288 floats
  float* part_o = ws + 1048576;    // 8*65536*16 = 8388608 floats -> ends 9437184
  float* ea     = ws + 10371072;   // 65536*16 = 1048576 floats (Epre region, d4-major)

  const int* ei = edge_index;
  const int* ej = edge_index + NE;

  // ---- edge sort (once; reused by both interaction blocks) ----
  (void)hipMemsetAsync(cnt, 0, NA * sizeof(int), stream);
  k_hist<<<NE/256, 256, 0, stream>>>(ei, cnt);
  k_scan<<<1, 1024, 0, stream>>>(cnt, off, cur, cntf);
  k_scatter<<<NE/256, 256, 0, stream>>>(ei, ej, coords, rbf_freq, cur, ej_s, rbf_s);
  k_bedge_csr<<<BSG, 256, 0, stream>>>(bedges, blist, boff, ind);

  k_embed<<<NA*H/256, 256, 0, stream>>>(A, apos, btypes, emb_atom, emb_pos, emb_block, x);

  for (int b = 0; b < NBI; ++b) {
    const float* w1 = inter_w1 + (size_t)b * 262 * H;
    k_wprep<<<128, 128, 0, stream>>>(inter_w2 + (size_t)b*H*H, upd_w1 + (size_t)b*2*H*H,
                                     inter_b2 + b*H, wbuf, bvec);
    // fused: P = x@W1a + b1 (y=0) ; Q = x@W1b (y=1, no bias)
    gemm128<<<dim3(NA/32, 2), 256, 0, stream>>>(x, nullptr, w1, H, 0, inter_b1 + b*H,
                                                nullptr, nullptr, nullptr,
                                                P, H, 0, NA, H, 0, 0, 128, 2097152);
    k_edge_csr<<<NA/8, 256, 0, stream>>>(P, Q, rbf_s, w1 + 256*H, ej_s, off, Hagg);
    // chained: U = silu([x|Hagg]@wbuf + b1 + cnt*bvec); x = U@upd_w2 + b2 + x
    k_upd_chain<<<NA/32, 256, 0, stream>>>(x, Hagg, wbuf, upd_b1 + b*H, bvec, cntf,
                                           upd_w2 + (size_t)b*H*H, upd_b2 + b*H, x);
  }

  k_block_mean<<<NBLKT*H/256, 256, 0, stream>>>(x, blocks);
  // fused: Pb = blocks@edge_w1a + b (y=0) ; Qb = blocks@edge_w1b (y=1)
  gemm128<<<dim3(NBLKT/32, 2), 256, 0, stream>>>(blocks, nullptr, edge_w1, H, 0, edge_b1,
                                                 nullptr, nullptr, nullptr,
                                                 Pb, H, 0, NBLKT, H, 0, 0, 128, 131072);
  k_gather_pre<<<BSG*EBE*H/256, 256, 0, stream>>>(Pb, Qb, bedges, Epre);
  gemm128<<<BSG*EBE/32, 256, 0, stream>>>(Epre, nullptr, edge_w2, H, 0, edge_b2, nullptr,
                                          nullptr, nullptr, ef2, H, 0, BSG*EBE, H, 0,
                                          0, 0, 0);
  gemm128<<<dim3(BSG*EBE/32, 3), 256, 0, stream>>>(ef2, nullptr, attn_in_w, 384, 0,
                                                   attn_in_b, nullptr, nullptr, nullptr,
                                                   qkv, 384, 0, BSG*EBE, H, 0, 128, 0, 0);
  k_attn4<EBE, 8><<<BSG*NHD*8*(EBE/256), 256, 0, stream>>>(qkv, part_m, part_l, part_o);
  k_attn4c<EBE, 8><<<BSG*NHD*EBE/64, 256, 0, stream>>>(part_m, part_l, part_o, ea);
  k_bsum_gather<<<NBLKT*32/256, 256, 0, stream>>>(ea, blist, boff, bsum);
  // blocks += (bsum/cnt)@out_w + out_b*[cnt>0]
  gemm128<<<NBLKT/32, 256, 0, stream>>>(bsum, nullptr, attn_out_w, H, 0, nullptr,
                                        attn_out_b, ind, blocks, blocks, H, 0,
                                        NBLKT, H, 0, 0, 0, 0);
  gemm128<<<dim3(NBLKT/32, 3), 256, 0, stream>>>(blocks, nullptr, attn_in_w, 384, 0,
                                                 attn_in_b, nullptr, nullptr, nullptr,
                                                 qkv, 384, 0, NBLKT, H, 0, 128, 0, 0);
  k_attnS<<<BSG*2, 256, 0, stream>>>(qkv, m2);
  k_final<<<BSG, 128, 0, stream>>>(m2, attn_out_w, attn_out_b, ln_g, ln_b,
                                   fin_w1, fin_b1, fin_w2, fin_b2, fin_w3, fin_b3, out);
}

// Round 21
// 555.583 us; speedup vs baseline: 1.1158x; 1.0022x over previous
//
#include <hip/hip_runtime.h>
#include <math.h>

#define H 128
#define NHD 8
#define DH 16
#define RB 6
#define NBI 2
#define BSG 16
#define LBLK 64
#define KATOM 16
#define NBLKT 1024
#define NA 16384
#define NE 262144
#define EBE 512

__device__ __forceinline__ float atomAddF(float* p, float v) {
#if defined(__gfx90a__) || defined(__gfx940__) || defined(__gfx941__) || defined(__gfx942__) || defined(__gfx950__)
  return unsafeAtomicAdd(p, v);
#else
  return atomicAdd(p, v);
#endif
}

__device__ __forceinline__ float fsilu(float v) {
  return v * __builtin_amdgcn_rcpf(1.0f + __expf(-v));
}

// ---------------- embedding ----------------
__global__ __launch_bounds__(256) void k_embed(
    const int* __restrict__ A, const int* __restrict__ apos,
    const int* __restrict__ btypes,
    const float* __restrict__ emb_atom, const float* __restrict__ emb_pos,
    const float* __restrict__ emb_block, float* __restrict__ x)
{
  int idx = blockIdx.x * 256 + threadIdx.x;   // over NA*H
  int n = idx >> 7, h = idx & 127;
  x[idx] = emb_atom[A[n] * H + h] + emb_pos[apos[n] * H + h]
         + emb_block[btypes[n >> 4] * H + h];
}

// ---------------- edge sort: histogram ----------------
__global__ __launch_bounds__(256) void k_hist(
    const int* __restrict__ ei, int* __restrict__ cnt)
{
  int e = blockIdx.x * 256 + threadIdx.x;
  atomicAdd(&cnt[ei[e]], 1);
}

// ---------------- edge sort: scan (single block, 1024 thr, 16 bins each) ----
__global__ __launch_bounds__(1024) void k_scan(
    const int* __restrict__ cnt, int* __restrict__ off,
    int* __restrict__ cur, float* __restrict__ cntf)
{
  __shared__ int ps[1024];
  int t = threadIdx.x;
  int base = t * 16;
  int local[16];
  int s = 0;
  #pragma unroll
  for (int k = 0; k < 16; ++k) { local[k] = s; s += cnt[base + k]; }
  ps[t] = s;
  __syncthreads();
  for (int d = 1; d < 1024; d <<= 1) {
    int v = (t >= d) ? ps[t - d] : 0;
    __syncthreads();
    ps[t] += v;
    __syncthreads();
  }
  int offset = (t == 0) ? 0 : ps[t - 1];
  #pragma unroll
  for (int k = 0; k < 16; ++k) {
    int o = offset + local[k];
    off[base + k] = o;
    cur[base + k] = o;
    cntf[base + k] = (float)cnt[base + k];
  }
  if (t == 1023) off[NA] = offset + s;
}

// ---------------- edge sort: scatter + fused RBF ----------------
__global__ __launch_bounds__(256) void k_scatter(
    const int* __restrict__ ei, const int* __restrict__ ej,
    const float* __restrict__ coords, const float* __restrict__ freq,
    int* __restrict__ cur, int* __restrict__ ej_s, float* __restrict__ rbf_s)
{
  int e = blockIdx.x * 256 + threadIdx.x;
  int i = ei[e], j = ej[e];
  int pos = atomicAdd(&cur[i], 1);
  ej_s[pos] = j;
  float dx = coords[i*3+0] - coords[j*3+0];
  float dy = coords[i*3+1] - coords[j*3+1];
  float dz = coords[i*3+2] - coords[j*3+2];
  float d = sqrtf(dx*dx + dy*dy + dz*dz);
  float u = fmaxf(d * 0.125f, 1e-3f);
  float u2 = u*u, u4 = u2*u2, u5 = u4*u, u6 = u5*u, u7 = u6*u;
  float env = 1.0f/u - 28.0f*u5 + 48.0f*u6 - 21.0f*u7;
  #pragma unroll
  for (int r = 0; r < RB; ++r)
    rbf_s[(size_t)pos*RB + r] = env * sinf(freq[r] * u);
}

// ---------------- block-edge CSR (per-graph src buckets) ----------------
__global__ __launch_bounds__(256) void k_bedge_csr(
    const int* __restrict__ bedges, int* __restrict__ blist,
    int* __restrict__ boff, float* __restrict__ ind)
{
  __shared__ int hist[64], offs[65], curs[64];
  int b = blockIdx.x, t = threadIdx.x;
  if (t < 64) hist[t] = 0;
  __syncthreads();
  for (int e = t; e < EBE; e += 256) atomicAdd(&hist[bedges[(b*EBE + e)*2]], 1);
  __syncthreads();
  if (t == 0) {
    offs[0] = 0;
    for (int k = 0; k < 64; ++k) offs[k+1] = offs[k] + hist[k];
  }
  __syncthreads();
  if (t < 64) curs[t] = offs[t];
  __syncthreads();
  for (int e = t; e < EBE; e += 256) {
    int src = bedges[(b*EBE + e)*2];
    int pos = atomicAdd(&curs[src], 1);
    blist[b*EBE + pos] = e;
  }
  if (t < 65) boff[b*65 + t] = offs[t];
  if (t < 64) ind[b*64 + t] = (hist[t] > 0) ? 1.0f : 0.0f;
}

// ---------------- per-atom CSR edge pass v2 (float4 channels, no atomics) ----
__global__ __launch_bounds__(256) void k_edge_csr(
    const float* __restrict__ P, const float* __restrict__ Q,
    const float* __restrict__ rbf_s, const float* __restrict__ W1c,
    const int* __restrict__ ej_s, const int* __restrict__ off,
    float* __restrict__ Hagg)
{
  __shared__ float w[RB * H];
  for (int idx = threadIdx.x; idx < RB * H; idx += 256) w[idx] = W1c[idx];
  __syncthreads();
  int c4 = threadIdx.x & 31;        // channel quad
  int sub = threadIdx.x >> 5;       // atom within block
  int i = blockIdx.x * 8 + sub;
  int e0 = off[i], e1 = off[i + 1];
  float4 pv = *(const float4*)&P[(size_t)i * H + c4 * 4];
  float4 W0 = *(const float4*)&w[0*H + c4*4];
  float4 W1 = *(const float4*)&w[1*H + c4*4];
  float4 W2 = *(const float4*)&w[2*H + c4*4];
  float4 W3 = *(const float4*)&w[3*H + c4*4];
  float4 W4 = *(const float4*)&w[4*H + c4*4];
  float4 W5 = *(const float4*)&w[5*H + c4*4];
  float4 acc = {0, 0, 0, 0};
  for (int e = e0; e < e1; ++e) {
    int j = ej_s[e];
    float4 qv = *(const float4*)&Q[(size_t)j * H + c4 * 4];
    const float* rb = &rbf_s[(size_t)e * RB];
    float r0 = rb[0], r1 = rb[1], r2 = rb[2], r3 = rb[3], r4 = rb[4], r5 = rb[5];
    float4 v;
    v.x = pv.x + qv.x + r0*W0.x + r1*W1.x + r2*W2.x + r3*W3.x + r4*W4.x + r5*W5.x;
    v.y = pv.y + qv.y + r0*W0.y + r1*W1.y + r2*W2.y + r3*W3.y + r4*W4.y + r5*W5.y;
    v.z = pv.z + qv.z + r0*W0.z + r1*W1.z + r2*W2.z + r3*W3.z + r4*W4.z + r5*W5.z;
    v.w = pv.w + qv.w + r0*W0.w + r1*W1.w + r2*W2.w + r3*W3.w + r4*W4.w + r5*W5.w;
    acc.x += fsilu(v.x);
    acc.y += fsilu(v.y);
    acc.z += fsilu(v.z);
    acc.w += fsilu(v.w);
  }
  *(float4*)&Hagg[(size_t)i * H + c4 * 4] = acc;
}

// ---------------- weight prep (both blocks in one launch via blockIdx.y) ----
__global__ __launch_bounds__(128) void k_wprep(
    const float* __restrict__ W2base, const float* __restrict__ U1base,
    const float* __restrict__ b2base, float* __restrict__ wbufbase,
    float* __restrict__ bvecbase)
{
  int y = blockIdx.y;
  const float* W2 = W2base + (size_t)y * H * H;
  const float* U1 = U1base + (size_t)y * 2 * H * H;
  const float* b2 = b2base + y * H;
  float* wbuf = wbufbase + (size_t)y * 256 * H;
  float* bvec = bvecbase + y * H;
  int k = blockIdx.x, c = threadIdx.x;
  const float* U1b = U1 + 128 * H;
  wbuf[k * H + c] = U1[k * H + c];
  float s = 0.0f;
  for (int t = 0; t < H; ++t) s += W2[k * H + t] * U1b[t * H + c];
  wbuf[(128 + k) * H + c] = s;
  if (k == 0) {
    float sb = 0.0f;
    for (int t = 0; t < H; ++t) sb += b2[t] * U1b[t * H + c];
    bvec[c] = sb;
  }
}

// ---------------- generic 128-col GEMM v2 + row-mode y fusion ----------------
__global__ __launch_bounds__(256) void gemm128(
    const float* __restrict__ A1, const float* __restrict__ A2,
    const float* __restrict__ W, int ldw, int wcol0,
    const float* __restrict__ bias, const float* __restrict__ bias2,
    const float* __restrict__ bias_scale,
    const float* __restrict__ res,
    float* __restrict__ C, int ldc, int ccol0,
    int M, int Ktot, int act, int ymul, int wrowmul, long long cymul)
{
  __shared__ float As[32][256];
  __shared__ float Ws[16][128];
  int tid = threadIdx.x;
  int m0 = blockIdx.x * 32;
  int yoff = blockIdx.y * ymul;
  W += (size_t)blockIdx.y * wrowmul * ldw;
  C += (size_t)blockIdx.y * cymul;
  bool doBias = (ymul != 0) || (blockIdx.y == 0);
  for (int idx = tid; idx < 32*32; idx += 256) {
    int r = idx >> 5, k4 = idx & 31;
    float4 v = *(const float4*)&A1[(size_t)(m0 + r)*H + k4*4];
    *(float4*)&As[r][k4*4] = v;
  }
  if (A2) {
    for (int idx = tid; idx < 32*32; idx += 256) {
      int r = idx >> 5, k4 = idx & 31;
      float4 v = *(const float4*)&A2[(size_t)(m0 + r)*H + k4*4];
      *(float4*)&As[r][128 + k4*4] = v;
    }
  }
  int rr = tid >> 5;    // 0..7
  int cq = tid & 31;    // col quad
  float acc[4][4] = {};
  for (int kk0 = 0; kk0 < Ktot; kk0 += 16) {
    __syncthreads();
    for (int idx = tid; idx < 16*32; idx += 256) {
      int kr = idx >> 5, c4 = idx & 31;
      float4 v = *(const float4*)&W[(size_t)(kk0 + kr)*ldw + wcol0 + yoff + c4*4];
      *(float4*)&Ws[kr][c4*4] = v;
    }
    __syncthreads();
    #pragma unroll
    for (int k4 = 0; k4 < 4; ++k4) {
      float4 w0 = *(const float4*)&Ws[k4*4+0][cq*4];
      float4 w1 = *(const float4*)&Ws[k4*4+1][cq*4];
      float4 w2 = *(const float4*)&Ws[k4*4+2][cq*4];
      float4 w3 = *(const float4*)&Ws[k4*4+3][cq*4];
      #pragma unroll
      for (int i = 0; i < 4; ++i) {
        float4 a = *(const float4*)&As[rr + 8*i][kk0 + k4*4];
        acc[i][0] += a.x*w0.x + a.y*w1.x + a.z*w2.x + a.w*w3.x;
        acc[i][1] += a.x*w0.y + a.y*w1.y + a.z*w2.y + a.w*w3.y;
        acc[i][2] += a.x*w0.z + a.y*w1.z + a.z*w2.z + a.w*w3.z;
        acc[i][3] += a.x*w0.w + a.y*w1.w + a.z*w2.w + a.w*w3.w;
      }
    }
  }
  #pragma unroll
  for (int i = 0; i < 4; ++i) {
    int m = m0 + rr + 8*i;
    float bs = bias_scale ? bias_scale[m] : 1.0f;
    float4 out;
    float* po = &out.x;
    #pragma unroll
    for (int j = 0; j < 4; ++j) {
      int c = cq*4 + j;
      float v = acc[i][j];
      if (bias && doBias) v += bias[yoff + c];
      if (bias2 && doBias) v += bias2[yoff + c] * bs;
      if (act == 1) v = fsilu(v);
      else if (act == 2) v = fmaxf(v, 0.0f);
      if (res) v += res[(size_t)m*H + c];
      po[j] = v;
    }
    *(float4*)&C[(size_t)m*ldc + ccol0 + yoff + cq*4] = out;
  }
}

// ---------------- chained update: U = silu([x|Hagg]@W1 + b1 + cnt*bvec);
//                  xout = U@W2 + b2 + x  (one kernel, U stays in LDS) --------
__global__ __launch_bounds__(256) void k_upd_chain(
    const float* __restrict__ x, const float* __restrict__ Hagg,
    const float* __restrict__ W1,    // wbuf [256][128]
    const float* __restrict__ b1, const float* __restrict__ bvec,
    const float* __restrict__ cntf,
    const float* __restrict__ W2,    // upd_w2 [128][128]
    const float* __restrict__ b2,
    float* __restrict__ xout)
{
  __shared__ float As[32][256];   // 32 KB
  __shared__ float Ws[16][128];   // 8 KB
  __shared__ float Us[32][128];   // 16 KB  -> 56 KB total, 2 blocks/CU
  int tid = threadIdx.x;
  int m0 = blockIdx.x * 32;
  for (int idx = tid; idx < 32*32; idx += 256) {
    int r = idx >> 5, k4 = idx & 31;
    *(float4*)&As[r][k4*4] = *(const float4*)&x[(size_t)(m0 + r)*H + k4*4];
    *(float4*)&As[r][128 + k4*4] = *(const float4*)&Hagg[(size_t)(m0 + r)*H + k4*4];
  }
  int rr = tid >> 5;    // 0..7
  int cq = tid & 31;    // col quad
  float acc[4][4] = {};
  for (int kk0 = 0; kk0 < 256; kk0 += 16) {
    __syncthreads();
    for (int idx = tid; idx < 16*32; idx += 256) {
      int kr = idx >> 5, c4 = idx & 31;
      *(float4*)&Ws[kr][c4*4] = *(const float4*)&W1[(size_t)(kk0 + kr)*H + c4*4];
    }
    __syncthreads();
    #pragma unroll
    for (int k4 = 0; k4 < 4; ++k4) {
      float4 w0 = *(const float4*)&Ws[k4*4+0][cq*4];
      float4 w1 = *(const float4*)&Ws[k4*4+1][cq*4];
      float4 w2 = *(const float4*)&Ws[k4*4+2][cq*4];
      float4 w3 = *(const float4*)&Ws[k4*4+3][cq*4];
      #pragma unroll
      for (int i = 0; i < 4; ++i) {
        float4 a = *(const float4*)&As[rr + 8*i][kk0 + k4*4];
        acc[i][0] += a.x*w0.x + a.y*w1.x + a.z*w2.x + a.w*w3.x;
        acc[i][1] += a.x*w0.y + a.y*w1.y + a.z*w2.y + a.w*w3.y;
        acc[i][2] += a.x*w0.z + a.y*w1.z + a.z*w2.z + a.w*w3.z;
        acc[i][3] += a.x*w0.w + a.y*w1.w + a.z*w2.w + a.w*w3.w;
      }
    }
  }
  #pragma unroll
  for (int i = 0; i < 4; ++i) {
    int m = m0 + rr + 8*i;
    float bs = cntf[m];
    float4 u;
    float* pu = &u.x;
    #pragma unroll
    for (int j = 0; j < 4; ++j) {
      int c = cq*4 + j;
      float v = acc[i][j] + b1[c] + bvec[c] * bs;
      pu[j] = fsilu(v);
    }
    *(float4*)&Us[rr + 8*i][cq*4] = u;
    acc[i][0] = 0.0f; acc[i][1] = 0.0f; acc[i][2] = 0.0f; acc[i][3] = 0.0f;
  }
  for (int kk0 = 0; kk0 < 128; kk0 += 16) {
    __syncthreads();
    for (int idx = tid; idx < 16*32; idx += 256) {
      int kr = idx >> 5, c4 = idx & 31;
      *(float4*)&Ws[kr][c4*4] = *(const float4*)&W2[(size_t)(kk0 + kr)*H + c4*4];
    }
    __syncthreads();
    #pragma unroll
    for (int k4 = 0; k4 < 4; ++k4) {
      float4 w0 = *(const float4*)&Ws[k4*4+0][cq*4];
      float4 w1 = *(const float4*)&Ws[k4*4+1][cq*4];
      float4 w2 = *(const float4*)&Ws[k4*4+2][cq*4];
      float4 w3 = *(const float4*)&Ws[k4*4+3][cq*4];
      #pragma unroll
      for (int i = 0; i < 4; ++i) {
        float4 a = *(const float4*)&Us[rr + 8*i][kk0 + k4*4];
        acc[i][0] += a.x*w0.x + a.y*w1.x + a.z*w2.x + a.w*w3.x;
        acc[i][1] += a.x*w0.y + a.y*w1.y + a.z*w2.y + a.w*w3.y;
        acc[i][2] += a.x*w0.z + a.y*w1.z + a.z*w2.z + a.w*w3.z;
        acc[i][3] += a.x*w0.w + a.y*w1.w + a.z*w2.w + a.w*w3.w;
      }
    }
  }
  #pragma unroll
  for (int i = 0; i < 4; ++i) {
    int m = m0 + rr + 8*i;
    float4 out;
    float* po = &out.x;
    #pragma unroll
    for (int j = 0; j < 4; ++j) {
      int c = cq*4 + j;
      po[j] = acc[i][j] + b2[c] + x[(size_t)m*H + c];
    }
    *(float4*)&xout[(size_t)m*H + cq*4] = out;
  }
}

// ---------------- fused block-edge prep: gather+relu -> @edge_w2 -> @attn_in_w ----
// Replaces k_gather_pre + gemm(ef2) + gemm(qkv,y=3): one launch, tiles in LDS.
__global__ __launch_bounds__(256) void k_eprep(
    const float* __restrict__ Pb, const float* __restrict__ Qb,
    const int* __restrict__ bedges,
    const float* __restrict__ W2e, const float* __restrict__ b2e,
    const float* __restrict__ Win, const float* __restrict__ bin,
    float* __restrict__ qkv)
{
  __shared__ float As[32][128];   // Epre tile (16 KB)
  __shared__ float Ws[16][128];   // weight panel (8 KB)
  __shared__ float Us[32][128];   // ef2 tile (16 KB)  -> 40 KB total
  int tid = threadIdx.x;
  int m0 = blockIdx.x * 32;
  // gather + relu Epre tile
  for (int idx = tid; idx < 32*32; idx += 256) {
    int r = idx >> 5, k4 = idx & 31;
    int row = m0 + r;
    int g = row >> 9;
    int src = bedges[row*2], dst = bedges[row*2 + 1];
    float4 pv = *(const float4*)&Pb[(size_t)(g*LBLK + src)*H + k4*4];
    float4 qv = *(const float4*)&Qb[(size_t)(g*LBLK + dst)*H + k4*4];
    float4 v;
    v.x = fmaxf(pv.x + qv.x, 0.0f);
    v.y = fmaxf(pv.y + qv.y, 0.0f);
    v.z = fmaxf(pv.z + qv.z, 0.0f);
    v.w = fmaxf(pv.w + qv.w, 0.0f);
    *(float4*)&As[r][k4*4] = v;
  }
  int rr = tid >> 5;    // 0..7
  int cq = tid & 31;    // col quad
  float acc[4][4] = {};
  // stage 1: ef2 = Epre @ edge_w2 + b2e  (K=128)
  for (int kk0 = 0; kk0 < 128; kk0 += 16) {
    __syncthreads();
    for (int idx = tid; idx < 16*32; idx += 256) {
      int kr = idx >> 5, c4 = idx & 31;
      *(float4*)&Ws[kr][c4*4] = *(const float4*)&W2e[(size_t)(kk0 + kr)*H + c4*4];
    }
    __syncthreads();
    #pragma unroll
    for (int k4 = 0; k4 < 4; ++k4) {
      float4 w0 = *(const float4*)&Ws[k4*4+0][cq*4];
      float4 w1 = *(const float4*)&Ws[k4*4+1][cq*4];
      float4 w2 = *(const float4*)&Ws[k4*4+2][cq*4];
      float4 w3 = *(const float4*)&Ws[k4*4+3][cq*4];
      #pragma unroll
      for (int i = 0; i < 4; ++i) {
        float4 a = *(const float4*)&As[rr + 8*i][kk0 + k4*4];
        acc[i][0] += a.x*w0.x + a.y*w1.x + a.z*w2.x + a.w*w3.x;
        acc[i][1] += a.x*w0.y + a.y*w1.y + a.z*w2.y + a.w*w3.y;
        acc[i][2] += a.x*w0.z + a.y*w1.z + a.z*w2.z + a.w*w3.z;
        acc[i][3] += a.x*w0.w + a.y*w1.w + a.z*w2.w + a.w*w3.w;
      }
    }
  }
  #pragma unroll
  for (int i = 0; i < 4; ++i) {
    float4 u;
    float* pu = &u.x;
    #pragma unroll
    for (int j = 0; j < 4; ++j) pu[j] = acc[i][j] + b2e[cq*4 + j];
    *(float4*)&Us[rr + 8*i][cq*4] = u;
  }
  // stage 2: qkv[:, chunk*128..] = ef2 @ attn_in_w + bin   (3 chunks)
  for (int chunk = 0; chunk < 3; ++chunk) {
    #pragma unroll
    for (int i = 0; i < 4; ++i) {
      acc[i][0] = 0.0f; acc[i][1] = 0.0f; acc[i][2] = 0.0f; acc[i][3] = 0.0f;
    }
    for (int kk0 = 0; kk0 < 128; kk0 += 16) {
      __syncthreads();
      for (int idx = tid; idx < 16*32; idx += 256) {
        int kr = idx >> 5, c4 = idx & 31;
        *(float4*)&Ws[kr][c4*4] =
            *(const float4*)&Win[(size_t)(kk0 + kr)*384 + chunk*128 + c4*4];
      }
      __syncthreads();
      #pragma unroll
      for (int k4 = 0; k4 < 4; ++k4) {
        float4 w0 = *(const float4*)&Ws[k4*4+0][cq*4];
        float4 w1 = *(const float4*)&Ws[k4*4+1][cq*4];
        float4 w2 = *(const float4*)&Ws[k4*4+2][cq*4];
        float4 w3 = *(const float4*)&Ws[k4*4+3][cq*4];
        #pragma unroll
        for (int i = 0; i < 4; ++i) {
          float4 a = *(const float4*)&Us[rr + 8*i][kk0 + k4*4];
          acc[i][0] += a.x*w0.x + a.y*w1.x + a.z*w2.x + a.w*w3.x;
          acc[i][1] += a.x*w0.y + a.y*w1.y + a.z*w2.y + a.w*w3.y;
          acc[i][2] += a.x*w0.z + a.y*w1.z + a.z*w2.z + a.w*w3.z;
          acc[i][3] += a.x*w0.w + a.y*w1.w + a.z*w2.w + a.w*w3.w;
        }
      }
    }
    #pragma unroll
    for (int i = 0; i < 4; ++i) {
      int m = m0 + rr + 8*i;
      float4 out;
      float* po = &out.x;
      #pragma unroll
      for (int j = 0; j < 4; ++j)
        po[j] = acc[i][j] + bin[chunk*128 + cq*4 + j];
      *(float4*)&qkv[(size_t)m*384 + chunk*128 + cq*4] = out;
    }
  }
}

// ---------------- block mean over K atoms ----------------
__global__ __launch_bounds__(256) void k_block_mean(
    const float* __restrict__ x, float* __restrict__ blocks)
{
  int idx = blockIdx.x * 256 + threadIdx.x;   // over NBLKT*H
  int nb = idx >> 7, h = idx & 127;
  float s = 0.0f;
  #pragma unroll
  for (int k = 0; k < KATOM; ++k)
    s += x[(size_t)(nb*KATOM + k)*H + h];
  blocks[idx] = s * (1.0f / KATOM);
}

// ---------------- MHA v7: thread-per-row, key-split, chunked online softmax ----
template <int S, int KS>
__global__ __launch_bounds__(256) void k_attn4(
    const float* __restrict__ qkv,
    float* __restrict__ pm, float* __restrict__ pl, float* __restrict__ po)
{
  constexpr int KP = S / KS;       // keys per split
  constexpr int RCH = S / 256;     // row chunks
  constexpr int NR = BSG * NHD * S;
  constexpr int CH = 32;           // score-cache chunk
  __shared__ float Ks[KP][DH];
  __shared__ float Vs[KP][DH];
  int idx = blockIdx.x;
  int rc = idx % RCH;
  int ks = (idx / RCH) % KS;
  int bh = idx / (RCH * KS);
  int b = bh >> 3, h = bh & 7;
  const float* base = qkv + (size_t)b * S * 384;
  int tid = threadIdx.x;
  for (int t = tid; t < KP * 4; t += 256) {
    int j = t >> 2, d4 = t & 3;
    int jg = ks * KP + j;
    *(float4*)&Ks[j][d4*4] = *(const float4*)(base + (size_t)jg*384 + 128 + h*DH + d4*4);
    *(float4*)&Vs[j][d4*4] = *(const float4*)(base + (size_t)jg*384 + 256 + h*DH + d4*4);
  }
  __syncthreads();
  int s = rc * 256 + tid;
  const float4* qp = (const float4*)(base + (size_t)s * 384 + h * DH);
  float4 q0 = qp[0], q1 = qp[1], q2 = qp[2], q3 = qp[3];
  float m = -1e30f, l = 0.0f;
  float4 o0 = {0,0,0,0}, o1 = {0,0,0,0}, o2 = {0,0,0,0}, o3 = {0,0,0,0};
  for (int c0 = 0; c0 < KP; c0 += CH) {
    float scv[CH];
    float mc = -1e30f;
    #pragma unroll
    for (int j = 0; j < CH; ++j) {
      float4 k0 = *(const float4*)&Ks[c0+j][0];
      float4 k1 = *(const float4*)&Ks[c0+j][4];
      float4 k2 = *(const float4*)&Ks[c0+j][8];
      float4 k3 = *(const float4*)&Ks[c0+j][12];
      float s0 = q0.x*k0.x + q0.y*k0.y + q0.z*k0.z + q0.w*k0.w;
      float s1 = q1.x*k1.x + q1.y*k1.y + q1.z*k1.z + q1.w*k1.w;
      float s2 = q2.x*k2.x + q2.y*k2.y + q2.z*k2.z + q2.w*k2.w;
      float s3 = q3.x*k3.x + q3.y*k3.y + q3.z*k3.z + q3.w*k3.w;
      float sc = (s0 + s1) + (s2 + s3);
      scv[j] = sc;
      mc = fmaxf(mc, sc);
    }
    float mn = fmaxf(m, mc);
    float corr = __expf((m - mn) * 0.25f);
    l *= corr;
    o0.x *= corr; o0.y *= corr; o0.z *= corr; o0.w *= corr;
    o1.x *= corr; o1.y *= corr; o1.z *= corr; o1.w *= corr;
    o2.x *= corr; o2.y *= corr; o2.z *= corr; o2.w *= corr;
    o3.x *= corr; o3.y *= corr; o3.z *= corr; o3.w *= corr;
    m = mn;
    #pragma unroll
    for (int j = 0; j < CH; ++j) {
      float p = __expf((scv[j] - m) * 0.25f);
      l += p;
      float4 v0 = *(const float4*)&Vs[c0+j][0];
      float4 v1 = *(const float4*)&Vs[c0+j][4];
      float4 v2 = *(const float4*)&Vs[c0+j][8];
      float4 v3 = *(const float4*)&Vs[c0+j][12];
      o0.x += p*v0.x; o0.y += p*v0.y; o0.z += p*v0.z; o0.w += p*v0.w;
      o1.x += p*v1.x; o1.y += p*v1.y; o1.z += p*v1.z; o1.w += p*v1.w;
      o2.x += p*v2.x; o2.y += p*v2.y; o2.z += p*v2.z; o2.w += p*v2.w;
      o3.x += p*v3.x; o3.y += p*v3.y; o3.z += p*v3.z; o3.w += p*v3.w;
    }
  }
  size_t R = (size_t)bh * S + s;
  pm[(size_t)ks * NR + R] = m;
  pl[(size_t)ks * NR + R] = l;
  float4* po4 = (float4*)po;
  po4[(size_t)(ks*4 + 0) * NR + R] = o0;
  po4[(size_t)(ks*4 + 1) * NR + R] = o1;
  po4[(size_t)(ks*4 + 2) * NR + R] = o2;
  po4[(size_t)(ks*4 + 3) * NR + R] = o3;
}

// combine KS partials per row (4 threads/row, d4 wave-uniform), write normalized ea
template <int S, int KS>
__global__ __launch_bounds__(256) void k_attn4c(
    const float* __restrict__ pm, const float* __restrict__ pl,
    const float* __restrict__ po, float* __restrict__ ea)
{
  constexpr int NR = BSG * NHD * S;
  int R = blockIdx.x * 64 + (threadIdx.x & 63);
  int d4 = threadIdx.x >> 6;   // wave-uniform
  float mv[KS];
  float m = -1e30f;
  #pragma unroll
  for (int k = 0; k < KS; ++k) { mv[k] = pm[(size_t)k*NR + R]; m = fmaxf(m, mv[k]); }
  const float4* po4 = (const float4*)po;
  float l = 0.0f;
  float4 o = {0, 0, 0, 0};
  #pragma unroll
  for (int k = 0; k < KS; ++k) {
    float w = __expf((mv[k] - m) * 0.25f);
    l += pl[(size_t)k*NR + R] * w;
    float4 p = po4[(size_t)(k*4 + d4)*NR + R];
    o.x += p.x*w; o.y += p.y*w; o.z += p.z*w; o.w += p.w*w;
  }
  float inv = 1.0f / l;
  float4 r = {o.x*inv, o.y*inv, o.z*inv, o.w*inv};
  ((float4*)ea)[(size_t)d4*NR + R] = r;
}

// gather ea rows per (block, channel) via block-edge CSR; divide by cnt
__global__ __launch_bounds__(256) void k_bsum_gather(
    const float* __restrict__ ea, const int* __restrict__ blist,
    const int* __restrict__ boff, float* __restrict__ bsum)
{
  constexpr int NR = BSG * NHD * EBE;
  int idx = blockIdx.x * 256 + threadIdx.x;   // over NBLKT*32
  int i = idx >> 5, c4 = idx & 31;
  int b = i >> 6, blk = i & 63;
  int h = c4 >> 2, d4 = c4 & 3;
  int e0 = boff[b*65 + blk], e1 = boff[b*65 + blk + 1];
  const float4* ea4 = (const float4*)ea;
  size_t basein = (size_t)d4 * NR + (size_t)(b*NHD + h) * EBE;
  float4 s = {0, 0, 0, 0};
  for (int e = e0; e < e1; ++e) {
    int srow = blist[b*EBE + e];
    float4 v = ea4[basein + srow];
    s.x += v.x; s.y += v.y; s.z += v.z; s.w += v.w;
  }
  float cnt = (float)(e1 - e0);
  float sc = (cnt > 0.0f) ? (1.0f / cnt) : 0.0f;
  float4 o = {s.x*sc, s.y*sc, s.z*sc, s.w*sc};
  *(float4*)&bsum[(size_t)i*H + c4*4] = o;
}

// ---------------- block self-attention: LDS K/V, wave-reduced mean, NO atomics ----
__global__ __launch_bounds__(256) void k_attnS(
    const float* __restrict__ qkv, float* __restrict__ m2)
{
  __shared__ float Ks[4][LBLK][DH];
  __shared__ float Vs[4][LBLK][DH];
  __shared__ float red[4][LBLK][DH + 1];   // pad 17: odd stride -> conflict-free
  int b = blockIdx.x >> 1, hq = blockIdx.x & 1;
  int tid = threadIdx.x;
  const float* base = qkv + (size_t)b * LBLK * 384;
  for (int t = tid; t < 1024; t += 256) {
    int hl = t >> 8, j = (t >> 2) & 63, d4 = t & 3;
    int h = hq*4 + hl;
    *(float4*)&Ks[hl][j][d4*4] = *(const float4*)(base + (size_t)j*384 + 128 + h*DH + d4*4);
    *(float4*)&Vs[hl][j][d4*4] = *(const float4*)(base + (size_t)j*384 + 256 + h*DH + d4*4);
  }
  __syncthreads();
  int hl = tid >> 6, s = tid & 63;   // hl uniform per wave; wave owns (b, h)
  int h = hq*4 + hl;
  const float4* qp = (const float4*)(base + (size_t)s * 384 + h * DH);
  float4 q0 = qp[0], q1 = qp[1], q2 = qp[2], q3 = qp[3];
  float m = -1e30f, l = 0.0f;
  float4 o0 = {0,0,0,0}, o1 = {0,0,0,0}, o2 = {0,0,0,0}, o3 = {0,0,0,0};
  for (int c0 = 0; c0 < LBLK; c0 += 32) {
    float scv[32];
    float mc = -1e30f;
    #pragma unroll
    for (int j = 0; j < 32; ++j) {
      float4 k0 = *(const float4*)&Ks[hl][c0+j][0];
      float4 k1 = *(const float4*)&Ks[hl][c0+j][4];
      float4 k2 = *(const float4*)&Ks[hl][c0+j][8];
      float4 k3 = *(const float4*)&Ks[hl][c0+j][12];
      float s0 = q0.x*k0.x + q0.y*k0.y + q0.z*k0.z + q0.w*k0.w;
      float s1 = q1.x*k1.x + q1.y*k1.y + q1.z*k1.z + q1.w*k1.w;
      float s2 = q2.x*k2.x + q2.y*k2.y + q2.z*k2.z + q2.w*k2.w;
      float s3 = q3.x*k3.x + q3.y*k3.y + q3.z*k3.z + q3.w*k3.w;
      float sc = (s0 + s1) + (s2 + s3);
      scv[j] = sc;
      mc = fmaxf(mc, sc);
    }
    float mn = fmaxf(m, mc);
    float corr = __expf((m - mn) * 0.25f);
    l *= corr;
    o0.x *= corr; o0.y *= corr; o0.z *= corr; o0.w *= corr;
    o1.x *= corr; o1.y *= corr; o1.z *= corr; o1.w *= corr;
    o2.x *= corr; o2.y *= corr; o2.z *= corr; o2.w *= corr;
    o3.x *= corr; o3.y *= corr; o3.z *= corr; o3.w *= corr;
    m = mn;
    #pragma unroll
    for (int j = 0; j < 32; ++j) {
      float p = __expf((scv[j] - m) * 0.25f);
      l += p;
      float4 v0 = *(const float4*)&Vs[hl][c0+j][0];
      float4 v1 = *(const float4*)&Vs[hl][c0+j][4];
      float4 v2 = *(const float4*)&Vs[hl][c0+j][8];
      float4 v3 = *(const float4*)&Vs[hl][c0+j][12];
      o0.x += p*v0.x; o0.y += p*v0.y; o0.z += p*v0.z; o0.w += p*v0.w;
      o1.x += p*v1.x; o1.y += p*v1.y; o1.z += p*v1.z; o1.w += p*v1.w;
      o2.x += p*v2.x; o2.y += p*v2.y; o2.z += p*v2.z; o2.w += p*v2.w;
      o3.x += p*v3.x; o3.y += p*v3.y; o3.z += p*v3.z; o3.w += p*v3.w;
    }
  }
  // normalize this row's output and stash in LDS (17-stride, conflict-free)
  float inv = (1.0f / l) * (1.0f / 64.0f);
  float ov[DH] = {o0.x,o0.y,o0.z,o0.w, o1.x,o1.y,o1.z,o1.w,
                  o2.x,o2.y,o2.z,o2.w, o3.x,o3.y,o3.z,o3.w};
  #pragma unroll
  for (int d = 0; d < DH; ++d) red[hl][s][d] = ov[d] * inv;
  __syncthreads();
  // wave owns (b,h): lanes 0..15 sum the 64 rows, plain store (no atomics)
  if (s < DH) {
    float acc = 0.0f;
    for (int r = 0; r < LBLK; ++r) acc += red[hl][r][s];
    m2[(size_t)b * H + h * DH + s] = acc;
  }
}

// ---------------- final: out-proj + LN + 3-layer MLP ----------------
__device__ __forceinline__ float bsum128(float v, float* red) {
  int t = threadIdx.x;
  red[t] = v; __syncthreads();
  #pragma unroll
  for (int off = 64; off > 0; off >>= 1) {
    if (t < off) red[t] += red[t + off];
    __syncthreads();
  }
  float s = red[0];
  __syncthreads();
  return s;
}

__global__ __launch_bounds__(128) void k_final(
    const float* __restrict__ m2, const float* __restrict__ out_w,
    const float* __restrict__ out_b, const float* __restrict__ lng,
    const float* __restrict__ lnb, const float* __restrict__ w1,
    const float* __restrict__ b1, const float* __restrict__ w2,
    const float* __restrict__ b2, const float* __restrict__ w3,
    const float* __restrict__ b3, float* __restrict__ out)
{
  __shared__ float buf[128];
  __shared__ float red[128];
  int b = blockIdx.x, t = threadIdx.x;
  buf[t] = m2[b*H + t];
  __syncthreads();
  float g = out_b[t];
  for (int k = 0; k < H; ++k) g += buf[k] * out_w[k*H + t];
  float mu = bsum128(g, red) * (1.0f / H);
  float df = g - mu;
  float var = bsum128(df * df, red) * (1.0f / H);
  float gn = df / sqrtf(var + 1e-5f) * lng[t] + lnb[t];
  __syncthreads();
  buf[t] = gn; __syncthreads();
  float h1 = b1[t];
  for (int k = 0; k < H; ++k) h1 += buf[k] * w1[k*H + t];
  h1 = fmaxf(h1, 0.0f);
  __syncthreads();
  buf[t] = h1; __syncthreads();
  float h2 = b2[t];
  for (int k = 0; k < H; ++k) h2 += buf[k] * w2[k*H + t];
  h2 = fmaxf(h2, 0.0f);
  float tot = bsum128(h2 * w3[t], red);
  if (t == 0) out[b] = tot + b3[0];
}

extern "C" void kernel_launch(void* const* d_in, const int* in_sizes, int n_in,
                              void* d_out, int out_size, void* d_ws, size_t ws_size,
                              hipStream_t stream) {
  (void)in_sizes; (void)n_in; (void)out_size; (void)ws_size;
  const int*   A          = (const int*)d_in[0];
  const int*   apos       = (const int*)d_in[1];
  const int*   btypes     = (const int*)d_in[2];
  const float* coords     = (const float*)d_in[3];
  const int*   edge_index = (const int*)d_in[4];
  const int*   bedges     = (const int*)d_in[5];
  const float* emb_atom   = (const float*)d_in[6];
  const float* emb_pos    = (const float*)d_in[7];
  const float* emb_block  = (const float*)d_in[8];
  const float* rbf_freq   = (const float*)d_in[9];
  const float* inter_w1   = (const float*)d_in[10];
  const float* inter_b1   = (const float*)d_in[11];
  const float* inter_w2   = (const float*)d_in[12];
  const float* inter_b2   = (const float*)d_in[13];
  const float* upd_w1     = (const float*)d_in[14];
  const float* upd_b1     = (const float*)d_in[15];
  const float* upd_w2     = (const float*)d_in[16];
  const float* upd_b2     = (const float*)d_in[17];
  const float* edge_w1    = (const float*)d_in[18];
  const float* edge_b1    = (const float*)d_in[19];
  const float* edge_w2    = (const float*)d_in[20];
  const float* edge_b2    = (const float*)d_in[21];
  const float* attn_in_w  = (const float*)d_in[22];
  const float* attn_in_b  = (const float*)d_in[23];
  const float* attn_out_w = (const float*)d_in[24];
  const float* attn_out_b = (const float*)d_in[25];
  const float* ln_g       = (const float*)d_in[26];
  const float* ln_b       = (const float*)d_in[27];
  const float* fin_w1     = (const float*)d_in[28];
  const float* fin_b1     = (const float*)d_in[29];
  const float* fin_w2     = (const float*)d_in[30];
  const float* fin_b2     = (const float*)d_in[31];
  const float* fin_w3     = (const float*)d_in[32];
  const float* fin_b3     = (const float*)d_in[33];
  float* out = (float*)d_out;

  float* ws = (float*)d_ws;
  float* x      = ws + 0;
  float* P      = ws + 2097152;
  float* Q      = ws + 4194304;
  float* Hagg   = ws + 6291456;
  float* rbf_s  = ws + 8388608;    // E*6 (sorted RBF)
  float* cntf   = ws + 9961472;    // NA
  float* blocks = ws + 9977856;    // NBLKT*H
  float* Pb     = ws + 10108928;
  float* Qb     = ws + 10240000;
  float* qkv    = ws + 12468224;   // BSG*EBE*384
  float* bsum   = ws + 15613952;   // NBLKT*H
  float* ind    = ws + 15746048;   // NBLKT
  float* m2     = ws + 15747072;   // BSG*H
  int* blist    = (int*)(ws + 15749120);  // BSG*EBE ints
  int* boff     = (int*)(ws + 15757312);  // BSG*65 ints
  // sort scratch + wprep live in the old-Epre region (dead until attention):
  int* ej_s   = (int*)(ws + 10371072);          // NE ints
  int* off    = (int*)(ws + 10371072 + 262144); // NA+1 ints
  int* cur    = (int*)(ws + 10371072 + 278784); // NA ints
  int* cnt    = (int*)(ws + 10371072 + 295168); // NA ints
  float* wbuf = ws + 10371072 + 311552;         // 2 x 256*128 floats
  float* bvec = ws + 10371072 + 311552 + 65536; // 2 x 128 floats
  // attention partials (KS=8, split-major) reuse x/P/Q/Hagg/rbf_s regions:
  float* part_m = ws + 0;          // 8*65536 = 524288 floats
  float* part_l = ws + 524288;     // 524288 floats
  float* part_o = ws + 1048576;    // 8*65536*16 = 8388608 floats -> ends 9437184
  float* ea     = ws + 10371072;   // 65536*16 = 1048576 floats (old Epre region)

  const int* ei = edge_index;
  const int* ej = edge_index + NE;

  // ---- edge sort (once; reused by both interaction blocks) ----
  (void)hipMemsetAsync(cnt, 0, NA * sizeof(int), stream);
  k_hist<<<NE/256, 256, 0, stream>>>(ei, cnt);
  k_scan<<<1, 1024, 0, stream>>>(cnt, off, cur, cntf);
  k_scatter<<<NE/256, 256, 0, stream>>>(ei, ej, coords, rbf_freq, cur, ej_s, rbf_s);
  k_bedge_csr<<<BSG, 256, 0, stream>>>(bedges, blist, boff, ind);
  // both interaction blocks' weight preps in one launch
  k_wprep<<<dim3(128, 2), 128, 0, stream>>>(inter_w2, upd_w1, inter_b2, wbuf, bvec);

  k_embed<<<NA*H/256, 256, 0, stream>>>(A, apos, btypes, emb_atom, emb_pos, emb_block, x);

  for (int b = 0; b < NBI; ++b) {
    const float* w1 = inter_w1 + (size_t)b * 262 * H;
    // fused: P = x@W1a + b1 (y=0) ; Q = x@W1b (y=1, no bias)
    gemm128<<<dim3(NA/32, 2), 256, 0, stream>>>(x, nullptr, w1, H, 0, inter_b1 + b*H,
                                                nullptr, nullptr, nullptr,
                                                P, H, 0, NA, H, 0, 0, 128, 2097152);
    k_edge_csr<<<NA/8, 256, 0, stream>>>(P, Q, rbf_s, w1 + 256*H, ej_s, off, Hagg);
    // chained: U = silu([x|Hagg]@wbuf + b1 + cnt*bvec); x = U@upd_w2 + b2 + x
    k_upd_chain<<<NA/32, 256, 0, stream>>>(x, Hagg, wbuf + (size_t)b*32768,
                                           upd_b1 + b*H, bvec + b*H, cntf,
                                           upd_w2 + (size_t)b*H*H, upd_b2 + b*H, x);
  }

  k_block_mean<<<NBLKT*H/256, 256, 0, stream>>>(x, blocks);
  // fused: Pb = blocks@edge_w1a + b (y=0) ; Qb = blocks@edge_w1b (y=1)
  gemm128<<<dim3(NBLKT/32, 2), 256, 0, stream>>>(blocks, nullptr, edge_w1, H, 0, edge_b1,
                                                 nullptr, nullptr, nullptr,
                                                 Pb, H, 0, NBLKT, H, 0, 0, 128, 131072);
  // fused: Epre gather+relu -> @edge_w2+b -> @attn_in_w+b -> qkv
  k_eprep<<<BSG*EBE/32, 256, 0, stream>>>(Pb, Qb, bedges, edge_w2, edge_b2,
                                          attn_in_w, attn_in_b, qkv);
  k_attn4<EBE, 8><<<BSG*NHD*8*(EBE/256), 256, 0, stream>>>(qkv, part_m, part_l, part_o);
  k_attn4c<EBE, 8><<<BSG*NHD*EBE/64, 256, 0, stream>>>(part_m, part_l, part_o, ea);
  k_bsum_gather<<<NBLKT*32/256, 256, 0, stream>>>(ea, blist, boff, bsum);
  // blocks += (bsum/cnt)@out_w + out_b*[cnt>0]
  gemm128<<<NBLKT/32, 256, 0, stream>>>(bsum, nullptr, attn_out_w, H, 0, nullptr,
                                        attn_out_b, ind, blocks, blocks, H, 0,
                                        NBLKT, H, 0, 0, 0, 0);
  gemm128<<<dim3(NBLKT/32, 3), 256, 0, stream>>>(blocks, nullptr, attn_in_w, 384, 0,
                                                 attn_in_b, nullptr, nullptr, nullptr,
                                                 qkv, 384, 0, NBLKT, H, 0, 128, 0, 0);
  k_attnS<<<BSG*2, 256, 0, stream>>>(qkv, m2);
  k_final<<<BSG, 128, 0, stream>>>(m2, attn_out_w, attn_out_b, ln_g, ln_b,
                                   fin_w1, fin_b1, fin_w2, fin_b2, fin_w3, fin_b3, out);
}

// Round 22
// 537.614 us; speedup vs baseline: 1.1531x; 1.0334x over previous
//
#include <hip/hip_runtime.h>
#include <math.h>

#define H 128
#define NHD 8
#define DH 16
#define RB 6
#define NBI 2
#define BSG 16
#define LBLK 64
#define KATOM 16
#define NBLKT 1024
#define NA 16384
#define NE 262144
#define EBE 512

__device__ __forceinline__ float atomAddF(float* p, float v) {
#if defined(__gfx90a__) || defined(__gfx940__) || defined(__gfx941__) || defined(__gfx942__) || defined(__gfx950__)
  return unsafeAtomicAdd(p, v);
#else
  return atomicAdd(p, v);
#endif
}

__device__ __forceinline__ float fsilu(float v) {
  return v * __builtin_amdgcn_rcpf(1.0f + __expf(-v));
}

// ---------------- embedding ----------------
__global__ __launch_bounds__(256) void k_embed(
    const int* __restrict__ A, const int* __restrict__ apos,
    const int* __restrict__ btypes,
    const float* __restrict__ emb_atom, const float* __restrict__ emb_pos,
    const float* __restrict__ emb_block, float* __restrict__ x)
{
  int idx = blockIdx.x * 256 + threadIdx.x;   // over NA*H
  int n = idx >> 7, h = idx & 127;
  x[idx] = emb_atom[A[n] * H + h] + emb_pos[apos[n] * H + h]
         + emb_block[btypes[n >> 4] * H + h];
}

// ---------------- edge sort: histogram ----------------
__global__ __launch_bounds__(256) void k_hist(
    const int* __restrict__ ei, int* __restrict__ cnt)
{
  int e = blockIdx.x * 256 + threadIdx.x;
  atomicAdd(&cnt[ei[e]], 1);
}

// ---------------- edge sort: scan (single block, 1024 thr, 16 bins each) ----
__global__ __launch_bounds__(1024) void k_scan(
    const int* __restrict__ cnt, int* __restrict__ off,
    int* __restrict__ cur, float* __restrict__ cntf)
{
  __shared__ int ps[1024];
  int t = threadIdx.x;
  int base = t * 16;
  int local[16];
  int s = 0;
  #pragma unroll
  for (int k = 0; k < 16; ++k) { local[k] = s; s += cnt[base + k]; }
  ps[t] = s;
  __syncthreads();
  for (int d = 1; d < 1024; d <<= 1) {
    int v = (t >= d) ? ps[t - d] : 0;
    __syncthreads();
    ps[t] += v;
    __syncthreads();
  }
  int offset = (t == 0) ? 0 : ps[t - 1];
  #pragma unroll
  for (int k = 0; k < 16; ++k) {
    int o = offset + local[k];
    off[base + k] = o;
    cur[base + k] = o;
    cntf[base + k] = (float)cnt[base + k];
  }
  if (t == 1023) off[NA] = offset + s;
}

// ---------------- edge sort: scatter + fused RBF ----------------
__global__ __launch_bounds__(256) void k_scatter(
    const int* __restrict__ ei, const int* __restrict__ ej,
    const float* __restrict__ coords, const float* __restrict__ freq,
    int* __restrict__ cur, int* __restrict__ ej_s, float* __restrict__ rbf_s)
{
  int e = blockIdx.x * 256 + threadIdx.x;
  int i = ei[e], j = ej[e];
  int pos = atomicAdd(&cur[i], 1);
  ej_s[pos] = j;
  float dx = coords[i*3+0] - coords[j*3+0];
  float dy = coords[i*3+1] - coords[j*3+1];
  float dz = coords[i*3+2] - coords[j*3+2];
  float d = sqrtf(dx*dx + dy*dy + dz*dz);
  float u = fmaxf(d * 0.125f, 1e-3f);
  float u2 = u*u, u4 = u2*u2, u5 = u4*u, u6 = u5*u, u7 = u6*u;
  float env = 1.0f/u - 28.0f*u5 + 48.0f*u6 - 21.0f*u7;
  #pragma unroll
  for (int r = 0; r < RB; ++r)
    rbf_s[(size_t)pos*RB + r] = env * sinf(freq[r] * u);
}

// ---------------- block-edge CSR (per-graph src buckets) ----------------
__global__ __launch_bounds__(256) void k_bedge_csr(
    const int* __restrict__ bedges, int* __restrict__ blist,
    int* __restrict__ boff, float* __restrict__ ind)
{
  __shared__ int hist[64], offs[65], curs[64];
  int b = blockIdx.x, t = threadIdx.x;
  if (t < 64) hist[t] = 0;
  __syncthreads();
  for (int e = t; e < EBE; e += 256) atomicAdd(&hist[bedges[(b*EBE + e)*2]], 1);
  __syncthreads();
  if (t == 0) {
    offs[0] = 0;
    for (int k = 0; k < 64; ++k) offs[k+1] = offs[k] + hist[k];
  }
  __syncthreads();
  if (t < 64) curs[t] = offs[t];
  __syncthreads();
  for (int e = t; e < EBE; e += 256) {
    int src = bedges[(b*EBE + e)*2];
    int pos = atomicAdd(&curs[src], 1);
    blist[b*EBE + pos] = e;
  }
  if (t < 65) boff[b*65 + t] = offs[t];
  if (t < 64) ind[b*64 + t] = (hist[t] > 0) ? 1.0f : 0.0f;
}

// ---------------- per-atom CSR edge pass v2 (float4 channels, no atomics) ----
__global__ __launch_bounds__(256) void k_edge_csr(
    const float* __restrict__ P, const float* __restrict__ Q,
    const float* __restrict__ rbf_s, const float* __restrict__ W1c,
    const int* __restrict__ ej_s, const int* __restrict__ off,
    float* __restrict__ Hagg)
{
  __shared__ float w[RB * H];
  for (int idx = threadIdx.x; idx < RB * H; idx += 256) w[idx] = W1c[idx];
  __syncthreads();
  int c4 = threadIdx.x & 31;        // channel quad
  int sub = threadIdx.x >> 5;       // atom within block
  int i = blockIdx.x * 8 + sub;
  int e0 = off[i], e1 = off[i + 1];
  float4 pv = *(const float4*)&P[(size_t)i * H + c4 * 4];
  float4 W0 = *(const float4*)&w[0*H + c4*4];
  float4 W1 = *(const float4*)&w[1*H + c4*4];
  float4 W2 = *(const float4*)&w[2*H + c4*4];
  float4 W3 = *(const float4*)&w[3*H + c4*4];
  float4 W4 = *(const float4*)&w[4*H + c4*4];
  float4 W5 = *(const float4*)&w[5*H + c4*4];
  float4 acc = {0, 0, 0, 0};
  for (int e = e0; e < e1; ++e) {
    int j = ej_s[e];
    float4 qv = *(const float4*)&Q[(size_t)j * H + c4 * 4];
    const float* rb = &rbf_s[(size_t)e * RB];
    float r0 = rb[0], r1 = rb[1], r2 = rb[2], r3 = rb[3], r4 = rb[4], r5 = rb[5];
    float4 v;
    v.x = pv.x + qv.x + r0*W0.x + r1*W1.x + r2*W2.x + r3*W3.x + r4*W4.x + r5*W5.x;
    v.y = pv.y + qv.y + r0*W0.y + r1*W1.y + r2*W2.y + r3*W3.y + r4*W4.y + r5*W5.y;
    v.z = pv.z + qv.z + r0*W0.z + r1*W1.z + r2*W2.z + r3*W3.z + r4*W4.z + r5*W5.z;
    v.w = pv.w + qv.w + r0*W0.w + r1*W1.w + r2*W2.w + r3*W3.w + r4*W4.w + r5*W5.w;
    acc.x += fsilu(v.x);
    acc.y += fsilu(v.y);
    acc.z += fsilu(v.z);
    acc.w += fsilu(v.w);
  }
  *(float4*)&Hagg[(size_t)i * H + c4 * 4] = acc;
}

// ---------------- weight prep (both blocks in one launch via blockIdx.y) ----
__global__ __launch_bounds__(128) void k_wprep(
    const float* __restrict__ W2base, const float* __restrict__ U1base,
    const float* __restrict__ b2base, float* __restrict__ wbufbase,
    float* __restrict__ bvecbase)
{
  int y = blockIdx.y;
  const float* W2 = W2base + (size_t)y * H * H;
  const float* U1 = U1base + (size_t)y * 2 * H * H;
  const float* b2 = b2base + y * H;
  float* wbuf = wbufbase + (size_t)y * 256 * H;
  float* bvec = bvecbase + y * H;
  int k = blockIdx.x, c = threadIdx.x;
  const float* U1b = U1 + 128 * H;
  wbuf[k * H + c] = U1[k * H + c];
  float s = 0.0f;
  for (int t = 0; t < H; ++t) s += W2[k * H + t] * U1b[t * H + c];
  wbuf[(128 + k) * H + c] = s;
  if (k == 0) {
    float sb = 0.0f;
    for (int t = 0; t < H; ++t) sb += b2[t] * U1b[t * H + c];
    bvec[c] = sb;
  }
}

// ---------------- generic 128-col GEMM v2 + row-mode y fusion ----------------
__global__ __launch_bounds__(256) void gemm128(
    const float* __restrict__ A1, const float* __restrict__ A2,
    const float* __restrict__ W, int ldw, int wcol0,
    const float* __restrict__ bias, const float* __restrict__ bias2,
    const float* __restrict__ bias_scale,
    const float* __restrict__ res,
    float* __restrict__ C, int ldc, int ccol0,
    int M, int Ktot, int act, int ymul, int wrowmul, long long cymul)
{
  __shared__ float As[32][256];
  __shared__ float Ws[16][128];
  int tid = threadIdx.x;
  int m0 = blockIdx.x * 32;
  int yoff = blockIdx.y * ymul;
  W += (size_t)blockIdx.y * wrowmul * ldw;
  C += (size_t)blockIdx.y * cymul;
  bool doBias = (ymul != 0) || (blockIdx.y == 0);
  for (int idx = tid; idx < 32*32; idx += 256) {
    int r = idx >> 5, k4 = idx & 31;
    float4 v = *(const float4*)&A1[(size_t)(m0 + r)*H + k4*4];
    *(float4*)&As[r][k4*4] = v;
  }
  if (A2) {
    for (int idx = tid; idx < 32*32; idx += 256) {
      int r = idx >> 5, k4 = idx & 31;
      float4 v = *(const float4*)&A2[(size_t)(m0 + r)*H + k4*4];
      *(float4*)&As[r][128 + k4*4] = v;
    }
  }
  int rr = tid >> 5;    // 0..7
  int cq = tid & 31;    // col quad
  float acc[4][4] = {};
  for (int kk0 = 0; kk0 < Ktot; kk0 += 16) {
    __syncthreads();
    for (int idx = tid; idx < 16*32; idx += 256) {
      int kr = idx >> 5, c4 = idx & 31;
      float4 v = *(const float4*)&W[(size_t)(kk0 + kr)*ldw + wcol0 + yoff + c4*4];
      *(float4*)&Ws[kr][c4*4] = v;
    }
    __syncthreads();
    #pragma unroll
    for (int k4 = 0; k4 < 4; ++k4) {
      float4 w0 = *(const float4*)&Ws[k4*4+0][cq*4];
      float4 w1 = *(const float4*)&Ws[k4*4+1][cq*4];
      float4 w2 = *(const float4*)&Ws[k4*4+2][cq*4];
      float4 w3 = *(const float4*)&Ws[k4*4+3][cq*4];
      #pragma unroll
      for (int i = 0; i < 4; ++i) {
        float4 a = *(const float4*)&As[rr + 8*i][kk0 + k4*4];
        acc[i][0] += a.x*w0.x + a.y*w1.x + a.z*w2.x + a.w*w3.x;
        acc[i][1] += a.x*w0.y + a.y*w1.y + a.z*w2.y + a.w*w3.y;
        acc[i][2] += a.x*w0.z + a.y*w1.z + a.z*w2.z + a.w*w3.z;
        acc[i][3] += a.x*w0.w + a.y*w1.w + a.z*w2.w + a.w*w3.w;
      }
    }
  }
  #pragma unroll
  for (int i = 0; i < 4; ++i) {
    int m = m0 + rr + 8*i;
    float bs = bias_scale ? bias_scale[m] : 1.0f;
    float4 out;
    float* po = &out.x;
    #pragma unroll
    for (int j = 0; j < 4; ++j) {
      int c = cq*4 + j;
      float v = acc[i][j];
      if (bias && doBias) v += bias[yoff + c];
      if (bias2 && doBias) v += bias2[yoff + c] * bs;
      if (act == 1) v = fsilu(v);
      else if (act == 2) v = fmaxf(v, 0.0f);
      if (res) v += res[(size_t)m*H + c];
      po[j] = v;
    }
    *(float4*)&C[(size_t)m*ldc + ccol0 + yoff + cq*4] = out;
  }
}

// ---------------- chained update: U = silu([x|Hagg]@W1 + b1 + cnt*bvec);
//                  xout = U@W2 + b2 + x  (one kernel, U stays in LDS) --------
__global__ __launch_bounds__(256) void k_upd_chain(
    const float* __restrict__ x, const float* __restrict__ Hagg,
    const float* __restrict__ W1,    // wbuf [256][128]
    const float* __restrict__ b1, const float* __restrict__ bvec,
    const float* __restrict__ cntf,
    const float* __restrict__ W2,    // upd_w2 [128][128]
    const float* __restrict__ b2,
    float* __restrict__ xout)
{
  __shared__ float As[32][256];   // 32 KB
  __shared__ float Ws[16][128];   // 8 KB
  __shared__ float Us[32][128];   // 16 KB  -> 56 KB total, 2 blocks/CU
  int tid = threadIdx.x;
  int m0 = blockIdx.x * 32;
  for (int idx = tid; idx < 32*32; idx += 256) {
    int r = idx >> 5, k4 = idx & 31;
    *(float4*)&As[r][k4*4] = *(const float4*)&x[(size_t)(m0 + r)*H + k4*4];
    *(float4*)&As[r][128 + k4*4] = *(const float4*)&Hagg[(size_t)(m0 + r)*H + k4*4];
  }
  int rr = tid >> 5;    // 0..7
  int cq = tid & 31;    // col quad
  float acc[4][4] = {};
  for (int kk0 = 0; kk0 < 256; kk0 += 16) {
    __syncthreads();
    for (int idx = tid; idx < 16*32; idx += 256) {
      int kr = idx >> 5, c4 = idx & 31;
      *(float4*)&Ws[kr][c4*4] = *(const float4*)&W1[(size_t)(kk0 + kr)*H + c4*4];
    }
    __syncthreads();
    #pragma unroll
    for (int k4 = 0; k4 < 4; ++k4) {
      float4 w0 = *(const float4*)&Ws[k4*4+0][cq*4];
      float4 w1 = *(const float4*)&Ws[k4*4+1][cq*4];
      float4 w2 = *(const float4*)&Ws[k4*4+2][cq*4];
      float4 w3 = *(const float4*)&Ws[k4*4+3][cq*4];
      #pragma unroll
      for (int i = 0; i < 4; ++i) {
        float4 a = *(const float4*)&As[rr + 8*i][kk0 + k4*4];
        acc[i][0] += a.x*w0.x + a.y*w1.x + a.z*w2.x + a.w*w3.x;
        acc[i][1] += a.x*w0.y + a.y*w1.y + a.z*w2.y + a.w*w3.y;
        acc[i][2] += a.x*w0.z + a.y*w1.z + a.z*w2.z + a.w*w3.z;
        acc[i][3] += a.x*w0.w + a.y*w1.w + a.z*w2.w + a.w*w3.w;
      }
    }
  }
  #pragma unroll
  for (int i = 0; i < 4; ++i) {
    int m = m0 + rr + 8*i;
    float bs = cntf[m];
    float4 u;
    float* pu = &u.x;
    #pragma unroll
    for (int j = 0; j < 4; ++j) {
      int c = cq*4 + j;
      float v = acc[i][j] + b1[c] + bvec[c] * bs;
      pu[j] = fsilu(v);
    }
    *(float4*)&Us[rr + 8*i][cq*4] = u;
    acc[i][0] = 0.0f; acc[i][1] = 0.0f; acc[i][2] = 0.0f; acc[i][3] = 0.0f;
  }
  for (int kk0 = 0; kk0 < 128; kk0 += 16) {
    __syncthreads();
    for (int idx = tid; idx < 16*32; idx += 256) {
      int kr = idx >> 5, c4 = idx & 31;
      *(float4*)&Ws[kr][c4*4] = *(const float4*)&W2[(size_t)(kk0 + kr)*H + c4*4];
    }
    __syncthreads();
    #pragma unroll
    for (int k4 = 0; k4 < 4; ++k4) {
      float4 w0 = *(const float4*)&Ws[k4*4+0][cq*4];
      float4 w1 = *(const float4*)&Ws[k4*4+1][cq*4];
      float4 w2 = *(const float4*)&Ws[k4*4+2][cq*4];
      float4 w3 = *(const float4*)&Ws[k4*4+3][cq*4];
      #pragma unroll
      for (int i = 0; i < 4; ++i) {
        float4 a = *(const float4*)&Us[rr + 8*i][kk0 + k4*4];
        acc[i][0] += a.x*w0.x + a.y*w1.x + a.z*w2.x + a.w*w3.x;
        acc[i][1] += a.x*w0.y + a.y*w1.y + a.z*w2.y + a.w*w3.y;
        acc[i][2] += a.x*w0.z + a.y*w1.z + a.z*w2.z + a.w*w3.z;
        acc[i][3] += a.x*w0.w + a.y*w1.w + a.z*w2.w + a.w*w3.w;
      }
    }
  }
  #pragma unroll
  for (int i = 0; i < 4; ++i) {
    int m = m0 + rr + 8*i;
    float4 out;
    float* po = &out.x;
    #pragma unroll
    for (int j = 0; j < 4; ++j) {
      int c = cq*4 + j;
      po[j] = acc[i][j] + b2[c] + x[(size_t)m*H + c];
    }
    *(float4*)&xout[(size_t)m*H + cq*4] = out;
  }
}

// ---------------- fused block-edge prep v2: y-split over qkv chunks ----------
// Every block: gather+relu -> ef2 tile (stage 1, redundant across y).
// Block y writes only qkv chunk y (stage 2). Grid (256, 3) -> 3 blocks/CU.
__global__ __launch_bounds__(256) void k_eprep(
    const float* __restrict__ Pb, const float* __restrict__ Qb,
    const int* __restrict__ bedges,
    const float* __restrict__ W2e, const float* __restrict__ b2e,
    const float* __restrict__ Win, const float* __restrict__ bin,
    float* __restrict__ qkv)
{
  __shared__ float As[32][128];   // Epre tile (16 KB)
  __shared__ float Ws[16][128];   // weight panel (8 KB)
  __shared__ float Us[32][128];   // ef2 tile (16 KB)  -> 40 KB total
  int tid = threadIdx.x;
  int m0 = blockIdx.x * 32;
  int chunk = blockIdx.y;
  // gather + relu Epre tile
  for (int idx = tid; idx < 32*32; idx += 256) {
    int r = idx >> 5, k4 = idx & 31;
    int row = m0 + r;
    int g = row >> 9;
    int src = bedges[row*2], dst = bedges[row*2 + 1];
    float4 pv = *(const float4*)&Pb[(size_t)(g*LBLK + src)*H + k4*4];
    float4 qv = *(const float4*)&Qb[(size_t)(g*LBLK + dst)*H + k4*4];
    float4 v;
    v.x = fmaxf(pv.x + qv.x, 0.0f);
    v.y = fmaxf(pv.y + qv.y, 0.0f);
    v.z = fmaxf(pv.z + qv.z, 0.0f);
    v.w = fmaxf(pv.w + qv.w, 0.0f);
    *(float4*)&As[r][k4*4] = v;
  }
  int rr = tid >> 5;    // 0..7
  int cq = tid & 31;    // col quad
  float acc[4][4] = {};
  // stage 1: ef2 = Epre @ edge_w2 + b2e  (K=128)
  for (int kk0 = 0; kk0 < 128; kk0 += 16) {
    __syncthreads();
    for (int idx = tid; idx < 16*32; idx += 256) {
      int kr = idx >> 5, c4 = idx & 31;
      *(float4*)&Ws[kr][c4*4] = *(const float4*)&W2e[(size_t)(kk0 + kr)*H + c4*4];
    }
    __syncthreads();
    #pragma unroll
    for (int k4 = 0; k4 < 4; ++k4) {
      float4 w0 = *(const float4*)&Ws[k4*4+0][cq*4];
      float4 w1 = *(const float4*)&Ws[k4*4+1][cq*4];
      float4 w2 = *(const float4*)&Ws[k4*4+2][cq*4];
      float4 w3 = *(const float4*)&Ws[k4*4+3][cq*4];
      #pragma unroll
      for (int i = 0; i < 4; ++i) {
        float4 a = *(const float4*)&As[rr + 8*i][kk0 + k4*4];
        acc[i][0] += a.x*w0.x + a.y*w1.x + a.z*w2.x + a.w*w3.x;
        acc[i][1] += a.x*w0.y + a.y*w1.y + a.z*w2.y + a.w*w3.y;
        acc[i][2] += a.x*w0.z + a.y*w1.z + a.z*w2.z + a.w*w3.z;
        acc[i][3] += a.x*w0.w + a.y*w1.w + a.z*w2.w + a.w*w3.w;
      }
    }
  }
  #pragma unroll
  for (int i = 0; i < 4; ++i) {
    float4 u;
    float* pu = &u.x;
    #pragma unroll
    for (int j = 0; j < 4; ++j) pu[j] = acc[i][j] + b2e[cq*4 + j];
    *(float4*)&Us[rr + 8*i][cq*4] = u;
    acc[i][0] = 0.0f; acc[i][1] = 0.0f; acc[i][2] = 0.0f; acc[i][3] = 0.0f;
  }
  // stage 2: qkv[:, chunk*128..] = ef2 @ attn_in_w + bin  (only own chunk)
  for (int kk0 = 0; kk0 < 128; kk0 += 16) {
    __syncthreads();
    for (int idx = tid; idx < 16*32; idx += 256) {
      int kr = idx >> 5, c4 = idx & 31;
      *(float4*)&Ws[kr][c4*4] =
          *(const float4*)&Win[(size_t)(kk0 + kr)*384 + chunk*128 + c4*4];
    }
    __syncthreads();
    #pragma unroll
    for (int k4 = 0; k4 < 4; ++k4) {
      float4 w0 = *(const float4*)&Ws[k4*4+0][cq*4];
      float4 w1 = *(const float4*)&Ws[k4*4+1][cq*4];
      float4 w2 = *(const float4*)&Ws[k4*4+2][cq*4];
      float4 w3 = *(const float4*)&Ws[k4*4+3][cq*4];
      #pragma unroll
      for (int i = 0; i < 4; ++i) {
        float4 a = *(const float4*)&Us[rr + 8*i][kk0 + k4*4];
        acc[i][0] += a.x*w0.x + a.y*w1.x + a.z*w2.x + a.w*w3.x;
        acc[i][1] += a.x*w0.y + a.y*w1.y + a.z*w2.y + a.w*w3.y;
        acc[i][2] += a.x*w0.z + a.y*w1.z + a.z*w2.z + a.w*w3.z;
        acc[i][3] += a.x*w0.w + a.y*w1.w + a.z*w2.w + a.w*w3.w;
      }
    }
  }
  #pragma unroll
  for (int i = 0; i < 4; ++i) {
    int m = m0 + rr + 8*i;
    float4 out;
    float* po = &out.x;
    #pragma unroll
    for (int j = 0; j < 4; ++j)
      po[j] = acc[i][j] + bin[chunk*128 + cq*4 + j];
    *(float4*)&qkv[(size_t)m*384 + chunk*128 + cq*4] = out;
  }
}

// ---------------- block mean over K atoms ----------------
__global__ __launch_bounds__(256) void k_block_mean(
    const float* __restrict__ x, float* __restrict__ blocks)
{
  int idx = blockIdx.x * 256 + threadIdx.x;   // over NBLKT*H
  int nb = idx >> 7, h = idx & 127;
  float s = 0.0f;
  #pragma unroll
  for (int k = 0; k < KATOM; ++k)
    s += x[(size_t)(nb*KATOM + k)*H + h];
  blocks[idx] = s * (1.0f / KATOM);
}

// ---------------- MHA v7: thread-per-row, key-split, chunked online softmax ----
template <int S, int KS>
__global__ __launch_bounds__(256) void k_attn4(
    const float* __restrict__ qkv,
    float* __restrict__ pm, float* __restrict__ pl, float* __restrict__ po)
{
  constexpr int KP = S / KS;       // keys per split
  constexpr int RCH = S / 256;     // row chunks
  constexpr int NR = BSG * NHD * S;
  constexpr int CH = 32;           // score-cache chunk
  __shared__ float Ks[KP][DH];
  __shared__ float Vs[KP][DH];
  int idx = blockIdx.x;
  int rc = idx % RCH;
  int ks = (idx / RCH) % KS;
  int bh = idx / (RCH * KS);
  int b = bh >> 3, h = bh & 7;
  const float* base = qkv + (size_t)b * S * 384;
  int tid = threadIdx.x;
  for (int t = tid; t < KP * 4; t += 256) {
    int j = t >> 2, d4 = t & 3;
    int jg = ks * KP + j;
    *(float4*)&Ks[j][d4*4] = *(const float4*)(base + (size_t)jg*384 + 128 + h*DH + d4*4);
    *(float4*)&Vs[j][d4*4] = *(const float4*)(base + (size_t)jg*384 + 256 + h*DH + d4*4);
  }
  __syncthreads();
  int s = rc * 256 + tid;
  const float4* qp = (const float4*)(base + (size_t)s * 384 + h * DH);
  float4 q0 = qp[0], q1 = qp[1], q2 = qp[2], q3 = qp[3];
  float m = -1e30f, l = 0.0f;
  float4 o0 = {0,0,0,0}, o1 = {0,0,0,0}, o2 = {0,0,0,0}, o3 = {0,0,0,0};
  for (int c0 = 0; c0 < KP; c0 += CH) {
    float scv[CH];
    float mc = -1e30f;
    #pragma unroll
    for (int j = 0; j < CH; ++j) {
      float4 k0 = *(const float4*)&Ks[c0+j][0];
      float4 k1 = *(const float4*)&Ks[c0+j][4];
      float4 k2 = *(const float4*)&Ks[c0+j][8];
      float4 k3 = *(const float4*)&Ks[c0+j][12];
      float s0 = q0.x*k0.x + q0.y*k0.y + q0.z*k0.z + q0.w*k0.w;
      float s1 = q1.x*k1.x + q1.y*k1.y + q1.z*k1.z + q1.w*k1.w;
      float s2 = q2.x*k2.x + q2.y*k2.y + q2.z*k2.z + q2.w*k2.w;
      float s3 = q3.x*k3.x + q3.y*k3.y + q3.z*k3.z + q3.w*k3.w;
      float sc = (s0 + s1) + (s2 + s3);
      scv[j] = sc;
      mc = fmaxf(mc, sc);
    }
    float mn = fmaxf(m, mc);
    float corr = __expf((m - mn) * 0.25f);
    l *= corr;
    o0.x *= corr; o0.y *= corr; o0.z *= corr; o0.w *= corr;
    o1.x *= corr; o1.y *= corr; o1.z *= corr; o1.w *= corr;
    o2.x *= corr; o2.y *= corr; o2.z *= corr; o2.w *= corr;
    o3.x *= corr; o3.y *= corr; o3.z *= corr; o3.w *= corr;
    m = mn;
    #pragma unroll
    for (int j = 0; j < CH; ++j) {
      float p = __expf((scv[j] - m) * 0.25f);
      l += p;
      float4 v0 = *(const float4*)&Vs[c0+j][0];
      float4 v1 = *(const float4*)&Vs[c0+j][4];
      float4 v2 = *(const float4*)&Vs[c0+j][8];
      float4 v3 = *(const float4*)&Vs[c0+j][12];
      o0.x += p*v0.x; o0.y += p*v0.y; o0.z += p*v0.z; o0.w += p*v0.w;
      o1.x += p*v1.x; o1.y += p*v1.y; o1.z += p*v1.z; o1.w += p*v1.w;
      o2.x += p*v2.x; o2.y += p*v2.y; o2.z += p*v2.z; o2.w += p*v2.w;
      o3.x += p*v3.x; o3.y += p*v3.y; o3.z += p*v3.z; o3.w += p*v3.w;
    }
  }
  size_t R = (size_t)bh * S + s;
  pm[(size_t)ks * NR + R] = m;
  pl[(size_t)ks * NR + R] = l;
  float4* po4 = (float4*)po;
  po4[(size_t)(ks*4 + 0) * NR + R] = o0;
  po4[(size_t)(ks*4 + 1) * NR + R] = o1;
  po4[(size_t)(ks*4 + 2) * NR + R] = o2;
  po4[(size_t)(ks*4 + 3) * NR + R] = o3;
}

// combine KS partials per row (4 threads/row, d4 wave-uniform), write normalized ea
template <int S, int KS>
__global__ __launch_bounds__(256) void k_attn4c(
    const float* __restrict__ pm, const float* __restrict__ pl,
    const float* __restrict__ po, float* __restrict__ ea)
{
  constexpr int NR = BSG * NHD * S;
  int R = blockIdx.x * 64 + (threadIdx.x & 63);
  int d4 = threadIdx.x >> 6;   // wave-uniform
  float mv[KS];
  float m = -1e30f;
  #pragma unroll
  for (int k = 0; k < KS; ++k) { mv[k] = pm[(size_t)k*NR + R]; m = fmaxf(m, mv[k]); }
  const float4* po4 = (const float4*)po;
  float l = 0.0f;
  float4 o = {0, 0, 0, 0};
  #pragma unroll
  for (int k = 0; k < KS; ++k) {
    float w = __expf((mv[k] - m) * 0.25f);
    l += pl[(size_t)k*NR + R] * w;
    float4 p = po4[(size_t)(k*4 + d4)*NR + R];
    o.x += p.x*w; o.y += p.y*w; o.z += p.z*w; o.w += p.w*w;
  }
  float inv = 1.0f / l;
  float4 r = {o.x*inv, o.y*inv, o.z*inv, o.w*inv};
  ((float4*)ea)[(size_t)d4*NR + R] = r;
}

// gather ea rows per (block, channel) via block-edge CSR; divide by cnt
__global__ __launch_bounds__(256) void k_bsum_gather(
    const float* __restrict__ ea, const int* __restrict__ blist,
    const int* __restrict__ boff, float* __restrict__ bsum)
{
  constexpr int NR = BSG * NHD * EBE;
  int idx = blockIdx.x * 256 + threadIdx.x;   // over NBLKT*32
  int i = idx >> 5, c4 = idx & 31;
  int b = i >> 6, blk = i & 63;
  int h = c4 >> 2, d4 = c4 & 3;
  int e0 = boff[b*65 + blk], e1 = boff[b*65 + blk + 1];
  const float4* ea4 = (const float4*)ea;
  size_t basein = (size_t)d4 * NR + (size_t)(b*NHD + h) * EBE;
  float4 s = {0, 0, 0, 0};
  for (int e = e0; e < e1; ++e) {
    int srow = blist[b*EBE + e];
    float4 v = ea4[basein + srow];
    s.x += v.x; s.y += v.y; s.z += v.z; s.w += v.w;
  }
  float cnt = (float)(e1 - e0);
  float sc = (cnt > 0.0f) ? (1.0f / cnt) : 0.0f;
  float4 o = {s.x*sc, s.y*sc, s.z*sc, s.w*sc};
  *(float4*)&bsum[(size_t)i*H + c4*4] = o;
}

// ---------------- block self-attention: LDS K/V, wave-reduced mean, NO atomics ----
__global__ __launch_bounds__(256) void k_attnS(
    const float* __restrict__ qkv, float* __restrict__ m2)
{
  __shared__ float Ks[4][LBLK][DH];
  __shared__ float Vs[4][LBLK][DH];
  __shared__ float red[4][LBLK][DH + 1];   // pad 17: odd stride -> conflict-free
  int b = blockIdx.x >> 1, hq = blockIdx.x & 1;
  int tid = threadIdx.x;
  const float* base = qkv + (size_t)b * LBLK * 384;
  for (int t = tid; t < 1024; t += 256) {
    int hl = t >> 8, j = (t >> 2) & 63, d4 = t & 3;
    int h = hq*4 + hl;
    *(float4*)&Ks[hl][j][d4*4] = *(const float4*)(base + (size_t)j*384 + 128 + h*DH + d4*4);
    *(float4*)&Vs[hl][j][d4*4] = *(const float4*)(base + (size_t)j*384 + 256 + h*DH + d4*4);
  }
  __syncthreads();
  int hl = tid >> 6, s = tid & 63;   // hl uniform per wave; wave owns (b, h)
  int h = hq*4 + hl;
  const float4* qp = (const float4*)(base + (size_t)s * 384 + h * DH);
  float4 q0 = qp[0], q1 = qp[1], q2 = qp[2], q3 = qp[3];
  float m = -1e30f, l = 0.0f;
  float4 o0 = {0,0,0,0}, o1 = {0,0,0,0}, o2 = {0,0,0,0}, o3 = {0,0,0,0};
  for (int c0 = 0; c0 < LBLK; c0 += 32) {
    float scv[32];
    float mc = -1e30f;
    #pragma unroll
    for (int j = 0; j < 32; ++j) {
      float4 k0 = *(const float4*)&Ks[hl][c0+j][0];
      float4 k1 = *(const float4*)&Ks[hl][c0+j][4];
      float4 k2 = *(const float4*)&Ks[hl][c0+j][8];
      float4 k3 = *(const float4*)&Ks[hl][c0+j][12];
      float s0 = q0.x*k0.x + q0.y*k0.y + q0.z*k0.z + q0.w*k0.w;
      float s1 = q1.x*k1.x + q1.y*k1.y + q1.z*k1.z + q1.w*k1.w;
      float s2 = q2.x*k2.x + q2.y*k2.y + q2.z*k2.z + q2.w*k2.w;
      float s3 = q3.x*k3.x + q3.y*k3.y + q3.z*k3.z + q3.w*k3.w;
      float sc = (s0 + s1) + (s2 + s3);
      scv[j] = sc;
      mc = fmaxf(mc, sc);
    }
    float mn = fmaxf(m, mc);
    float corr = __expf((m - mn) * 0.25f);
    l *= corr;
    o0.x *= corr; o0.y *= corr; o0.z *= corr; o0.w *= corr;
    o1.x *= corr; o1.y *= corr; o1.z *= corr; o1.w *= corr;
    o2.x *= corr; o2.y *= corr; o2.z *= corr; o2.w *= corr;
    o3.x *= corr; o3.y *= corr; o3.z *= corr; o3.w *= corr;
    m = mn;
    #pragma unroll
    for (int j = 0; j < 32; ++j) {
      float p = __expf((scv[j] - m) * 0.25f);
      l += p;
      float4 v0 = *(const float4*)&Vs[hl][c0+j][0];
      float4 v1 = *(const float4*)&Vs[hl][c0+j][4];
      float4 v2 = *(const float4*)&Vs[hl][c0+j][8];
      float4 v3 = *(const float4*)&Vs[hl][c0+j][12];
      o0.x += p*v0.x; o0.y += p*v0.y; o0.z += p*v0.z; o0.w += p*v0.w;
      o1.x += p*v1.x; o1.y += p*v1.y; o1.z += p*v1.z; o1.w += p*v1.w;
      o2.x += p*v2.x; o2.y += p*v2.y; o2.z += p*v2.z; o2.w += p*v2.w;
      o3.x += p*v3.x; o3.y += p*v3.y; o3.z += p*v3.z; o3.w += p*v3.w;
    }
  }
  // normalize this row's output and stash in LDS (17-stride, conflict-free)
  float inv = (1.0f / l) * (1.0f / 64.0f);
  float ov[DH] = {o0.x,o0.y,o0.z,o0.w, o1.x,o1.y,o1.z,o1.w,
                  o2.x,o2.y,o2.z,o2.w, o3.x,o3.y,o3.z,o3.w};
  #pragma unroll
  for (int d = 0; d < DH; ++d) red[hl][s][d] = ov[d] * inv;
  __syncthreads();
  // wave owns (b,h): lanes 0..15 sum the 64 rows, plain store (no atomics)
  if (s < DH) {
    float acc = 0.0f;
    for (int r = 0; r < LBLK; ++r) acc += red[hl][r][s];
    m2[(size_t)b * H + h * DH + s] = acc;
  }
}

// ---------------- final: out-proj + LN + 3-layer MLP ----------------
__device__ __forceinline__ float bsum128(float v, float* red) {
  int t = threadIdx.x;
  red[t] = v; __syncthreads();
  #pragma unroll
  for (int off = 64; off > 0; off >>= 1) {
    if (t < off) red[t] += red[t + off];
    __syncthreads();
  }
  float s = red[0];
  __syncthreads();
  return s;
}

__global__ __launch_bounds__(128) void k_final(
    const float* __restrict__ m2, const float* __restrict__ out_w,
    const float* __restrict__ out_b, const float* __restrict__ lng,
    const float* __restrict__ lnb, const float* __restrict__ w1,
    const float* __restrict__ b1, const float* __restrict__ w2,
    const float* __restrict__ b2, const float* __restrict__ w3,
    const float* __restrict__ b3, float* __restrict__ out)
{
  __shared__ float buf[128];
  __shared__ float red[128];
  int b = blockIdx.x, t = threadIdx.x;
  buf[t] = m2[b*H + t];
  __syncthreads();
  float g = out_b[t];
  for (int k = 0; k < H; ++k) g += buf[k] * out_w[k*H + t];
  float mu = bsum128(g, red) * (1.0f / H);
  float df = g - mu;
  float var = bsum128(df * df, red) * (1.0f / H);
  float gn = df / sqrtf(var + 1e-5f) * lng[t] + lnb[t];
  __syncthreads();
  buf[t] = gn; __syncthreads();
  float h1 = b1[t];
  for (int k = 0; k < H; ++k) h1 += buf[k] * w1[k*H + t];
  h1 = fmaxf(h1, 0.0f);
  __syncthreads();
  buf[t] = h1; __syncthreads();
  float h2 = b2[t];
  for (int k = 0; k < H; ++k) h2 += buf[k] * w2[k*H + t];
  h2 = fmaxf(h2, 0.0f);
  float tot = bsum128(h2 * w3[t], red);
  if (t == 0) out[b] = tot + b3[0];
}

extern "C" void kernel_launch(void* const* d_in, const int* in_sizes, int n_in,
                              void* d_out, int out_size, void* d_ws, size_t ws_size,
                              hipStream_t stream) {
  (void)in_sizes; (void)n_in; (void)out_size; (void)ws_size;
  const int*   A          = (const int*)d_in[0];
  const int*   apos       = (const int*)d_in[1];
  const int*   btypes     = (const int*)d_in[2];
  const float* coords     = (const float*)d_in[3];
  const int*   edge_index = (const int*)d_in[4];
  const int*   bedges     = (const int*)d_in[5];
  const float* emb_atom   = (const float*)d_in[6];
  const float* emb_pos    = (const float*)d_in[7];
  const float* emb_block  = (const float*)d_in[8];
  const float* rbf_freq   = (const float*)d_in[9];
  const float* inter_w1   = (const float*)d_in[10];
  const float* inter_b1   = (const float*)d_in[11];
  const float* inter_w2   = (const float*)d_in[12];
  const float* inter_b2   = (const float*)d_in[13];
  const float* upd_w1     = (const float*)d_in[14];
  const float* upd_b1     = (const float*)d_in[15];
  const float* upd_w2     = (const float*)d_in[16];
  const float* upd_b2     = (const float*)d_in[17];
  const float* edge_w1    = (const float*)d_in[18];
  const float* edge_b1    = (const float*)d_in[19];
  const float* edge_w2    = (const float*)d_in[20];
  const float* edge_b2    = (const float*)d_in[21];
  const float* attn_in_w  = (const float*)d_in[22];
  const float* attn_in_b  = (const float*)d_in[23];
  const float* attn_out_w = (const float*)d_in[24];
  const float* attn_out_b = (const float*)d_in[25];
  const float* ln_g       = (const float*)d_in[26];
  const float* ln_b       = (const float*)d_in[27];
  const float* fin_w1     = (const float*)d_in[28];
  const float* fin_b1     = (const float*)d_in[29];
  const float* fin_w2     = (const float*)d_in[30];
  const float* fin_b2     = (const float*)d_in[31];
  const float* fin_w3     = (const float*)d_in[32];
  const float* fin_b3     = (const float*)d_in[33];
  float* out = (float*)d_out;

  float* ws = (float*)d_ws;
  float* x      = ws + 0;
  float* P      = ws + 2097152;
  float* Q      = ws + 4194304;
  float* Hagg   = ws + 6291456;
  float* rbf_s  = ws + 8388608;    // E*6 (sorted RBF)
  float* cntf   = ws + 9961472;    // NA
  float* blocks = ws + 9977856;    // NBLKT*H
  float* Pb     = ws + 10108928;
  float* Qb     = ws + 10240000;
  float* qkv    = ws + 12468224;   // BSG*EBE*384
  float* bsum   = ws + 15613952;   // NBLKT*H
  float* ind    = ws + 15746048;   // NBLKT
  float* m2     = ws + 15747072;   // BSG*H
  int* blist    = (int*)(ws + 15749120);  // BSG*EBE ints
  int* boff     = (int*)(ws + 15757312);  // BSG*65 ints
  // sort scratch + wprep live in the old-Epre region (dead until attention):
  int* ej_s   = (int*)(ws + 10371072);          // NE ints
  int* off    = (int*)(ws + 10371072 + 262144); // NA+1 ints
  int* cur    = (int*)(ws + 10371072 + 278784); // NA ints
  int* cnt    = (int*)(ws + 10371072 + 295168); // NA ints
  float* wbuf = ws + 10371072 + 311552;         // 2 x 256*128 floats
  float* bvec = ws + 10371072 + 311552 + 65536; // 2 x 128 floats
  // attention partials (KS=8, split-major) reuse x/P/Q/Hagg/rbf_s regions:
  float* part_m = ws + 0;          // 8*65536 = 524288 floats
  float* part_l = ws + 524288;     // 524288 floats
  float* part_o = ws + 1048576;    // 8*65536*16 = 8388608 floats -> ends 9437184
  float* ea     = ws + 10371072;   // 65536*16 = 1048576 floats (old Epre region)

  const int* ei = edge_index;
  const int* ej = edge_index + NE;

  // ---- edge sort (once; reused by both interaction blocks) ----
  (void)hipMemsetAsync(cnt, 0, NA * sizeof(int), stream);
  k_hist<<<NE/256, 256, 0, stream>>>(ei, cnt);
  k_scan<<<1, 1024, 0, stream>>>(cnt, off, cur, cntf);
  k_scatter<<<NE/256, 256, 0, stream>>>(ei, ej, coords, rbf_freq, cur, ej_s, rbf_s);
  k_bedge_csr<<<BSG, 256, 0, stream>>>(bedges, blist, boff, ind);
  // both interaction blocks' weight preps in one launch
  k_wprep<<<dim3(128, 2), 128, 0, stream>>>(inter_w2, upd_w1, inter_b2, wbuf, bvec);

  k_embed<<<NA*H/256, 256, 0, stream>>>(A, apos, btypes, emb_atom, emb_pos, emb_block, x);

  for (int b = 0; b < NBI; ++b) {
    const float* w1 = inter_w1 + (size_t)b * 262 * H;
    // fused: P = x@W1a + b1 (y=0) ; Q = x@W1b (y=1, no bias)
    gemm128<<<dim3(NA/32, 2), 256, 0, stream>>>(x, nullptr, w1, H, 0, inter_b1 + b*H,
                                                nullptr, nullptr, nullptr,
                                                P, H, 0, NA, H, 0, 0, 128, 2097152);
    k_edge_csr<<<NA/8, 256, 0, stream>>>(P, Q, rbf_s, w1 + 256*H, ej_s, off, Hagg);
    // chained: U = silu([x|Hagg]@wbuf + b1 + cnt*bvec); x = U@upd_w2 + b2 + x
    k_upd_chain<<<NA/32, 256, 0, stream>>>(x, Hagg, wbuf + (size_t)b*32768,
                                           upd_b1 + b*H, bvec + b*H, cntf,
                                           upd_w2 + (size_t)b*H*H, upd_b2 + b*H, x);
  }

  k_block_mean<<<NBLKT*H/256, 256, 0, stream>>>(x, blocks);
  // fused: Pb = blocks@edge_w1a + b (y=0) ; Qb = blocks@edge_w1b (y=1)
  gemm128<<<dim3(NBLKT/32, 2), 256, 0, stream>>>(blocks, nullptr, edge_w1, H, 0, edge_b1,
                                                 nullptr, nullptr, nullptr,
                                                 Pb, H, 0, NBLKT, H, 0, 0, 128, 131072);
  // fused: Epre gather+relu -> @edge_w2+b -> @attn_in_w+b -> qkv (y-split chunks)
  k_eprep<<<dim3(BSG*EBE/32, 3), 256, 0, stream>>>(Pb, Qb, bedges, edge_w2, edge_b2,
                                                   attn_in_w, attn_in_b, qkv);
  k_attn4<EBE, 8><<<BSG*NHD*8*(EBE/256), 256, 0, stream>>>(qkv, part_m, part_l, part_o);
  k_attn4c<EBE, 8><<<BSG*NHD*EBE/64, 256, 0, stream>>>(part_m, part_l, part_o, ea);
  k_bsum_gather<<<NBLKT*32/256, 256, 0, stream>>>(ea, blist, boff, bsum);
  // blocks += (bsum/cnt)@out_w + out_b*[cnt>0]
  gemm128<<<NBLKT/32, 256, 0, stream>>>(bsum, nullptr, attn_out_w, H, 0, nullptr,
                                        attn_out_b, ind, blocks, blocks, H, 0,
                                        NBLKT, H, 0, 0, 0, 0);
  gemm128<<<dim3(NBLKT/32, 3), 256, 0, stream>>>(blocks, nullptr, attn_in_w, 384, 0,
                                                 attn_in_b, nullptr, nullptr, nullptr,
                                                 qkv, 384, 0, NBLKT, H, 0, 128, 0, 0);
  k_attnS<<<BSG*2, 256, 0, stream>>>(qkv, m2);
  k_final<<<BSG, 128, 0, stream>>>(m2, attn_out_w, attn_out_b, ln_g, ln_b,
                                   fin_w1, fin_b1, fin_w2, fin_b2, fin_w3, fin_b3, out);
}

// Round 23
// 522.691 us; speedup vs baseline: 1.1861x; 1.0286x over previous
//
#include <hip/hip_runtime.h>
#include <math.h>

#define H 128
#define NHD 8
#define DH 16
#define RB 6
#define NBI 2
#define BSG 16
#define LBLK 64
#define KATOM 16
#define NBLKT 1024
#define NA 16384
#define NE 262144
#define EBE 512

__device__ __forceinline__ float atomAddF(float* p, float v) {
#if defined(__gfx90a__) || defined(__gfx940__) || defined(__gfx941__) || defined(__gfx942__) || defined(__gfx950__)
  return unsafeAtomicAdd(p, v);
#else
  return atomicAdd(p, v);
#endif
}

__device__ __forceinline__ float fsilu(float v) {
  return v * __builtin_amdgcn_rcpf(1.0f + __expf(-v));
}

// ---------------- embedding ----------------
__global__ __launch_bounds__(256) void k_embed(
    const int* __restrict__ A, const int* __restrict__ apos,
    const int* __restrict__ btypes,
    const float* __restrict__ emb_atom, const float* __restrict__ emb_pos,
    const float* __restrict__ emb_block, float* __restrict__ x)
{
  int idx = blockIdx.x * 256 + threadIdx.x;   // over NA*H
  int n = idx >> 7, h = idx & 127;
  x[idx] = emb_atom[A[n] * H + h] + emb_pos[apos[n] * H + h]
         + emb_block[btypes[n >> 4] * H + h];
}

// ---------------- edge sort: histogram ----------------
__global__ __launch_bounds__(256) void k_hist(
    const int* __restrict__ ei, int* __restrict__ cnt)
{
  int e = blockIdx.x * 256 + threadIdx.x;
  atomicAdd(&cnt[ei[e]], 1);
}

// ---------------- edge sort: scan (single block, 1024 thr, 16 bins each) ----
__global__ __launch_bounds__(1024) void k_scan(
    const int* __restrict__ cnt, int* __restrict__ off,
    int* __restrict__ cur, float* __restrict__ cntf)
{
  __shared__ int ps[1024];
  int t = threadIdx.x;
  int base = t * 16;
  int local[16];
  int s = 0;
  #pragma unroll
  for (int k = 0; k < 16; ++k) { local[k] = s; s += cnt[base + k]; }
  ps[t] = s;
  __syncthreads();
  for (int d = 1; d < 1024; d <<= 1) {
    int v = (t >= d) ? ps[t - d] : 0;
    __syncthreads();
    ps[t] += v;
    __syncthreads();
  }
  int offset = (t == 0) ? 0 : ps[t - 1];
  #pragma unroll
  for (int k = 0; k < 16; ++k) {
    int o = offset + local[k];
    off[base + k] = o;
    cur[base + k] = o;
    cntf[base + k] = (float)cnt[base + k];
  }
  if (t == 1023) off[NA] = offset + s;
}

// ---------------- edge sort: scatter + fused RBF ----------------
__global__ __launch_bounds__(256) void k_scatter(
    const int* __restrict__ ei, const int* __restrict__ ej,
    const float* __restrict__ coords, const float* __restrict__ freq,
    int* __restrict__ cur, int* __restrict__ ej_s, float* __restrict__ rbf_s)
{
  int e = blockIdx.x * 256 + threadIdx.x;
  int i = ei[e], j = ej[e];
  int pos = atomicAdd(&cur[i], 1);
  ej_s[pos] = j;
  float dx = coords[i*3+0] - coords[j*3+0];
  float dy = coords[i*3+1] - coords[j*3+1];
  float dz = coords[i*3+2] - coords[j*3+2];
  float d = sqrtf(dx*dx + dy*dy + dz*dz);
  float u = fmaxf(d * 0.125f, 1e-3f);
  float u2 = u*u, u4 = u2*u2, u5 = u4*u, u6 = u5*u, u7 = u6*u;
  float env = 1.0f/u - 28.0f*u5 + 48.0f*u6 - 21.0f*u7;
  #pragma unroll
  for (int r = 0; r < RB; ++r)
    rbf_s[(size_t)pos*RB + r] = env * sinf(freq[r] * u);
}

// ---------------- block-edge CSR (per-graph src buckets) ----------------
__global__ __launch_bounds__(256) void k_bedge_csr(
    const int* __restrict__ bedges, int* __restrict__ blist,
    int* __restrict__ boff, float* __restrict__ ind)
{
  __shared__ int hist[64], offs[65], curs[64];
  int b = blockIdx.x, t = threadIdx.x;
  if (t < 64) hist[t] = 0;
  __syncthreads();
  for (int e = t; e < EBE; e += 256) atomicAdd(&hist[bedges[(b*EBE + e)*2]], 1);
  __syncthreads();
  if (t == 0) {
    offs[0] = 0;
    for (int k = 0; k < 64; ++k) offs[k+1] = offs[k] + hist[k];
  }
  __syncthreads();
  if (t < 64) curs[t] = offs[t];
  __syncthreads();
  for (int e = t; e < EBE; e += 256) {
    int src = bedges[(b*EBE + e)*2];
    int pos = atomicAdd(&curs[src], 1);
    blist[b*EBE + pos] = e;
  }
  if (t < 65) boff[b*65 + t] = offs[t];
  if (t < 64) ind[b*64 + t] = (hist[t] > 0) ? 1.0f : 0.0f;
}

// ---------------- per-atom CSR edge pass v2 (float4 channels, no atomics) ----
__global__ __launch_bounds__(256) void k_edge_csr(
    const float* __restrict__ P, const float* __restrict__ Q,
    const float* __restrict__ rbf_s, const float* __restrict__ W1c,
    const int* __restrict__ ej_s, const int* __restrict__ off,
    float* __restrict__ Hagg)
{
  __shared__ float w[RB * H];
  for (int idx = threadIdx.x; idx < RB * H; idx += 256) w[idx] = W1c[idx];
  __syncthreads();
  int c4 = threadIdx.x & 31;        // channel quad
  int sub = threadIdx.x >> 5;       // atom within block
  int i = blockIdx.x * 8 + sub;
  int e0 = off[i], e1 = off[i + 1];
  float4 pv = *(const float4*)&P[(size_t)i * H + c4 * 4];
  float4 W0 = *(const float4*)&w[0*H + c4*4];
  float4 W1 = *(const float4*)&w[1*H + c4*4];
  float4 W2 = *(const float4*)&w[2*H + c4*4];
  float4 W3 = *(const float4*)&w[3*H + c4*4];
  float4 W4 = *(const float4*)&w[4*H + c4*4];
  float4 W5 = *(const float4*)&w[5*H + c4*4];
  float4 acc = {0, 0, 0, 0};
  for (int e = e0; e < e1; ++e) {
    int j = ej_s[e];
    float4 qv = *(const float4*)&Q[(size_t)j * H + c4 * 4];
    const float* rb = &rbf_s[(size_t)e * RB];
    float r0 = rb[0], r1 = rb[1], r2 = rb[2], r3 = rb[3], r4 = rb[4], r5 = rb[5];
    float4 v;
    v.x = pv.x + qv.x + r0*W0.x + r1*W1.x + r2*W2.x + r3*W3.x + r4*W4.x + r5*W5.x;
    v.y = pv.y + qv.y + r0*W0.y + r1*W1.y + r2*W2.y + r3*W3.y + r4*W4.y + r5*W5.y;
    v.z = pv.z + qv.z + r0*W0.z + r1*W1.z + r2*W2.z + r3*W3.z + r4*W4.z + r5*W5.z;
    v.w = pv.w + qv.w + r0*W0.w + r1*W1.w + r2*W2.w + r3*W3.w + r4*W4.w + r5*W5.w;
    acc.x += fsilu(v.x);
    acc.y += fsilu(v.y);
    acc.z += fsilu(v.z);
    acc.w += fsilu(v.w);
  }
  *(float4*)&Hagg[(size_t)i * H + c4 * 4] = acc;
}

// ---------------- weight prep (both blocks in one launch via blockIdx.y) ----
__global__ __launch_bounds__(128) void k_wprep(
    const float* __restrict__ W2base, const float* __restrict__ U1base,
    const float* __restrict__ b2base, float* __restrict__ wbufbase,
    float* __restrict__ bvecbase)
{
  int y = blockIdx.y;
  const float* W2 = W2base + (size_t)y * H * H;
  const float* U1 = U1base + (size_t)y * 2 * H * H;
  const float* b2 = b2base + y * H;
  float* wbuf = wbufbase + (size_t)y * 256 * H;
  float* bvec = bvecbase + y * H;
  int k = blockIdx.x, c = threadIdx.x;
  const float* U1b = U1 + 128 * H;
  wbuf[k * H + c] = U1[k * H + c];
  float s = 0.0f;
  for (int t = 0; t < H; ++t) s += W2[k * H + t] * U1b[t * H + c];
  wbuf[(128 + k) * H + c] = s;
  if (k == 0) {
    float sb = 0.0f;
    for (int t = 0; t < H; ++t) sb += b2[t] * U1b[t * H + c];
    bvec[c] = sb;
  }
}

// ---------------- generic 128-col GEMM v2 + row-mode y fusion ----------------
__global__ __launch_bounds__(256) void gemm128(
    const float* __restrict__ A1, const float* __restrict__ A2,
    const float* __restrict__ W, int ldw, int wcol0,
    const float* __restrict__ bias, const float* __restrict__ bias2,
    const float* __restrict__ bias_scale,
    const float* __restrict__ res,
    float* __restrict__ C, int ldc, int ccol0,
    int M, int Ktot, int act, int ymul, int wrowmul, long long cymul)
{
  __shared__ float As[32][256];
  __shared__ float Ws[16][128];
  int tid = threadIdx.x;
  int m0 = blockIdx.x * 32;
  int yoff = blockIdx.y * ymul;
  W += (size_t)blockIdx.y * wrowmul * ldw;
  C += (size_t)blockIdx.y * cymul;
  bool doBias = (ymul != 0) || (blockIdx.y == 0);
  for (int idx = tid; idx < 32*32; idx += 256) {
    int r = idx >> 5, k4 = idx & 31;
    float4 v = *(const float4*)&A1[(size_t)(m0 + r)*H + k4*4];
    *(float4*)&As[r][k4*4] = v;
  }
  if (A2) {
    for (int idx = tid; idx < 32*32; idx += 256) {
      int r = idx >> 5, k4 = idx & 31;
      float4 v = *(const float4*)&A2[(size_t)(m0 + r)*H + k4*4];
      *(float4*)&As[r][128 + k4*4] = v;
    }
  }
  int rr = tid >> 5;    // 0..7
  int cq = tid & 31;    // col quad
  float acc[4][4] = {};
  for (int kk0 = 0; kk0 < Ktot; kk0 += 16) {
    __syncthreads();
    for (int idx = tid; idx < 16*32; idx += 256) {
      int kr = idx >> 5, c4 = idx & 31;
      float4 v = *(const float4*)&W[(size_t)(kk0 + kr)*ldw + wcol0 + yoff + c4*4];
      *(float4*)&Ws[kr][c4*4] = v;
    }
    __syncthreads();
    #pragma unroll
    for (int k4 = 0; k4 < 4; ++k4) {
      float4 w0 = *(const float4*)&Ws[k4*4+0][cq*4];
      float4 w1 = *(const float4*)&Ws[k4*4+1][cq*4];
      float4 w2 = *(const float4*)&Ws[k4*4+2][cq*4];
      float4 w3 = *(const float4*)&Ws[k4*4+3][cq*4];
      #pragma unroll
      for (int i = 0; i < 4; ++i) {
        float4 a = *(const float4*)&As[rr + 8*i][kk0 + k4*4];
        acc[i][0] += a.x*w0.x + a.y*w1.x + a.z*w2.x + a.w*w3.x;
        acc[i][1] += a.x*w0.y + a.y*w1.y + a.z*w2.y + a.w*w3.y;
        acc[i][2] += a.x*w0.z + a.y*w1.z + a.z*w2.z + a.w*w3.z;
        acc[i][3] += a.x*w0.w + a.y*w1.w + a.z*w2.w + a.w*w3.w;
      }
    }
  }
  #pragma unroll
  for (int i = 0; i < 4; ++i) {
    int m = m0 + rr + 8*i;
    float bs = bias_scale ? bias_scale[m] : 1.0f;
    float4 out;
    float* po = &out.x;
    #pragma unroll
    for (int j = 0; j < 4; ++j) {
      int c = cq*4 + j;
      float v = acc[i][j];
      if (bias && doBias) v += bias[yoff + c];
      if (bias2 && doBias) v += bias2[yoff + c] * bs;
      if (act == 1) v = fsilu(v);
      else if (act == 2) v = fmaxf(v, 0.0f);
      if (res) v += res[(size_t)m*H + c];
      po[j] = v;
    }
    *(float4*)&C[(size_t)m*ldc + ccol0 + yoff + cq*4] = out;
  }
}

// ---------------- chained update: U = silu([x|Hagg]@W1 + b1 + cnt*bvec);
//                  xout = U@W2 + b2 + x  (one kernel, U stays in LDS) --------
__global__ __launch_bounds__(256) void k_upd_chain(
    const float* __restrict__ x, const float* __restrict__ Hagg,
    const float* __restrict__ W1,    // wbuf [256][128]
    const float* __restrict__ b1, const float* __restrict__ bvec,
    const float* __restrict__ cntf,
    const float* __restrict__ W2,    // upd_w2 [128][128]
    const float* __restrict__ b2,
    float* __restrict__ xout)
{
  __shared__ float As[32][256];   // 32 KB
  __shared__ float Ws[16][128];   // 8 KB
  __shared__ float Us[32][128];   // 16 KB  -> 56 KB total, 2 blocks/CU
  int tid = threadIdx.x;
  int m0 = blockIdx.x * 32;
  for (int idx = tid; idx < 32*32; idx += 256) {
    int r = idx >> 5, k4 = idx & 31;
    *(float4*)&As[r][k4*4] = *(const float4*)&x[(size_t)(m0 + r)*H + k4*4];
    *(float4*)&As[r][128 + k4*4] = *(const float4*)&Hagg[(size_t)(m0 + r)*H + k4*4];
  }
  int rr = tid >> 5;    // 0..7
  int cq = tid & 31;    // col quad
  float acc[4][4] = {};
  for (int kk0 = 0; kk0 < 256; kk0 += 16) {
    __syncthreads();
    for (int idx = tid; idx < 16*32; idx += 256) {
      int kr = idx >> 5, c4 = idx & 31;
      *(float4*)&Ws[kr][c4*4] = *(const float4*)&W1[(size_t)(kk0 + kr)*H + c4*4];
    }
    __syncthreads();
    #pragma unroll
    for (int k4 = 0; k4 < 4; ++k4) {
      float4 w0 = *(const float4*)&Ws[k4*4+0][cq*4];
      float4 w1 = *(const float4*)&Ws[k4*4+1][cq*4];
      float4 w2 = *(const float4*)&Ws[k4*4+2][cq*4];
      float4 w3 = *(const float4*)&Ws[k4*4+3][cq*4];
      #pragma unroll
      for (int i = 0; i < 4; ++i) {
        float4 a = *(const float4*)&As[rr + 8*i][kk0 + k4*4];
        acc[i][0] += a.x*w0.x + a.y*w1.x + a.z*w2.x + a.w*w3.x;
        acc[i][1] += a.x*w0.y + a.y*w1.y + a.z*w2.y + a.w*w3.y;
        acc[i][2] += a.x*w0.z + a.y*w1.z + a.z*w2.z + a.w*w3.z;
        acc[i][3] += a.x*w0.w + a.y*w1.w + a.z*w2.w + a.w*w3.w;
      }
    }
  }
  #pragma unroll
  for (int i = 0; i < 4; ++i) {
    int m = m0 + rr + 8*i;
    float bs = cntf[m];
    float4 u;
    float* pu = &u.x;
    #pragma unroll
    for (int j = 0; j < 4; ++j) {
      int c = cq*4 + j;
      float v = acc[i][j] + b1[c] + bvec[c] * bs;
      pu[j] = fsilu(v);
    }
    *(float4*)&Us[rr + 8*i][cq*4] = u;
    acc[i][0] = 0.0f; acc[i][1] = 0.0f; acc[i][2] = 0.0f; acc[i][3] = 0.0f;
  }
  for (int kk0 = 0; kk0 < 128; kk0 += 16) {
    __syncthreads();
    for (int idx = tid; idx < 16*32; idx += 256) {
      int kr = idx >> 5, c4 = idx & 31;
      *(float4*)&Ws[kr][c4*4] = *(const float4*)&W2[(size_t)(kk0 + kr)*H + c4*4];
    }
    __syncthreads();
    #pragma unroll
    for (int k4 = 0; k4 < 4; ++k4) {
      float4 w0 = *(const float4*)&Ws[k4*4+0][cq*4];
      float4 w1 = *(const float4*)&Ws[k4*4+1][cq*4];
      float4 w2 = *(const float4*)&Ws[k4*4+2][cq*4];
      float4 w3 = *(const float4*)&Ws[k4*4+3][cq*4];
      #pragma unroll
      for (int i = 0; i < 4; ++i) {
        float4 a = *(const float4*)&Us[rr + 8*i][kk0 + k4*4];
        acc[i][0] += a.x*w0.x + a.y*w1.x + a.z*w2.x + a.w*w3.x;
        acc[i][1] += a.x*w0.y + a.y*w1.y + a.z*w2.y + a.w*w3.y;
        acc[i][2] += a.x*w0.z + a.y*w1.z + a.z*w2.z + a.w*w3.z;
        acc[i][3] += a.x*w0.w + a.y*w1.w + a.z*w2.w + a.w*w3.w;
      }
    }
  }
  #pragma unroll
  for (int i = 0; i < 4; ++i) {
    int m = m0 + rr + 8*i;
    float4 out;
    float* po = &out.x;
    #pragma unroll
    for (int j = 0; j < 4; ++j) {
      int c = cq*4 + j;
      po[j] = acc[i][j] + b2[c] + x[(size_t)m*H + c];
    }
    *(float4*)&xout[(size_t)m*H + cq*4] = out;
  }
}

// ---------------- fused block-edge prep v2: y-split over qkv chunks ----------
__global__ __launch_bounds__(256) void k_eprep(
    const float* __restrict__ Pb, const float* __restrict__ Qb,
    const int* __restrict__ bedges,
    const float* __restrict__ W2e, const float* __restrict__ b2e,
    const float* __restrict__ Win, const float* __restrict__ bin,
    float* __restrict__ qkv)
{
  __shared__ float As[32][128];   // Epre tile (16 KB)
  __shared__ float Ws[16][128];   // weight panel (8 KB)
  __shared__ float Us[32][128];   // ef2 tile (16 KB)  -> 40 KB total
  int tid = threadIdx.x;
  int m0 = blockIdx.x * 32;
  int chunk = blockIdx.y;
  for (int idx = tid; idx < 32*32; idx += 256) {
    int r = idx >> 5, k4 = idx & 31;
    int row = m0 + r;
    int g = row >> 9;
    int src = bedges[row*2], dst = bedges[row*2 + 1];
    float4 pv = *(const float4*)&Pb[(size_t)(g*LBLK + src)*H + k4*4];
    float4 qv = *(const float4*)&Qb[(size_t)(g*LBLK + dst)*H + k4*4];
    float4 v;
    v.x = fmaxf(pv.x + qv.x, 0.0f);
    v.y = fmaxf(pv.y + qv.y, 0.0f);
    v.z = fmaxf(pv.z + qv.z, 0.0f);
    v.w = fmaxf(pv.w + qv.w, 0.0f);
    *(float4*)&As[r][k4*4] = v;
  }
  int rr = tid >> 5;    // 0..7
  int cq = tid & 31;    // col quad
  float acc[4][4] = {};
  for (int kk0 = 0; kk0 < 128; kk0 += 16) {
    __syncthreads();
    for (int idx = tid; idx < 16*32; idx += 256) {
      int kr = idx >> 5, c4 = idx & 31;
      *(float4*)&Ws[kr][c4*4] = *(const float4*)&W2e[(size_t)(kk0 + kr)*H + c4*4];
    }
    __syncthreads();
    #pragma unroll
    for (int k4 = 0; k4 < 4; ++k4) {
      float4 w0 = *(const float4*)&Ws[k4*4+0][cq*4];
      float4 w1 = *(const float4*)&Ws[k4*4+1][cq*4];
      float4 w2 = *(const float4*)&Ws[k4*4+2][cq*4];
      float4 w3 = *(const float4*)&Ws[k4*4+3][cq*4];
      #pragma unroll
      for (int i = 0; i < 4; ++i) {
        float4 a = *(const float4*)&As[rr + 8*i][kk0 + k4*4];
        acc[i][0] += a.x*w0.x + a.y*w1.x + a.z*w2.x + a.w*w3.x;
        acc[i][1] += a.x*w0.y + a.y*w1.y + a.z*w2.y + a.w*w3.y;
        acc[i][2] += a.x*w0.z + a.y*w1.z + a.z*w2.z + a.w*w3.z;
        acc[i][3] += a.x*w0.w + a.y*w1.w + a.z*w2.w + a.w*w3.w;
      }
    }
  }
  #pragma unroll
  for (int i = 0; i < 4; ++i) {
    float4 u;
    float* pu = &u.x;
    #pragma unroll
    for (int j = 0; j < 4; ++j) pu[j] = acc[i][j] + b2e[cq*4 + j];
    *(float4*)&Us[rr + 8*i][cq*4] = u;
    acc[i][0] = 0.0f; acc[i][1] = 0.0f; acc[i][2] = 0.0f; acc[i][3] = 0.0f;
  }
  for (int kk0 = 0; kk0 < 128; kk0 += 16) {
    __syncthreads();
    for (int idx = tid; idx < 16*32; idx += 256) {
      int kr = idx >> 5, c4 = idx & 31;
      *(float4*)&Ws[kr][c4*4] =
          *(const float4*)&Win[(size_t)(kk0 + kr)*384 + chunk*128 + c4*4];
    }
    __syncthreads();
    #pragma unroll
    for (int k4 = 0; k4 < 4; ++k4) {
      float4 w0 = *(const float4*)&Ws[k4*4+0][cq*4];
      float4 w1 = *(const float4*)&Ws[k4*4+1][cq*4];
      float4 w2 = *(const float4*)&Ws[k4*4+2][cq*4];
      float4 w3 = *(const float4*)&Ws[k4*4+3][cq*4];
      #pragma unroll
      for (int i = 0; i < 4; ++i) {
        float4 a = *(const float4*)&Us[rr + 8*i][kk0 + k4*4];
        acc[i][0] += a.x*w0.x + a.y*w1.x + a.z*w2.x + a.w*w3.x;
        acc[i][1] += a.x*w0.y + a.y*w1.y + a.z*w2.y + a.w*w3.y;
        acc[i][2] += a.x*w0.z + a.y*w1.z + a.z*w2.z + a.w*w3.z;
        acc[i][3] += a.x*w0.w + a.y*w1.w + a.z*w2.w + a.w*w3.w;
      }
    }
  }
  #pragma unroll
  for (int i = 0; i < 4; ++i) {
    int m = m0 + rr + 8*i;
    float4 out;
    float* po = &out.x;
    #pragma unroll
    for (int j = 0; j < 4; ++j)
      po[j] = acc[i][j] + bin[chunk*128 + cq*4 + j];
    *(float4*)&qkv[(size_t)m*384 + chunk*128 + cq*4] = out;
  }
}

// ---------------- fused block tail: blocks' = bsum@out_w + out_b*ind + blocks;
//                  qkv chunk y = blocks' @ attn_in_w + bin  (y-split) ---------
__global__ __launch_bounds__(256) void k_bprep(
    const float* __restrict__ bsum, const float* __restrict__ Wout,
    const float* __restrict__ bout, const float* __restrict__ ind,
    const float* __restrict__ blocks,
    const float* __restrict__ Win, const float* __restrict__ bin,
    float* __restrict__ qkv)
{
  __shared__ float As[32][128];   // bsum tile
  __shared__ float Ws[16][128];
  __shared__ float Us[32][128];   // updated blocks tile
  int tid = threadIdx.x;
  int m0 = blockIdx.x * 32;
  int chunk = blockIdx.y;
  for (int idx = tid; idx < 32*32; idx += 256) {
    int r = idx >> 5, k4 = idx & 31;
    *(float4*)&As[r][k4*4] = *(const float4*)&bsum[(size_t)(m0 + r)*H + k4*4];
  }
  int rr = tid >> 5;    // 0..7
  int cq = tid & 31;    // col quad
  float acc[4][4] = {};
  // stage 1: bsum @ attn_out_w
  for (int kk0 = 0; kk0 < 128; kk0 += 16) {
    __syncthreads();
    for (int idx = tid; idx < 16*32; idx += 256) {
      int kr = idx >> 5, c4 = idx & 31;
      *(float4*)&Ws[kr][c4*4] = *(const float4*)&Wout[(size_t)(kk0 + kr)*H + c4*4];
    }
    __syncthreads();
    #pragma unroll
    for (int k4 = 0; k4 < 4; ++k4) {
      float4 w0 = *(const float4*)&Ws[k4*4+0][cq*4];
      float4 w1 = *(const float4*)&Ws[k4*4+1][cq*4];
      float4 w2 = *(const float4*)&Ws[k4*4+2][cq*4];
      float4 w3 = *(const float4*)&Ws[k4*4+3][cq*4];
      #pragma unroll
      for (int i = 0; i < 4; ++i) {
        float4 a = *(const float4*)&As[rr + 8*i][kk0 + k4*4];
        acc[i][0] += a.x*w0.x + a.y*w1.x + a.z*w2.x + a.w*w3.x;
        acc[i][1] += a.x*w0.y + a.y*w1.y + a.z*w2.y + a.w*w3.y;
        acc[i][2] += a.x*w0.z + a.y*w1.z + a.z*w2.z + a.w*w3.z;
        acc[i][3] += a.x*w0.w + a.y*w1.w + a.z*w2.w + a.w*w3.w;
      }
    }
  }
  // epilogue 1 (matches old gemm order: +bias2*ind, +res blocks)
  #pragma unroll
  for (int i = 0; i < 4; ++i) {
    int m = m0 + rr + 8*i;
    float bs = ind[m];
    float4 u;
    float* pu = &u.x;
    #pragma unroll
    for (int j = 0; j < 4; ++j) {
      int c = cq*4 + j;
      pu[j] = acc[i][j] + bout[c] * bs + blocks[(size_t)m*H + c];
    }
    *(float4*)&Us[rr + 8*i][cq*4] = u;
    acc[i][0] = 0.0f; acc[i][1] = 0.0f; acc[i][2] = 0.0f; acc[i][3] = 0.0f;
  }
  // stage 2: qkv chunk = blocks' @ attn_in_w + bin
  for (int kk0 = 0; kk0 < 128; kk0 += 16) {
    __syncthreads();
    for (int idx = tid; idx < 16*32; idx += 256) {
      int kr = idx >> 5, c4 = idx & 31;
      *(float4*)&Ws[kr][c4*4] =
          *(const float4*)&Win[(size_t)(kk0 + kr)*384 + chunk*128 + c4*4];
    }
    __syncthreads();
    #pragma unroll
    for (int k4 = 0; k4 < 4; ++k4) {
      float4 w0 = *(const float4*)&Ws[k4*4+0][cq*4];
      float4 w1 = *(const float4*)&Ws[k4*4+1][cq*4];
      float4 w2 = *(const float4*)&Ws[k4*4+2][cq*4];
      float4 w3 = *(const float4*)&Ws[k4*4+3][cq*4];
      #pragma unroll
      for (int i = 0; i < 4; ++i) {
        float4 a = *(const float4*)&Us[rr + 8*i][kk0 + k4*4];
        acc[i][0] += a.x*w0.x + a.y*w1.x + a.z*w2.x + a.w*w3.x;
        acc[i][1] += a.x*w0.y + a.y*w1.y + a.z*w2.y + a.w*w3.y;
        acc[i][2] += a.x*w0.z + a.y*w1.z + a.z*w2.z + a.w*w3.z;
        acc[i][3] += a.x*w0.w + a.y*w1.w + a.z*w2.w + a.w*w3.w;
      }
    }
  }
  #pragma unroll
  for (int i = 0; i < 4; ++i) {
    int m = m0 + rr + 8*i;
    float4 out;
    float* po = &out.x;
    #pragma unroll
    for (int j = 0; j < 4; ++j)
      po[j] = acc[i][j] + bin[chunk*128 + cq*4 + j];
    *(float4*)&qkv[(size_t)m*384 + chunk*128 + cq*4] = out;
  }
}

// ---------------- block mean over K atoms ----------------
__global__ __launch_bounds__(256) void k_block_mean(
    const float* __restrict__ x, float* __restrict__ blocks)
{
  int idx = blockIdx.x * 256 + threadIdx.x;   // over NBLKT*H
  int nb = idx >> 7, h = idx & 127;
  float s = 0.0f;
  #pragma unroll
  for (int k = 0; k < KATOM; ++k)
    s += x[(size_t)(nb*KATOM + k)*H + h];
  blocks[idx] = s * (1.0f / KATOM);
}

// ---------------- MHA v7: thread-per-row, key-split, chunked online softmax ----
template <int S, int KS>
__global__ __launch_bounds__(256) void k_attn4(
    const float* __restrict__ qkv,
    float* __restrict__ pm, float* __restrict__ pl, float* __restrict__ po)
{
  constexpr int KP = S / KS;       // keys per split
  constexpr int RCH = S / 256;     // row chunks
  constexpr int NR = BSG * NHD * S;
  constexpr int CH = 32;           // score-cache chunk
  __shared__ float Ks[KP][DH];
  __shared__ float Vs[KP][DH];
  int idx = blockIdx.x;
  int rc = idx % RCH;
  int ks = (idx / RCH) % KS;
  int bh = idx / (RCH * KS);
  int b = bh >> 3, h = bh & 7;
  const float* base = qkv + (size_t)b * S * 384;
  int tid = threadIdx.x;
  for (int t = tid; t < KP * 4; t += 256) {
    int j = t >> 2, d4 = t & 3;
    int jg = ks * KP + j;
    *(float4*)&Ks[j][d4*4] = *(const float4*)(base + (size_t)jg*384 + 128 + h*DH + d4*4);
    *(float4*)&Vs[j][d4*4] = *(const float4*)(base + (size_t)jg*384 + 256 + h*DH + d4*4);
  }
  __syncthreads();
  int s = rc * 256 + tid;
  const float4* qp = (const float4*)(base + (size_t)s * 384 + h * DH);
  float4 q0 = qp[0], q1 = qp[1], q2 = qp[2], q3 = qp[3];
  float m = -1e30f, l = 0.0f;
  float4 o0 = {0,0,0,0}, o1 = {0,0,0,0}, o2 = {0,0,0,0}, o3 = {0,0,0,0};
  for (int c0 = 0; c0 < KP; c0 += CH) {
    float scv[CH];
    float mc = -1e30f;
    #pragma unroll
    for (int j = 0; j < CH; ++j) {
      float4 k0 = *(const float4*)&Ks[c0+j][0];
      float4 k1 = *(const float4*)&Ks[c0+j][4];
      float4 k2 = *(const float4*)&Ks[c0+j][8];
      float4 k3 = *(const float4*)&Ks[c0+j][12];
      float s0 = q0.x*k0.x + q0.y*k0.y + q0.z*k0.z + q0.w*k0.w;
      float s1 = q1.x*k1.x + q1.y*k1.y + q1.z*k1.z + q1.w*k1.w;
      float s2 = q2.x*k2.x + q2.y*k2.y + q2.z*k2.z + q2.w*k2.w;
      float s3 = q3.x*k3.x + q3.y*k3.y + q3.z*k3.z + q3.w*k3.w;
      float sc = (s0 + s1) + (s2 + s3);
      scv[j] = sc;
      mc = fmaxf(mc, sc);
    }
    float mn = fmaxf(m, mc);
    float corr = __expf((m - mn) * 0.25f);
    l *= corr;
    o0.x *= corr; o0.y *= corr; o0.z *= corr; o0.w *= corr;
    o1.x *= corr; o1.y *= corr; o1.z *= corr; o1.w *= corr;
    o2.x *= corr; o2.y *= corr; o2.z *= corr; o2.w *= corr;
    o3.x *= corr; o3.y *= corr; o3.z *= corr; o3.w *= corr;
    m = mn;
    #pragma unroll
    for (int j = 0; j < CH; ++j) {
      float p = __expf((scv[j] - m) * 0.25f);
      l += p;
      float4 v0 = *(const float4*)&Vs[c0+j][0];
      float4 v1 = *(const float4*)&Vs[c0+j][4];
      float4 v2 = *(const float4*)&Vs[c0+j][8];
      float4 v3 = *(const float4*)&Vs[c0+j][12];
      o0.x += p*v0.x; o0.y += p*v0.y; o0.z += p*v0.z; o0.w += p*v0.w;
      o1.x += p*v1.x; o1.y += p*v1.y; o1.z += p*v1.z; o1.w += p*v1.w;
      o2.x += p*v2.x; o2.y += p*v2.y; o2.z += p*v2.z; o2.w += p*v2.w;
      o3.x += p*v3.x; o3.y += p*v3.y; o3.z += p*v3.z; o3.w += p*v3.w;
    }
  }
  size_t R = (size_t)bh * S + s;
  pm[(size_t)ks * NR + R] = m;
  pl[(size_t)ks * NR + R] = l;
  float4* po4 = (float4*)po;
  po4[(size_t)(ks*4 + 0) * NR + R] = o0;
  po4[(size_t)(ks*4 + 1) * NR + R] = o1;
  po4[(size_t)(ks*4 + 2) * NR + R] = o2;
  po4[(size_t)(ks*4 + 3) * NR + R] = o3;
}

// combine KS partials per row (4 threads/row, d4 wave-uniform), write normalized ea
template <int S, int KS>
__global__ __launch_bounds__(256) void k_attn4c(
    const float* __restrict__ pm, const float* __restrict__ pl,
    const float* __restrict__ po, float* __restrict__ ea)
{
  constexpr int NR = BSG * NHD * S;
  int R = blockIdx.x * 64 + (threadIdx.x & 63);
  int d4 = threadIdx.x >> 6;   // wave-uniform
  float mv[KS];
  float m = -1e30f;
  #pragma unroll
  for (int k = 0; k < KS; ++k) { mv[k] = pm[(size_t)k*NR + R]; m = fmaxf(m, mv[k]); }
  const float4* po4 = (const float4*)po;
  float l = 0.0f;
  float4 o = {0, 0, 0, 0};
  #pragma unroll
  for (int k = 0; k < KS; ++k) {
    float w = __expf((mv[k] - m) * 0.25f);
    l += pl[(size_t)k*NR + R] * w;
    float4 p = po4[(size_t)(k*4 + d4)*NR + R];
    o.x += p.x*w; o.y += p.y*w; o.z += p.z*w; o.w += p.w*w;
  }
  float inv = 1.0f / l;
  float4 r = {o.x*inv, o.y*inv, o.z*inv, o.w*inv};
  ((float4*)ea)[(size_t)d4*NR + R] = r;
}

// gather ea rows per (block, channel) via block-edge CSR; divide by cnt
__global__ __launch_bounds__(256) void k_bsum_gather(
    const float* __restrict__ ea, const int* __restrict__ blist,
    const int* __restrict__ boff, float* __restrict__ bsum)
{
  constexpr int NR = BSG * NHD * EBE;
  int idx = blockIdx.x * 256 + threadIdx.x;   // over NBLKT*32
  int i = idx >> 5, c4 = idx & 31;
  int b = i >> 6, blk = i & 63;
  int h = c4 >> 2, d4 = c4 & 3;
  int e0 = boff[b*65 + blk], e1 = boff[b*65 + blk + 1];
  const float4* ea4 = (const float4*)ea;
  size_t basein = (size_t)d4 * NR + (size_t)(b*NHD + h) * EBE;
  float4 s = {0, 0, 0, 0};
  for (int e = e0; e < e1; ++e) {
    int srow = blist[b*EBE + e];
    float4 v = ea4[basein + srow];
    s.x += v.x; s.y += v.y; s.z += v.z; s.w += v.w;
  }
  float cnt = (float)(e1 - e0);
  float sc = (cnt > 0.0f) ? (1.0f / cnt) : 0.0f;
  float4 o = {s.x*sc, s.y*sc, s.z*sc, s.w*sc};
  *(float4*)&bsum[(size_t)i*H + c4*4] = o;
}

// ---------------- block self-attention: LDS K/V, wave-reduced mean, NO atomics ----
__global__ __launch_bounds__(256) void k_attnS(
    const float* __restrict__ qkv, float* __restrict__ m2)
{
  __shared__ float Ks[4][LBLK][DH];
  __shared__ float Vs[4][LBLK][DH];
  __shared__ float red[4][LBLK][DH + 1];   // pad 17: odd stride -> conflict-free
  int b = blockIdx.x >> 1, hq = blockIdx.x & 1;
  int tid = threadIdx.x;
  const float* base = qkv + (size_t)b * LBLK * 384;
  for (int t = tid; t < 1024; t += 256) {
    int hl = t >> 8, j = (t >> 2) & 63, d4 = t & 3;
    int h = hq*4 + hl;
    *(float4*)&Ks[hl][j][d4*4] = *(const float4*)(base + (size_t)j*384 + 128 + h*DH + d4*4);
    *(float4*)&Vs[hl][j][d4*4] = *(const float4*)(base + (size_t)j*384 + 256 + h*DH + d4*4);
  }
  __syncthreads();
  int hl = tid >> 6, s = tid & 63;   // hl uniform per wave; wave owns (b, h)
  int h = hq*4 + hl;
  const float4* qp = (const float4*)(base + (size_t)s * 384 + h * DH);
  float4 q0 = qp[0], q1 = qp[1], q2 = qp[2], q3 = qp[3];
  float m = -1e30f, l = 0.0f;
  float4 o0 = {0,0,0,0}, o1 = {0,0,0,0}, o2 = {0,0,0,0}, o3 = {0,0,0,0};
  for (int c0 = 0; c0 < LBLK; c0 += 32) {
    float scv[32];
    float mc = -1e30f;
    #pragma unroll
    for (int j = 0; j < 32; ++j) {
      float4 k0 = *(const float4*)&Ks[hl][c0+j][0];
      float4 k1 = *(const float4*)&Ks[hl][c0+j][4];
      float4 k2 = *(const float4*)&Ks[hl][c0+j][8];
      float4 k3 = *(const float4*)&Ks[hl][c0+j][12];
      float s0 = q0.x*k0.x + q0.y*k0.y + q0.z*k0.z + q0.w*k0.w;
      float s1 = q1.x*k1.x + q1.y*k1.y + q1.z*k1.z + q1.w*k1.w;
      float s2 = q2.x*k2.x + q2.y*k2.y + q2.z*k2.z + q2.w*k2.w;
      float s3 = q3.x*k3.x + q3.y*k3.y + q3.z*k3.z + q3.w*k3.w;
      float sc = (s0 + s1) + (s2 + s3);
      scv[j] = sc;
      mc = fmaxf(mc, sc);
    }
    float mn = fmaxf(m, mc);
    float corr = __expf((m - mn) * 0.25f);
    l *= corr;
    o0.x *= corr; o0.y *= corr; o0.z *= corr; o0.w *= corr;
    o1.x *= corr; o1.y *= corr; o1.z *= corr; o1.w *= corr;
    o2.x *= corr; o2.y *= corr; o2.z *= corr; o2.w *= corr;
    o3.x *= corr; o3.y *= corr; o3.z *= corr; o3.w *= corr;
    m = mn;
    #pragma unroll
    for (int j = 0; j < 32; ++j) {
      float p = __expf((scv[j] - m) * 0.25f);
      l += p;
      float4 v0 = *(const float4*)&Vs[hl][c0+j][0];
      float4 v1 = *(const float4*)&Vs[hl][c0+j][4];
      float4 v2 = *(const float4*)&Vs[hl][c0+j][8];
      float4 v3 = *(const float4*)&Vs[hl][c0+j][12];
      o0.x += p*v0.x; o0.y += p*v0.y; o0.z += p*v0.z; o0.w += p*v0.w;
      o1.x += p*v1.x; o1.y += p*v1.y; o1.z += p*v1.z; o1.w += p*v1.w;
      o2.x += p*v2.x; o2.y += p*v2.y; o2.z += p*v2.z; o2.w += p*v2.w;
      o3.x += p*v3.x; o3.y += p*v3.y; o3.z += p*v3.z; o3.w += p*v3.w;
    }
  }
  // normalize this row's output and stash in LDS (17-stride, conflict-free)
  float inv = (1.0f / l) * (1.0f / 64.0f);
  float ov[DH] = {o0.x,o0.y,o0.z,o0.w, o1.x,o1.y,o1.z,o1.w,
                  o2.x,o2.y,o2.z,o2.w, o3.x,o3.y,o3.z,o3.w};
  #pragma unroll
  for (int d = 0; d < DH; ++d) red[hl][s][d] = ov[d] * inv;
  __syncthreads();
  // wave owns (b,h): lanes 0..15 sum the 64 rows, plain store (no atomics)
  if (s < DH) {
    float acc = 0.0f;
    for (int r = 0; r < LBLK; ++r) acc += red[hl][r][s];
    m2[(size_t)b * H + h * DH + s] = acc;
  }
}

// ---------------- final: out-proj + LN + 3-layer MLP ----------------
__device__ __forceinline__ float bsum128(float v, float* red) {
  int t = threadIdx.x;
  red[t] = v; __syncthreads();
  #pragma unroll
  for (int off = 64; off > 0; off >>= 1) {
    if (t < off) red[t] += red[t + off];
    __syncthreads();
  }
  float s = red[0];
  __syncthreads();
  return s;
}

__global__ __launch_bounds__(128) void k_final(
    const float* __restrict__ m2, const float* __restrict__ out_w,
    const float* __restrict__ out_b, const float* __restrict__ lng,
    const float* __restrict__ lnb, const float* __restrict__ w1,
    const float* __restrict__ b1, const float* __restrict__ w2,
    const float* __restrict__ b2, const float* __restrict__ w3,
    const float* __restrict__ b3, float* __restrict__ out)
{
  __shared__ float buf[128];
  __shared__ float red[128];
  int b = blockIdx.x, t = threadIdx.x;
  buf[t] = m2[b*H + t];
  __syncthreads();
  float g = out_b[t];
  for (int k = 0; k < H; ++k) g += buf[k] * out_w[k*H + t];
  float mu = bsum128(g, red) * (1.0f / H);
  float df = g - mu;
  float var = bsum128(df * df, red) * (1.0f / H);
  float gn = df / sqrtf(var + 1e-5f) * lng[t] + lnb[t];
  __syncthreads();
  buf[t] = gn; __syncthreads();
  float h1 = b1[t];
  for (int k = 0; k < H; ++k) h1 += buf[k] * w1[k*H + t];
  h1 = fmaxf(h1, 0.0f);
  __syncthreads();
  buf[t] = h1; __syncthreads();
  float h2 = b2[t];
  for (int k = 0; k < H; ++k) h2 += buf[k] * w2[k*H + t];
  h2 = fmaxf(h2, 0.0f);
  float tot = bsum128(h2 * w3[t], red);
  if (t == 0) out[b] = tot + b3[0];
}

extern "C" void kernel_launch(void* const* d_in, const int* in_sizes, int n_in,
                              void* d_out, int out_size, void* d_ws, size_t ws_size,
                              hipStream_t stream) {
  (void)in_sizes; (void)n_in; (void)out_size; (void)ws_size;
  const int*   A          = (const int*)d_in[0];
  const int*   apos       = (const int*)d_in[1];
  const int*   btypes     = (const int*)d_in[2];
  const float* coords     = (const float*)d_in[3];
  const int*   edge_index = (const int*)d_in[4];
  const int*   bedges     = (const int*)d_in[5];
  const float* emb_atom   = (const float*)d_in[6];
  const float* emb_pos    = (const float*)d_in[7];
  const float* emb_block  = (const float*)d_in[8];
  const float* rbf_freq   = (const float*)d_in[9];
  const float* inter_w1   = (const float*)d_in[10];
  const float* inter_b1   = (const float*)d_in[11];
  const float* inter_w2   = (const float*)d_in[12];
  const float* inter_b2   = (const float*)d_in[13];
  const float* upd_w1     = (const float*)d_in[14];
  const float* upd_b1     = (const float*)d_in[15];
  const float* upd_w2     = (const float*)d_in[16];
  const float* upd_b2     = (const float*)d_in[17];
  const float* edge_w1    = (const float*)d_in[18];
  const float* edge_b1    = (const float*)d_in[19];
  const float* edge_w2    = (const float*)d_in[20];
  const float* edge_b2    = (const float*)d_in[21];
  const float* attn_in_w  = (const float*)d_in[22];
  const float* attn_in_b  = (const float*)d_in[23];
  const float* attn_out_w = (const float*)d_in[24];
  const float* attn_out_b = (const float*)d_in[25];
  const float* ln_g       = (const float*)d_in[26];
  const float* ln_b       = (const float*)d_in[27];
  const float* fin_w1     = (const float*)d_in[28];
  const float* fin_b1     = (const float*)d_in[29];
  const float* fin_w2     = (const float*)d_in[30];
  const float* fin_b2     = (const float*)d_in[31];
  const float* fin_w3     = (const float*)d_in[32];
  const float* fin_b3     = (const float*)d_in[33];
  float* out = (float*)d_out;

  float* ws = (float*)d_ws;
  float* x      = ws + 0;
  float* P      = ws + 2097152;
  float* Q      = ws + 4194304;
  float* Hagg   = ws + 6291456;
  float* rbf_s  = ws + 8388608;    // E*6 (sorted RBF)
  float* cntf   = ws + 9961472;    // NA
  float* blocks = ws + 9977856;    // NBLKT*H
  float* Pb     = ws + 10108928;
  float* Qb     = ws + 10240000;
  float* qkv    = ws + 12468224;   // BSG*EBE*384
  float* bsum   = ws + 15613952;   // NBLKT*H
  float* ind    = ws + 15746048;   // NBLKT
  float* m2     = ws + 15747072;   // BSG*H
  int* blist    = (int*)(ws + 15749120);  // BSG*EBE ints
  int* boff     = (int*)(ws + 15757312);  // BSG*65 ints
  // sort scratch + wprep live in the old-Epre region (dead until attention):
  int* ej_s   = (int*)(ws + 10371072);          // NE ints
  int* off    = (int*)(ws + 10371072 + 262144); // NA+1 ints
  int* cur    = (int*)(ws + 10371072 + 278784); // NA ints
  int* cnt    = (int*)(ws + 10371072 + 295168); // NA ints
  float* wbuf = ws + 10371072 + 311552;         // 2 x 256*128 floats
  float* bvec = ws + 10371072 + 311552 + 65536; // 2 x 128 floats
  // attention partials (KS=8, split-major) reuse x/P/Q/Hagg/rbf_s regions:
  float* part_m = ws + 0;          // 8*65536 = 524288 floats
  float* part_l = ws + 524288;     // 524288 floats
  float* part_o = ws + 1048576;    // 8*65536*16 = 8388608 floats -> ends 9437184
  float* ea     = ws + 10371072;   // 65536*16 = 1048576 floats (old Epre region)

  const int* ei = edge_index;
  const int* ej = edge_index + NE;

  // ---- edge sort (once; reused by both interaction blocks) ----
  (void)hipMemsetAsync(cnt, 0, NA * sizeof(int), stream);
  k_hist<<<NE/256, 256, 0, stream>>>(ei, cnt);
  k_scan<<<1, 1024, 0, stream>>>(cnt, off, cur, cntf);
  k_scatter<<<NE/256, 256, 0, stream>>>(ei, ej, coords, rbf_freq, cur, ej_s, rbf_s);
  k_bedge_csr<<<BSG, 256, 0, stream>>>(bedges, blist, boff, ind);
  // both interaction blocks' weight preps in one launch
  k_wprep<<<dim3(128, 2), 128, 0, stream>>>(inter_w2, upd_w1, inter_b2, wbuf, bvec);

  k_embed<<<NA*H/256, 256, 0, stream>>>(A, apos, btypes, emb_atom, emb_pos, emb_block, x);

  for (int b = 0; b < NBI; ++b) {
    const float* w1 = inter_w1 + (size_t)b * 262 * H;
    // fused: P = x@W1a + b1 (y=0) ; Q = x@W1b (y=1, no bias)
    gemm128<<<dim3(NA/32, 2), 256, 0, stream>>>(x, nullptr, w1, H, 0, inter_b1 + b*H,
                                                nullptr, nullptr, nullptr,
                                                P, H, 0, NA, H, 0, 0, 128, 2097152);
    k_edge_csr<<<NA/8, 256, 0, stream>>>(P, Q, rbf_s, w1 + 256*H, ej_s, off, Hagg);
    // chained: U = silu([x|Hagg]@wbuf + b1 + cnt*bvec); x = U@upd_w2 + b2 + x
    k_upd_chain<<<NA/32, 256, 0, stream>>>(x, Hagg, wbuf + (size_t)b*32768,
                                           upd_b1 + b*H, bvec + b*H, cntf,
                                           upd_w2 + (size_t)b*H*H, upd_b2 + b*H, x);
  }

  k_block_mean<<<NBLKT*H/256, 256, 0, stream>>>(x, blocks);
  // fused: Pb = blocks@edge_w1a + b (y=0) ; Qb = blocks@edge_w1b (y=1)
  gemm128<<<dim3(NBLKT/32, 2), 256, 0, stream>>>(blocks, nullptr, edge_w1, H, 0, edge_b1,
                                                 nullptr, nullptr, nullptr,
                                                 Pb, H, 0, NBLKT, H, 0, 0, 128, 131072);
  // fused: Epre gather+relu -> @edge_w2+b -> @attn_in_w+b -> qkv (y-split chunks)
  k_eprep<<<dim3(BSG*EBE/32, 3), 256, 0, stream>>>(Pb, Qb, bedges, edge_w2, edge_b2,
                                                   attn_in_w, attn_in_b, qkv);
  k_attn4<EBE, 8><<<BSG*NHD*8*(EBE/256), 256, 0, stream>>>(qkv, part_m, part_l, part_o);
  k_attn4c<EBE, 8><<<BSG*NHD*EBE/64, 256, 0, stream>>>(part_m, part_l, part_o, ea);
  k_bsum_gather<<<NBLKT*32/256, 256, 0, stream>>>(ea, blist, boff, bsum);
  // fused tail: blocks' = bsum@out_w + out_b*ind + blocks ; qkv = blocks'@attn_in_w
  k_bprep<<<dim3(NBLKT/32, 3), 256, 0, stream>>>(bsum, attn_out_w, attn_out_b, ind,
                                                 blocks, attn_in_w, attn_in_b, qkv);
  k_attnS<<<BSG*2, 256, 0, stream>>>(qkv, m2);
  k_final<<<BSG, 128, 0, stream>>>(m2, attn_out_w, attn_out_b, ln_g, ln_b,
                                   fin_w1, fin_b1, fin_w2, fin_b2, fin_w3, fin_b3, out);
}